// Round 4
// baseline (2276.345 us; speedup 1.0000x reference)
//
#include <hip/hip_runtime.h>
#include <cstddef>

namespace {

constexpr int B  = 4;
constexpr int C  = 768;
constexpr int T  = 512;
constexpr int H  = 12;
constexpr int D  = 64;
constexpr int NL = 6;
constexpr int W  = 4;
constexpr int FF = 3072;

typedef __attribute__((ext_vector_type(8))) short sh8;
typedef __attribute__((ext_vector_type(4))) float f32x4;

__device__ inline float gelu_exact(float x) {
  return 0.5f * x * (1.0f + erff(x * 0.70710678118654752440f));
}
__device__ inline unsigned short f2b(float f) {
  unsigned u = __float_as_uint(f);
  unsigned r = (u + 0x7fffu + ((u >> 16) & 1u)) >> 16;
  return (unsigned short)r;
}
__device__ inline float b2f(unsigned short u) {
  return __uint_as_float((unsigned)u << 16);
}
__device__ inline void gload_lds16(const void* g, void* l) {
  __builtin_amdgcn_global_load_lds(
      (const __attribute__((address_space(1))) unsigned int*)g,
      (__attribute__((address_space(3))) unsigned int*)l, 16, 0, 0);
}

// ---------------------------------------------------------------------------
// flat fp32 -> bf16 (8 elems/thread)
__global__ __launch_bounds__(256) void cvt_flat8(
    const float* __restrict__ s, unsigned short* __restrict__ d)
{
  const size_t i = ((size_t)blockIdx.x * 256 + threadIdx.x) * 8;
  float4 a = *(const float4*)(s + i);
  float4 b = *(const float4*)(s + i + 4);
  sh8 u;
  u[0] = (short)f2b(a.x); u[1] = (short)f2b(a.y);
  u[2] = (short)f2b(a.z); u[3] = (short)f2b(a.w);
  u[4] = (short)f2b(b.x); u[5] = (short)f2b(b.y);
  u[6] = (short)f2b(b.z); u[7] = (short)f2b(b.w);
  *(sh8*)(d + i) = u;
}

// QKVO weights fp32 [C][C] -> bf16, 4 matrices via blockIdx.y
__global__ __launch_bounds__(256) void cvt_qkvo(
    const float* __restrict__ q, const float* __restrict__ k,
    const float* __restrict__ v, const float* __restrict__ o,
    unsigned short* __restrict__ dq, unsigned short* __restrict__ dk,
    unsigned short* __restrict__ dv, unsigned short* __restrict__ dov)
{
  const int z = blockIdx.y;
  const float* s = z == 0 ? q : z == 1 ? k : z == 2 ? v : o;
  unsigned short* d = z == 0 ? dq : z == 1 ? dk : z == 2 ? dv : dov;
  const size_t i = ((size_t)blockIdx.x * 256 + threadIdx.x) * 8;
  float4 a = *(const float4*)(s + i);
  float4 b = *(const float4*)(s + i + 4);
  sh8 u;
  u[0] = (short)f2b(a.x); u[1] = (short)f2b(a.y);
  u[2] = (short)f2b(a.z); u[3] = (short)f2b(a.w);
  u[4] = (short)f2b(b.x); u[5] = (short)f2b(b.y);
  u[6] = (short)f2b(b.z); u[7] = (short)f2b(b.w);
  *(sh8*)(d + i) = u;
}

// FFN weight permute+convert: [O][Cin][3] fp32 -> [3][O][Cin] bf16
__global__ __launch_bounds__(256) void cvt_conv_w(
    const float* __restrict__ s1, const float* __restrict__ s2,
    unsigned short* __restrict__ d1, unsigned short* __restrict__ d2)
{
  const int z = blockIdx.y;
  const float* src = z ? s2 : s1;
  unsigned short* dst = z ? d2 : d1;
  const int O  = z ? C : FF;
  const int Ci = z ? FF : C;
  const int Ci4 = Ci >> 2;
  const size_t idx = (size_t)blockIdx.x * 256 + threadIdx.x;
  const int o  = (int)(idx / Ci4);
  const int c4 = (int)(idx % Ci4) << 2;
  const float* s = src + ((size_t)o * Ci + c4) * 3;
  float4 f0 = *(const float4*)(s);
  float4 f1 = *(const float4*)(s + 4);
  float4 f2 = *(const float4*)(s + 8);
  const float f[12] = {f0.x, f0.y, f0.z, f0.w, f1.x, f1.y, f1.z, f1.w,
                       f2.x, f2.y, f2.z, f2.w};
#pragma unroll
  for (int tap = 0; tap < 3; ++tap) {
    ushort4 h;
    h.x = f2b(f[0 * 3 + tap]);
    h.y = f2b(f[1 * 3 + tap]);
    h.z = f2b(f[2 * 3 + tap]);
    h.w = f2b(f[3 * 3 + tap]);
    *(ushort4*)(dst + ((size_t)tap * O + o) * Ci + c4) = h;
  }
}

// ---------------------------------------------------------------------------
// MFMA conv/GEMM, all-bf16 operands.
// out[b,o,t] = sum_{c,kk} w[kk][o][c] * in[b,c,t+kk-HP] (+bias)
// BM=128 x BN(128|64), BK=32. BN=128: 2x2 waves each 64x64 (16 MFMA/K-step).
// A: [TAPS][128][32] linear, staged via global_load_lds (16B/lane).
// B: [ROWS][40] bf16 (t-major transpose, pitch 80B = conflict-light).
// SPLIT: blockIdx.z = b*3+kk, atomicAdd fp32 epilogue (FFN-down tap split).
template <int TAPS, int BN, bool SPLIT, bool GELU, bool MASK_IN, bool MASK_OUT,
          bool OBF16>
__global__ __launch_bounds__(256) void mfma_conv(
    const unsigned short* __restrict__ xin,        // bf16 [B][Cin][T]
    const unsigned short* __restrict__ w0p, const unsigned short* __restrict__ w1p,
    const unsigned short* __restrict__ w2p,        // bf16 [TAPS][O][Cin]
    const float* __restrict__ b0, const float* __restrict__ b1,
    const float* __restrict__ b2,
    const float* __restrict__ mask,                // [B][T]
    void* __restrict__ o0p, void* __restrict__ o1p, void* __restrict__ o2p,
    int Cin, int O, int tilesPerPlane)
{
  constexpr int BM = 128, BK = 32;
  constexpr int ROWS_B = BN + TAPS - 1;
  constexpr int PB = 40;
  constexpr int WN = (BN == 128) ? 2 : 1;
  constexpr int WM = 4 / WN;
  constexpr int MF = BM / (WM * 16);
  constexpr int NF = BN / (WN * 16);
  __shared__ unsigned short Aw[TAPS * BM * BK];
  __shared__ unsigned short Bx[ROWS_B * PB];

  const int zz = blockIdx.z;
  const int b  = SPLIT ? zz / 3 : zz;
  const int kk = SPLIT ? zz % 3 : 0;
  const int TOFF = SPLIT ? (kk - 1) : ((TAPS == 3) ? -1 : 0);
  const int t0 = blockIdx.x * BN;
  const int plane = blockIdx.y / tilesPerPlane;
  const int o0 = (blockIdx.y % tilesPerPlane) * BM;

  const int tid = threadIdx.x;
  const int lane = tid & 63, wid = tid >> 6;
  const int wm = wid / WN, wn = wid % WN;
  const int l15 = lane & 15, lhi = lane >> 4;
  const size_t xbase = (size_t)b * Cin * T;
  const int bmask = b * T;

  const unsigned short* wsel = plane == 0 ? w0p : (plane == 1 ? w1p : w2p);
  if (SPLIT) wsel += (size_t)kk * O * Cin;
  const float* bp = plane == 0 ? b0 : (plane == 1 ? b1 : b2);

  f32x4 acc[MF][NF] = {};

  for (int c0 = 0; c0 < Cin; c0 += BK) {
    __syncthreads();
    // ---- stage A: async global->LDS (bf16 weights, 16B per lane) ----
#pragma unroll
    for (int tap = 0; tap < TAPS; ++tap) {
      const unsigned short* wpl = wsel + (size_t)tap * O * Cin + c0;
#pragma unroll
      for (int j = 0; j < 2; ++j) {
        const int rbase = j * 64 + wid * 16;  // wave-uniform row base
        const unsigned short* src =
            wpl + (size_t)(o0 + rbase + (lane >> 2)) * Cin + ((lane & 3) << 3);
        gload_lds16(src, &Aw[tap * (BM * BK) + rbase * BK]);
      }
    }
    // ---- stage B: transposed bf16 (coalesced 128B runs of t per load) ----
    {
      constexpr int NPASS = 4 * BN / 256;  // 128->2, 64->1
#pragma unroll
      for (int p = 0; p < NPASS; ++p) {
        const int c8 = ((p * (256 / BN)) + (tid / BN)) * 8;
        for (int rr = tid & (BN - 1); rr < ROWS_B; rr += BN) {
          const int tsrc = t0 + rr + TOFF;
          sh8 u = (sh8)0;
          if ((unsigned)tsrc < (unsigned)T) {
            const unsigned short* xp = xin + xbase + (size_t)(c0 + c8) * T + tsrc;
            if (MASK_IN) {
              const float mk = mask[bmask + tsrc];
#pragma unroll
              for (int j = 0; j < 8; ++j)
                u[j] = (short)f2b(b2f(xp[(size_t)j * T]) * mk);
            } else {
#pragma unroll
              for (int j = 0; j < 8; ++j) u[j] = (short)xp[(size_t)j * T];
            }
          }
          *(sh8*)&Bx[rr * PB + c8] = u;
        }
      }
    }
    __syncthreads();
    // ---- MFMA ----
#pragma unroll
    for (int tap = 0; tap < TAPS; ++tap) {
      sh8 af[MF], bfr[NF];
#pragma unroll
      for (int m = 0; m < MF; ++m)
        af[m] = *(const sh8*)&Aw[tap * (BM * BK) +
                                 (wm * MF * 16 + m * 16 + l15) * BK + lhi * 8];
#pragma unroll
      for (int n = 0; n < NF; ++n)
        bfr[n] = *(const sh8*)&Bx[(wn * NF * 16 + n * 16 + l15 + tap) * PB + lhi * 8];
#pragma unroll
      for (int m = 0; m < MF; ++m)
#pragma unroll
        for (int n = 0; n < NF; ++n)
          acc[m][n] = __builtin_amdgcn_mfma_f32_16x16x32_bf16(
              af[m], bfr[n], acc[m][n], 0, 0, 0);
    }
  }

  // ---- epilogue ----
  void* obase = plane == 0 ? o0p : (plane == 1 ? o1p : o2p);
  float* opf = (float*)obase + (size_t)b * O * T;
  unsigned short* oph = (unsigned short*)obase + (size_t)b * O * T;
#pragma unroll
  for (int m = 0; m < MF; ++m) {
    const int o = o0 + wm * MF * 16 + m * 16 + (lhi << 2);
#pragma unroll
    for (int n = 0; n < NF; ++n) {
      const int t = t0 + wn * NF * 16 + n * 16 + l15;
      const float mk = MASK_OUT ? mask[bmask + t] : 1.f;
#pragma unroll
      for (int r = 0; r < 4; ++r) {
        float v = acc[m][n][r];
        if (SPLIT) {
          if (kk == 0) v += bp[o + r];
        } else {
          v += bp[o + r];
        }
        if (GELU) v = gelu_exact(v);
        if (MASK_OUT) v *= mk;
        if constexpr (OBF16) {
          oph[(size_t)(o + r) * T + t] = f2b(v);
        } else if constexpr (SPLIT) {
          atomicAdd(&opf[(size_t)(o + r) * T + t], v);
        } else {
          opf[(size_t)(o + r) * T + t] = v;
        }
      }
    }
  }
}

// ---------------------------------------------------------------------------
// Fused attention (unchanged structure; bf16 output for Wo input).
__global__ __launch_bounds__(256) void fused_attn(
    const unsigned short* __restrict__ qg,  // [B][C][T] bf16
    const unsigned short* __restrict__ kg,
    const unsigned short* __restrict__ vg,
    const float* __restrict__ mask,         // [B][T]
    const float* __restrict__ ek,           // [D][9]
    const float* __restrict__ ev,           // [D][9]
    unsigned short* __restrict__ outp)      // [B][C][T] bf16
{
  constexpr int PITCH = 72;
  __shared__ unsigned short Qs[64 * PITCH];
  __shared__ unsigned short Ks[64 * PITCH];
  __shared__ unsigned short Vs[64 * PITCH];
  __shared__ unsigned short Ps[64 * PITCH];
  __shared__ float eks[D * 9], evs[D * 9];
  __shared__ float qekl[64 * 12];
  __shared__ float mks[64];

  const int t0 = blockIdx.x * 64;
  const int bh = blockIdx.y;
  const int b = bh / H, h = bh % H;
  const int tid = threadIdx.x;
  const int lane = tid & 63, w = tid >> 6;
  const int l15 = lane & 15, lhi = lane >> 4;

  const size_t hoff = ((size_t)b * C + h * D) * T;
  const unsigned short* qh = qg + hoff;
  const unsigned short* kh = kg + hoff;
  const unsigned short* vh = vg + hoff;

  for (int e = tid; e < D * 9; e += 256) { eks[e] = ek[e]; evs[e] = ev[e]; }
  {
    const int tl = tid & 63, d0 = (tid >> 6) << 4;
    sh8 u0, u1;
#pragma unroll
    for (int j = 0; j < 8; ++j)
      u0[j] = (short)f2b(0.125f * b2f(qh[(size_t)(d0 + j) * T + t0 + tl]));
#pragma unroll
    for (int j = 0; j < 8; ++j)
      u1[j] = (short)f2b(0.125f * b2f(qh[(size_t)(d0 + 8 + j) * T + t0 + tl]));
    *(sh8*)&Qs[tl * PITCH + d0] = u0;
    *(sh8*)&Qs[tl * PITCH + d0 + 8] = u1;
  }
  __syncthreads();
  {
    const int tl = tid & 63, g = tid >> 6;
    for (int j = g; j < 9; j += 4) {
      float a = 0.f;
      for (int d = 0; d < D; ++d)
        a = fmaf(b2f(Qs[tl * PITCH + d]), eks[d * 9 + j], a);
      qekl[tl * 12 + j] = a;
    }
  }
  const int t_loc = w * 16 + l15;
  const int t = t0 + t_loc;
  const float mask_t = mask[b * T + t];
  const sh8 bq0 = *(const sh8*)&Qs[t_loc * PITCH + lhi * 8];
  const sh8 bq1 = *(const sh8*)&Qs[t_loc * PITCH + 32 + lhi * 8];

  float m_run = -1e30f, l_run = 0.f;
  f32x4 oacc[4] = {};

  for (int s0 = 0; s0 < T; s0 += 64) {
    __syncthreads();
    {
      const int sl = tid & 63;
#pragma unroll
      for (int cc = 0; cc < 2; ++cc) {
        const int d0 = (((tid >> 6) << 1) + cc) << 3;
        sh8 u;
#pragma unroll
        for (int j = 0; j < 8; ++j)
          u[j] = (short)kh[(size_t)(d0 + j) * T + s0 + sl];
        *(sh8*)&Ks[sl * PITCH + d0] = u;
      }
    }
    {
#pragma unroll
      for (int cc = 0; cc < 2; ++cc) {
        const int idx = tid + (cc << 8);
        const int dr = idx >> 3, ch = (idx & 7) << 3;
        sh8 u = *(const sh8*)&vh[(size_t)dr * T + s0 + ch];
        *(sh8*)&Vs[dr * PITCH + ch] = u;
      }
    }
    if (tid < 64) mks[tid] = mask[b * T + s0 + tid];
    __syncthreads();

    float p[16];
#pragma unroll
    for (int n = 0; n < 4; ++n) {
      const sh8 a0 = *(const sh8*)&Ks[(n * 16 + l15) * PITCH + lhi * 8];
      const sh8 a1 = *(const sh8*)&Ks[(n * 16 + l15) * PITCH + 32 + lhi * 8];
      f32x4 acc = {};
      acc = __builtin_amdgcn_mfma_f32_16x16x32_bf16(a0, bq0, acc, 0, 0, 0);
      acc = __builtin_amdgcn_mfma_f32_16x16x32_bf16(a1, bq1, acc, 0, 0, 0);
#pragma unroll
      for (int r = 0; r < 4; ++r) {
        const int s = s0 + n * 16 + lhi * 4 + r;
        float v = acc[r];
        const int j = s - t + 4;
        if ((unsigned)j < 9u) v += qekl[t_loc * 12 + j];
        if (mask_t * mks[s - s0] == 0.f) v = -10000.0f;
        p[n * 4 + r] = v;
      }
    }
    float mloc = p[0];
#pragma unroll
    for (int i = 1; i < 16; ++i) mloc = fmaxf(mloc, p[i]);
    mloc = fmaxf(mloc, __shfl_xor(mloc, 16));
    mloc = fmaxf(mloc, __shfl_xor(mloc, 32));
    const float m_new = fmaxf(m_run, mloc);
    const float f = __expf(m_run - m_new);
    float sloc = 0.f;
#pragma unroll
    for (int i = 0; i < 16; ++i) { p[i] = __expf(p[i] - m_new); sloc += p[i]; }
    sloc += __shfl_xor(sloc, 16);
    sloc += __shfl_xor(sloc, 32);
    l_run = l_run * f + sloc;
    m_run = m_new;
#pragma unroll
    for (int m = 0; m < 4; ++m)
#pragma unroll
      for (int r = 0; r < 4; ++r) oacc[m][r] *= f;
#pragma unroll
    for (int n = 0; n < 4; ++n) {
      uint2 pk;
      pk.x = (unsigned)f2b(p[n * 4 + 0]) | ((unsigned)f2b(p[n * 4 + 1]) << 16);
      pk.y = (unsigned)f2b(p[n * 4 + 2]) | ((unsigned)f2b(p[n * 4 + 3]) << 16);
      *(uint2*)&Ps[t_loc * PITCH + n * 16 + lhi * 4] = pk;
    }
    asm volatile("s_waitcnt lgkmcnt(0)" ::: "memory");
    const sh8 bp0 = *(const sh8*)&Ps[t_loc * PITCH + lhi * 8];
    const sh8 bp1 = *(const sh8*)&Ps[t_loc * PITCH + 32 + lhi * 8];
#pragma unroll
    for (int m = 0; m < 4; ++m) {
      const sh8 a0 = *(const sh8*)&Vs[(m * 16 + l15) * PITCH + lhi * 8];
      const sh8 a1 = *(const sh8*)&Vs[(m * 16 + l15) * PITCH + 32 + lhi * 8];
      oacc[m] = __builtin_amdgcn_mfma_f32_16x16x32_bf16(a0, bp0, oacc[m], 0, 0, 0);
      oacc[m] = __builtin_amdgcn_mfma_f32_16x16x32_bf16(a1, bp1, oacc[m], 0, 0, 0);
    }
    if (t + 4 >= s0 && t < s0 + 68) {
#pragma unroll
      for (int j = 0; j < 9; ++j) {
        const int s = t + j - 4;
        if (s >= s0 && s < s0 + 64) {
          const float pv = b2f(Ps[t_loc * PITCH + (s - s0)]);
#pragma unroll
          for (int m = 0; m < 4; ++m)
#pragma unroll
            for (int r = 0; r < 4; ++r)
              oacc[m][r] = fmaf(pv, evs[(m * 16 + lhi * 4 + r) * 9 + j], oacc[m][r]);
        }
      }
    }
  }
  const float invl = 1.f / l_run;
  unsigned short* ob = outp + ((size_t)b * C + h * D) * T + t;
#pragma unroll
  for (int m = 0; m < 4; ++m)
#pragma unroll
    for (int r = 0; r < 4; ++r)
      ob[(size_t)(m * 16 + lhi * 4 + r) * T] = f2b(oacc[m][r] * invl);
}

// ---------------------------------------------------------------------------
// dst = LayerNorm_C(x + y) (+mask); also emits bf16 copy for conv inputs.
template <bool MASK_OUT>
__global__ __launch_bounds__(256) void add_norm_kernel(
    const float* x, const float* y,
    const float* __restrict__ g, const float* __restrict__ bta,
    const float* __restrict__ mask, float* dst, unsigned short* dsth)
{
  const int b = blockIdx.y;
  const int t0 = blockIdx.x * 16;
  const int r = threadIdx.x >> 4, tc = threadIdx.x & 15;
  const int t = t0 + tc;
  const float* xb = x + (size_t)b * C * T;
  const float* yb = y + (size_t)b * C * T;
  float sum = 0.f, sq = 0.f;
  for (int ci = r; ci < C; ci += 16) {
    float v = xb[(size_t)ci * T + t] + yb[(size_t)ci * T + t];
    sum += v;
    sq = fmaf(v, v, sq);
  }
  __shared__ float ssum[16][17], ssq[16][17];
  __shared__ float mean_s[16], rstd_s[16];
  ssum[r][tc] = sum;
  ssq[r][tc] = sq;
  __syncthreads();
  if (r == 0) {
    float s = 0.f, q2 = 0.f;
#pragma unroll
    for (int i = 0; i < 16; ++i) { s += ssum[i][tc]; q2 += ssq[i][tc]; }
    const float m = s / C;
    mean_s[tc] = m;
    rstd_s[tc] = rsqrtf(q2 / C - m * m + 1e-5f);
  }
  __syncthreads();
  const float m = mean_s[tc], rs = rstd_s[tc];
  const float mk = MASK_OUT ? mask[b * T + t] : 1.f;
  float* db = dst + (size_t)b * C * T;
  unsigned short* dbh = dsth + (size_t)b * C * T;
  for (int ci = r; ci < C; ci += 16) {
    float v = xb[(size_t)ci * T + t] + yb[(size_t)ci * T + t];
    float o = (v - m) * rs * g[ci] + bta[ci];
    if (MASK_OUT) o *= mk;
    db[(size_t)ci * T + t] = o;
    dbh[(size_t)ci * T + t] = f2b(o);
  }
}

}  // namespace

extern "C" void kernel_launch(void* const* d_in, const int* in_sizes, int n_in,
                              void* d_out, int out_size, void* d_ws, size_t ws_size,
                              hipStream_t stream) {
  const float* x_in = (const float*)d_in[0];
  const float* mask = (const float*)d_in[1];
  const float* Wq = (const float*)d_in[2];
  const float* bq = (const float*)d_in[3];
  const float* Wk = (const float*)d_in[4];
  const float* bk = (const float*)d_in[5];
  const float* Wv = (const float*)d_in[6];
  const float* bv = (const float*)d_in[7];
  const float* Wo = (const float*)d_in[8];
  const float* bo = (const float*)d_in[9];
  const float* ek = (const float*)d_in[10];
  const float* ev = (const float*)d_in[11];
  const float* w1 = (const float*)d_in[12];
  const float* b1 = (const float*)d_in[13];
  const float* w2 = (const float*)d_in[14];
  const float* b2 = (const float*)d_in[15];
  const float* n1g = (const float*)d_in[16];
  const float* n1b = (const float*)d_in[17];
  const float* n2g = (const float*)d_in[18];
  const float* n2b = (const float*)d_in[19];

  float* ws = (float*)d_ws;
  const size_t SZ_X = (size_t)B * C * T;          // 1,572,864
  float* yb = ws;
  float* xb = yb + SZ_X;
  unsigned short* xbh = (unsigned short*)(xb + SZ_X);   // conv-input bf16
  unsigned short* qbh = xbh + SZ_X;
  unsigned short* kbh = qbh + SZ_X;
  unsigned short* vbh = kbh + SZ_X;
  unsigned short* hidh = vbh + SZ_X;                    // B*FF*T (attn out + ffn hid)
  unsigned short* w1b = hidh + (size_t)B * FF * T;      // [3][FF][C]
  unsigned short* w2b = w1b + (size_t)3 * FF * C;       // [3][C][FF]
  unsigned short* wqb = w2b + (size_t)3 * FF * C;       // [C][C]
  unsigned short* wkb = wqb + (size_t)C * C;
  unsigned short* wvb = wkb + (size_t)C * C;
  unsigned short* wob = wvb + (size_t)C * C;
  float* outp = (float*)d_out;

  const dim3 blk(256);
  // layer-0 conv input: x_in -> bf16
  cvt_flat8<<<dim3(SZ_X / 2048), blk, 0, stream>>>(x_in, xbh);

  for (int i = 0; i < NL; ++i) {
    const float* xs = (i == 0) ? x_in : xb;
    const size_t wOff = (size_t)i * C * C;
    // weights -> bf16 (QKVO flat; w1/w2 tap-permuted)
    cvt_qkvo<<<dim3((C * C) / 2048, 4), blk, 0, stream>>>(
        Wq + wOff, Wk + wOff, Wv + wOff, Wo + wOff, wqb, wkb, wvb, wob);
    cvt_conv_w<<<dim3((FF * C / 4) / 256, 2), blk, 0, stream>>>(
        w1 + (size_t)i * FF * C * 3, w2 + (size_t)i * C * FF * 3, w1b, w2b);
    // fused QKV projection -> bf16 q,k,v
    mfma_conv<1, 128, false, false, false, false, true>
        <<<dim3(4, 18, B), blk, 0, stream>>>(
        xbh, wqb, wkb, wvb, bq + i * C, bk + i * C, bv + i * C, mask,
        qbh, kbh, vbh, C, C, 6);
    // fused attention -> bf16
    fused_attn<<<dim3(T / 64, B * H), blk, 0, stream>>>(
        qbh, kbh, vbh, mask, ek + (size_t)i * D * 9, ev + (size_t)i * D * 9, hidh);
    // output projection (BN=64 for grid size)
    mfma_conv<1, 64, false, false, false, false, false>
        <<<dim3(8, 6, B), blk, 0, stream>>>(
        hidh, wob, wob, wob, bo + i * C, bo + i * C, bo + i * C, mask,
        yb, yb, yb, C, C, 6);
    add_norm_kernel<false><<<dim3(T / 16, B), blk, 0, stream>>>(
        xs, yb, n1g + i * C, n1b + i * C, mask, xb, xbh);
    // FFN up: C->FF, K=3, GELU, mask-in, bf16 out
    mfma_conv<3, 128, false, true, true, false, true>
        <<<dim3(4, 24, B), blk, 0, stream>>>(
        xbh, w1b, w1b, w1b, b1 + i * FF, b1 + i * FF, b1 + i * FF, mask,
        hidh, hidh, hidh, C, FF, 24);
    // FFN down: FF->C, tap-split-K, atomic fp32
    hipMemsetAsync(yb, 0, SZ_X * sizeof(float), stream);
    mfma_conv<1, 128, true, false, true, true, false>
        <<<dim3(4, 6, B * 3), blk, 0, stream>>>(
        hidh, w2b, w2b, w2b, b2 + i * C, b2 + i * C, b2 + i * C, mask,
        yb, yb, yb, FF, C, 6);
    add_norm_kernel<true><<<dim3(T / 16, B), blk, 0, stream>>>(
        xb, yb, n2g + i * C, n2b + i * C, mask, (i == NL - 1) ? outp : xb, xbh);
  }
}

// Round 5
// 1845.296 us; speedup vs baseline: 1.2336x; 1.2336x over previous
//
#include <hip/hip_runtime.h>
#include <cstddef>

namespace {

constexpr int B  = 4;
constexpr int C  = 768;
constexpr int T  = 512;
constexpr int H  = 12;
constexpr int D  = 64;
constexpr int NL = 6;
constexpr int W  = 4;
constexpr int FF = 3072;

typedef __attribute__((ext_vector_type(8))) short sh8;
typedef __attribute__((ext_vector_type(4))) float f32x4;

__device__ inline float gelu_exact(float x) {
  return 0.5f * x * (1.0f + erff(x * 0.70710678118654752440f));
}
__device__ inline unsigned short f2b(float f) {
  unsigned u = __float_as_uint(f);
  unsigned r = (u + 0x7fffu + ((u >> 16) & 1u)) >> 16;
  return (unsigned short)r;
}
__device__ inline float b2f(unsigned short u) {
  return __uint_as_float((unsigned)u << 16);
}
__device__ inline void gload_lds16(const void* g, void* l) {
  __builtin_amdgcn_global_load_lds(
      (const __attribute__((address_space(1))) unsigned int*)g,
      (__attribute__((address_space(3))) unsigned int*)l, 16, 0, 0);
}

// ---------------------------------------------------------------------------
// flat fp32 -> bf16 (8 elems/thread)
__global__ __launch_bounds__(256) void cvt_flat8(
    const float* __restrict__ s, unsigned short* __restrict__ d)
{
  const size_t i = ((size_t)blockIdx.x * 256 + threadIdx.x) * 8;
  float4 a = *(const float4*)(s + i);
  float4 b = *(const float4*)(s + i + 4);
  sh8 u;
  u[0] = (short)f2b(a.x); u[1] = (short)f2b(a.y);
  u[2] = (short)f2b(a.z); u[3] = (short)f2b(a.w);
  u[4] = (short)f2b(b.x); u[5] = (short)f2b(b.y);
  u[6] = (short)f2b(b.z); u[7] = (short)f2b(b.w);
  *(sh8*)(d + i) = u;
}

// QKVO weights fp32 [C][C] -> bf16 MFMA-fragment-tiled:
// dst[((mt*(C/32)+ks)*64 + (lhi*16+l15))*8 + j] = W[mt*16+l15][ks*32+lhi*8+j]
__global__ __launch_bounds__(256) void cvt_qkvo_tiled(
    const float* __restrict__ q, const float* __restrict__ k,
    const float* __restrict__ v, const float* __restrict__ o,
    unsigned short* __restrict__ dq, unsigned short* __restrict__ dk,
    unsigned short* __restrict__ dv, unsigned short* __restrict__ dov)
{
  const int z = blockIdx.y;
  const float* s = z == 0 ? q : z == 1 ? k : z == 2 ? v : o;
  unsigned short* d = z == 0 ? dq : z == 1 ? dk : z == 2 ? dv : dov;
  const int flat = blockIdx.x * 256 + threadIdx.x;   // over C*C/8
  const int row = flat / (C / 8);
  const int c   = (flat % (C / 8)) * 8;
  const int ks = c >> 5, lhi = (c >> 3) & 3, mt = row >> 4, l15 = row & 15;
  const float* sp = s + (size_t)row * C + c;
  float4 a = *(const float4*)(sp);
  float4 b = *(const float4*)(sp + 4);
  sh8 u;
  u[0] = (short)f2b(a.x); u[1] = (short)f2b(a.y);
  u[2] = (short)f2b(a.z); u[3] = (short)f2b(a.w);
  u[4] = (short)f2b(b.x); u[5] = (short)f2b(b.y);
  u[6] = (short)f2b(b.z); u[7] = (short)f2b(b.w);
  *(sh8*)(d + ((size_t)(mt * (C / 32) + ks) * 64 + lhi * 16 + l15) * 8) = u;
}

// FFN weights [O][Ci][3] fp32 -> 3 tap planes, each fragment-tiled bf16.
__global__ __launch_bounds__(256) void cvt_ffn_tiled(
    const float* __restrict__ s1, const float* __restrict__ s2,
    unsigned short* __restrict__ d1, unsigned short* __restrict__ d2)
{
  const int z = blockIdx.y;
  const float* src = z ? s2 : s1;
  unsigned short* dst = z ? d2 : d1;
  const int O  = z ? C : FF;
  const int Ci = z ? FF : C;
  const int flat = blockIdx.x * 256 + threadIdx.x;   // over O*Ci/8
  const int row = flat / (Ci / 8);
  const int c   = (flat % (Ci / 8)) * 8;
  const int ks = c >> 5, lhi = (c >> 3) & 3, mt = row >> 4, l15 = row & 15;
  const float* sp = src + ((size_t)row * Ci + c) * 3;
  float f[24];
#pragma unroll
  for (int i = 0; i < 6; ++i) {
    float4 t4 = *(const float4*)(sp + i * 4);
    f[i * 4 + 0] = t4.x; f[i * 4 + 1] = t4.y; f[i * 4 + 2] = t4.z; f[i * 4 + 3] = t4.w;
  }
  const size_t fragoff =
      ((size_t)(mt * (Ci / 32) + ks) * 64 + lhi * 16 + l15) * 8;
#pragma unroll
  for (int tap = 0; tap < 3; ++tap) {
    sh8 u;
#pragma unroll
    for (int j = 0; j < 8; ++j) u[j] = (short)f2b(f[j * 3 + tap]);
    *(sh8*)(dst + (size_t)tap * O * Ci + fragoff) = u;
  }
}

// ---------------------------------------------------------------------------
// MFMA conv/GEMM, bf16 operands, fragment-tiled weights.
// out[b,o,t] = sum_{c,kk} w[kk][o][c] * in[b,c,t+kk-HP] (+bias)
// BM=128 x BN=64, BK=32; 4 waves 2x2 (each 64x32). A staged one
// global_load_lds_dwordx4 per 16x32 fragment tile (linear, conflict-free).
// KSPLIT>1: blockIdx.z = b*KSPLIT+kk, fp32 atomicAdd epilogue.
template <int TAPS, int KSPLIT, bool GELU, bool MASK_IN, bool MASK_OUT, bool OBF16>
__global__ __launch_bounds__(256) void mfma_conv(
    const unsigned short* __restrict__ xin,        // bf16 [B][Cin][T]
    const unsigned short* __restrict__ w0p, const unsigned short* __restrict__ w1p,
    const unsigned short* __restrict__ w2p,        // tiled bf16 per plane
    const float* __restrict__ b0, const float* __restrict__ b1,
    const float* __restrict__ b2,
    const float* __restrict__ mask,                // [B][T]
    void* __restrict__ o0p, void* __restrict__ o1p, void* __restrict__ o2p,
    int Cin, int O, int tilesPerPlane)
{
  constexpr int BN = 64;
  constexpr int ROWS_B = BN + TAPS - 1;
  constexpr int PB = 40;
  constexpr bool SPLIT = (KSPLIT > 1);
  __shared__ unsigned short Aw[TAPS * 8 * 512];
  __shared__ unsigned short Bx[ROWS_B * PB];

  const int zz = blockIdx.z;
  const int b  = SPLIT ? zz / KSPLIT : zz;
  const int kk = SPLIT ? zz % KSPLIT : 0;
  const int TOFF = (TAPS == 3) ? -1 : 0;
  const int t0 = blockIdx.x * BN;
  const int plane = blockIdx.y / tilesPerPlane;
  const int mt0 = (blockIdx.y % tilesPerPlane) * 8;
  const int o0 = mt0 * 16;

  const int tid = threadIdx.x;
  const int lane = tid & 63, wid = tid >> 6;
  const int wm = wid >> 1, wn = wid & 1;
  const int l15 = lane & 15, lhi = lane >> 4;
  const size_t xbase = (size_t)b * Cin * T;
  const int bmask = b * T;

  const unsigned short* wsel = plane == 0 ? w0p : (plane == 1 ? w1p : w2p);
  const float* bp = plane == 0 ? b0 : (plane == 1 ? b1 : b2);

  const int KST = Cin >> 5;
  const int kchunk = KST / KSPLIT;
  const int ks0 = kk * kchunk, ks1 = ks0 + kchunk;
  const int OT = O >> 4;

  f32x4 acc[4][2] = {};

  for (int ks = ks0; ks < ks1; ++ks) {
    __syncthreads();
    // ---- stage A: one async 1024B burst per 16x32 fragment tile ----
#pragma unroll
    for (int tap = 0; tap < TAPS; ++tap) {
#pragma unroll
      for (int j = 0; j < 2; ++j) {
        const int rt = wid * 2 + j;
        const unsigned short* src =
            wsel + (((size_t)tap * OT + mt0 + rt) * KST + ks) * 512 + lane * 8;
        gload_lds16(src, &Aw[(tap * 8 + rt) * 512]);
      }
    }
    // ---- stage B: transposed bf16 [t][c], pitch-40 ----
    {
      const int c8 = (tid >> 6) << 3;
      const int c0 = ks << 5;
      for (int rr = tid & 63; rr < ROWS_B; rr += 64) {
        const int tsrc = t0 + rr + TOFF;
        sh8 u = (sh8)0;
        if ((unsigned)tsrc < (unsigned)T) {
          const unsigned short* xp = xin + xbase + (size_t)(c0 + c8) * T + tsrc;
          if (MASK_IN) {
            const float mk = mask[bmask + tsrc];
#pragma unroll
            for (int j = 0; j < 8; ++j)
              u[j] = (short)f2b(b2f(xp[(size_t)j * T]) * mk);
          } else {
#pragma unroll
            for (int j = 0; j < 8; ++j) u[j] = (short)xp[(size_t)j * T];
          }
        }
        *(sh8*)&Bx[rr * PB + c8] = u;
      }
    }
    __syncthreads();
    // ---- MFMA ----
#pragma unroll
    for (int tap = 0; tap < TAPS; ++tap) {
      sh8 af[4], bfr[2];
#pragma unroll
      for (int m = 0; m < 4; ++m)
        af[m] = *(const sh8*)&Aw[(tap * 8 + wm * 4 + m) * 512 + lane * 8];
#pragma unroll
      for (int n = 0; n < 2; ++n)
        bfr[n] = *(const sh8*)&Bx[(wn * 32 + n * 16 + l15 + tap) * PB + lhi * 8];
#pragma unroll
      for (int m = 0; m < 4; ++m)
#pragma unroll
        for (int n = 0; n < 2; ++n)
          acc[m][n] = __builtin_amdgcn_mfma_f32_16x16x32_bf16(
              af[m], bfr[n], acc[m][n], 0, 0, 0);
    }
  }

  // ---- epilogue ----
  void* obase = plane == 0 ? o0p : (plane == 1 ? o1p : o2p);
  float* opf = (float*)obase + (size_t)b * O * T;
  unsigned short* oph = (unsigned short*)obase + (size_t)b * O * T;
#pragma unroll
  for (int m = 0; m < 4; ++m) {
    const int o = o0 + (wm * 4 + m) * 16 + (lhi << 2);
#pragma unroll
    for (int n = 0; n < 2; ++n) {
      const int t = t0 + wn * 32 + n * 16 + l15;
      const float mk = MASK_OUT ? mask[bmask + t] : 1.f;
#pragma unroll
      for (int r = 0; r < 4; ++r) {
        float v = acc[m][n][r];
        if (SPLIT) {
          if (kk == 0) v += bp[o + r];
        } else {
          v += bp[o + r];
        }
        if (GELU) v = gelu_exact(v);
        if (MASK_OUT) v *= mk;
        if constexpr (OBF16) {
          oph[(size_t)(o + r) * T + t] = f2b(v);
        } else if constexpr (SPLIT) {
          atomicAdd(&opf[(size_t)(o + r) * T + t], v);
        } else {
          opf[(size_t)(o + r) * T + t] = v;
        }
      }
    }
  }
}

// ---------------------------------------------------------------------------
// Fused attention (unchanged; bf16 in/out).
__global__ __launch_bounds__(256) void fused_attn(
    const unsigned short* __restrict__ qg,  // [B][C][T] bf16
    const unsigned short* __restrict__ kg,
    const unsigned short* __restrict__ vg,
    const float* __restrict__ mask,         // [B][T]
    const float* __restrict__ ek,           // [D][9]
    const float* __restrict__ ev,           // [D][9]
    unsigned short* __restrict__ outp)      // [B][C][T] bf16
{
  constexpr int PITCH = 72;
  __shared__ unsigned short Qs[64 * PITCH];
  __shared__ unsigned short Ks[64 * PITCH];
  __shared__ unsigned short Vs[64 * PITCH];
  __shared__ unsigned short Ps[64 * PITCH];
  __shared__ float eks[D * 9], evs[D * 9];
  __shared__ float qekl[64 * 12];
  __shared__ float mks[64];

  const int t0 = blockIdx.x * 64;
  const int bh = blockIdx.y;
  const int b = bh / H, h = bh % H;
  const int tid = threadIdx.x;
  const int lane = tid & 63, w = tid >> 6;
  const int l15 = lane & 15, lhi = lane >> 4;

  const size_t hoff = ((size_t)b * C + h * D) * T;
  const unsigned short* qh = qg + hoff;
  const unsigned short* kh = kg + hoff;
  const unsigned short* vh = vg + hoff;

  for (int e = tid; e < D * 9; e += 256) { eks[e] = ek[e]; evs[e] = ev[e]; }
  {
    const int tl = tid & 63, d0 = (tid >> 6) << 4;
    sh8 u0, u1;
#pragma unroll
    for (int j = 0; j < 8; ++j)
      u0[j] = (short)f2b(0.125f * b2f(qh[(size_t)(d0 + j) * T + t0 + tl]));
#pragma unroll
    for (int j = 0; j < 8; ++j)
      u1[j] = (short)f2b(0.125f * b2f(qh[(size_t)(d0 + 8 + j) * T + t0 + tl]));
    *(sh8*)&Qs[tl * PITCH + d0] = u0;
    *(sh8*)&Qs[tl * PITCH + d0 + 8] = u1;
  }
  __syncthreads();
  {
    const int tl = tid & 63, g = tid >> 6;
    for (int j = g; j < 9; j += 4) {
      float a = 0.f;
      for (int d = 0; d < D; ++d)
        a = fmaf(b2f(Qs[tl * PITCH + d]), eks[d * 9 + j], a);
      qekl[tl * 12 + j] = a;
    }
  }
  const int t_loc = w * 16 + l15;
  const int t = t0 + t_loc;
  const float mask_t = mask[b * T + t];
  const sh8 bq0 = *(const sh8*)&Qs[t_loc * PITCH + lhi * 8];
  const sh8 bq1 = *(const sh8*)&Qs[t_loc * PITCH + 32 + lhi * 8];

  float m_run = -1e30f, l_run = 0.f;
  f32x4 oacc[4] = {};

  for (int s0 = 0; s0 < T; s0 += 64) {
    __syncthreads();
    {
      const int sl = tid & 63;
#pragma unroll
      for (int cc = 0; cc < 2; ++cc) {
        const int d0 = (((tid >> 6) << 1) + cc) << 3;
        sh8 u;
#pragma unroll
        for (int j = 0; j < 8; ++j)
          u[j] = (short)kh[(size_t)(d0 + j) * T + s0 + sl];
        *(sh8*)&Ks[sl * PITCH + d0] = u;
      }
    }
    {
#pragma unroll
      for (int cc = 0; cc < 2; ++cc) {
        const int idx = tid + (cc << 8);
        const int dr = idx >> 3, ch = (idx & 7) << 3;
        sh8 u = *(const sh8*)&vh[(size_t)dr * T + s0 + ch];
        *(sh8*)&Vs[dr * PITCH + ch] = u;
      }
    }
    if (tid < 64) mks[tid] = mask[b * T + s0 + tid];
    __syncthreads();

    float p[16];
#pragma unroll
    for (int n = 0; n < 4; ++n) {
      const sh8 a0 = *(const sh8*)&Ks[(n * 16 + l15) * PITCH + lhi * 8];
      const sh8 a1 = *(const sh8*)&Ks[(n * 16 + l15) * PITCH + 32 + lhi * 8];
      f32x4 acc = {};
      acc = __builtin_amdgcn_mfma_f32_16x16x32_bf16(a0, bq0, acc, 0, 0, 0);
      acc = __builtin_amdgcn_mfma_f32_16x16x32_bf16(a1, bq1, acc, 0, 0, 0);
#pragma unroll
      for (int r = 0; r < 4; ++r) {
        const int s = s0 + n * 16 + lhi * 4 + r;
        float v = acc[r];
        const int j = s - t + 4;
        if ((unsigned)j < 9u) v += qekl[t_loc * 12 + j];
        if (mask_t * mks[s - s0] == 0.f) v = -10000.0f;
        p[n * 4 + r] = v;
      }
    }
    float mloc = p[0];
#pragma unroll
    for (int i = 1; i < 16; ++i) mloc = fmaxf(mloc, p[i]);
    mloc = fmaxf(mloc, __shfl_xor(mloc, 16));
    mloc = fmaxf(mloc, __shfl_xor(mloc, 32));
    const float m_new = fmaxf(m_run, mloc);
    const float f = __expf(m_run - m_new);
    float sloc = 0.f;
#pragma unroll
    for (int i = 0; i < 16; ++i) { p[i] = __expf(p[i] - m_new); sloc += p[i]; }
    sloc += __shfl_xor(sloc, 16);
    sloc += __shfl_xor(sloc, 32);
    l_run = l_run * f + sloc;
    m_run = m_new;
#pragma unroll
    for (int m = 0; m < 4; ++m)
#pragma unroll
      for (int r = 0; r < 4; ++r) oacc[m][r] *= f;
#pragma unroll
    for (int n = 0; n < 4; ++n) {
      uint2 pk;
      pk.x = (unsigned)f2b(p[n * 4 + 0]) | ((unsigned)f2b(p[n * 4 + 1]) << 16);
      pk.y = (unsigned)f2b(p[n * 4 + 2]) | ((unsigned)f2b(p[n * 4 + 3]) << 16);
      *(uint2*)&Ps[t_loc * PITCH + n * 16 + lhi * 4] = pk;
    }
    asm volatile("s_waitcnt lgkmcnt(0)" ::: "memory");
    const sh8 bp0 = *(const sh8*)&Ps[t_loc * PITCH + lhi * 8];
    const sh8 bp1 = *(const sh8*)&Ps[t_loc * PITCH + 32 + lhi * 8];
#pragma unroll
    for (int m = 0; m < 4; ++m) {
      const sh8 a0 = *(const sh8*)&Vs[(m * 16 + l15) * PITCH + lhi * 8];
      const sh8 a1 = *(const sh8*)&Vs[(m * 16 + l15) * PITCH + 32 + lhi * 8];
      oacc[m] = __builtin_amdgcn_mfma_f32_16x16x32_bf16(a0, bp0, oacc[m], 0, 0, 0);
      oacc[m] = __builtin_amdgcn_mfma_f32_16x16x32_bf16(a1, bp1, oacc[m], 0, 0, 0);
    }
    if (t + 4 >= s0 && t < s0 + 68) {
#pragma unroll
      for (int j = 0; j < 9; ++j) {
        const int s = t + j - 4;
        if (s >= s0 && s < s0 + 64) {
          const float pv = b2f(Ps[t_loc * PITCH + (s - s0)]);
#pragma unroll
          for (int m = 0; m < 4; ++m)
#pragma unroll
            for (int r = 0; r < 4; ++r)
              oacc[m][r] = fmaf(pv, evs[(m * 16 + lhi * 4 + r) * 9 + j], oacc[m][r]);
        }
      }
    }
  }
  const float invl = 1.f / l_run;
  unsigned short* ob = outp + ((size_t)b * C + h * D) * T + t;
#pragma unroll
  for (int m = 0; m < 4; ++m)
#pragma unroll
    for (int r = 0; r < 4; ++r)
      ob[(size_t)(m * 16 + lhi * 4 + r) * T] = f2b(oacc[m][r] * invl);
}

// ---------------------------------------------------------------------------
// dst = LayerNorm_C(x + y) (+mask); also emits bf16 copy for conv inputs.
template <bool MASK_OUT>
__global__ __launch_bounds__(256) void add_norm_kernel(
    const float* x, const float* y,
    const float* __restrict__ g, const float* __restrict__ bta,
    const float* __restrict__ mask, float* dst, unsigned short* dsth)
{
  const int b = blockIdx.y;
  const int t0 = blockIdx.x * 16;
  const int r = threadIdx.x >> 4, tc = threadIdx.x & 15;
  const int t = t0 + tc;
  const float* xb = x + (size_t)b * C * T;
  const float* yb = y + (size_t)b * C * T;
  float sum = 0.f, sq = 0.f;
  for (int ci = r; ci < C; ci += 16) {
    float v = xb[(size_t)ci * T + t] + yb[(size_t)ci * T + t];
    sum += v;
    sq = fmaf(v, v, sq);
  }
  __shared__ float ssum[16][17], ssq[16][17];
  __shared__ float mean_s[16], rstd_s[16];
  ssum[r][tc] = sum;
  ssq[r][tc] = sq;
  __syncthreads();
  if (r == 0) {
    float s = 0.f, q2 = 0.f;
#pragma unroll
    for (int i = 0; i < 16; ++i) { s += ssum[i][tc]; q2 += ssq[i][tc]; }
    const float m = s / C;
    mean_s[tc] = m;
    rstd_s[tc] = rsqrtf(q2 / C - m * m + 1e-5f);
  }
  __syncthreads();
  const float m = mean_s[tc], rs = rstd_s[tc];
  const float mk = MASK_OUT ? mask[b * T + t] : 1.f;
  float* db = dst + (size_t)b * C * T;
  unsigned short* dbh = dsth + (size_t)b * C * T;
  for (int ci = r; ci < C; ci += 16) {
    float v = xb[(size_t)ci * T + t] + yb[(size_t)ci * T + t];
    float o = (v - m) * rs * g[ci] + bta[ci];
    if (MASK_OUT) o *= mk;
    db[(size_t)ci * T + t] = o;
    dbh[(size_t)ci * T + t] = f2b(o);
  }
}

}  // namespace

extern "C" void kernel_launch(void* const* d_in, const int* in_sizes, int n_in,
                              void* d_out, int out_size, void* d_ws, size_t ws_size,
                              hipStream_t stream) {
  const float* x_in = (const float*)d_in[0];
  const float* mask = (const float*)d_in[1];
  const float* Wq = (const float*)d_in[2];
  const float* bq = (const float*)d_in[3];
  const float* Wk = (const float*)d_in[4];
  const float* bk = (const float*)d_in[5];
  const float* Wv = (const float*)d_in[6];
  const float* bv = (const float*)d_in[7];
  const float* Wo = (const float*)d_in[8];
  const float* bo = (const float*)d_in[9];
  const float* ek = (const float*)d_in[10];
  const float* ev = (const float*)d_in[11];
  const float* w1 = (const float*)d_in[12];
  const float* b1 = (const float*)d_in[13];
  const float* w2 = (const float*)d_in[14];
  const float* b2 = (const float*)d_in[15];
  const float* n1g = (const float*)d_in[16];
  const float* n1b = (const float*)d_in[17];
  const float* n2g = (const float*)d_in[18];
  const float* n2b = (const float*)d_in[19];

  float* ws = (float*)d_ws;
  const size_t SZ_X = (size_t)B * C * T;          // 1,572,864
  float* yb = ws;
  float* xb = yb + SZ_X;
  unsigned short* xbh = (unsigned short*)(xb + SZ_X);   // conv-input bf16
  unsigned short* qbh = xbh + SZ_X;
  unsigned short* kbh = qbh + SZ_X;
  unsigned short* vbh = kbh + SZ_X;
  unsigned short* hidh = vbh + SZ_X;                    // B*FF*T
  unsigned short* w1t = hidh + (size_t)B * FF * T;      // [3][FF*C] tiled
  unsigned short* w2t = w1t + (size_t)3 * FF * C;       // [3][C*FF] tiled
  unsigned short* wqt = w2t + (size_t)3 * FF * C;       // [C*C] tiled
  unsigned short* wkt = wqt + (size_t)C * C;
  unsigned short* wvt = wkt + (size_t)C * C;
  unsigned short* wot = wvt + (size_t)C * C;
  float* outp = (float*)d_out;

  const dim3 blk(256);
  cvt_flat8<<<dim3(SZ_X / 2048), blk, 0, stream>>>(x_in, xbh);

  for (int i = 0; i < NL; ++i) {
    const float* xs = (i == 0) ? x_in : xb;
    const size_t wOff = (size_t)i * C * C;
    // weights -> bf16 fragment-tiled
    cvt_qkvo_tiled<<<dim3((C * C / 8) / 256, 4), blk, 0, stream>>>(
        Wq + wOff, Wk + wOff, Wv + wOff, Wo + wOff, wqt, wkt, wvt, wot);
    cvt_ffn_tiled<<<dim3((FF * C / 8) / 256, 2), blk, 0, stream>>>(
        w1 + (size_t)i * FF * C * 3, w2 + (size_t)i * C * FF * 3, w1t, w2t);
    // fused QKV projection -> bf16 q,k,v   (576 blocks)
    mfma_conv<1, 1, false, false, false, true>
        <<<dim3(8, 18, B), blk, 0, stream>>>(
        xbh, wqt, wkt, wvt, bq + i * C, bk + i * C, bv + i * C, mask,
        qbh, kbh, vbh, C, C, 6);
    // fused attention -> bf16
    fused_attn<<<dim3(T / 64, B * H), blk, 0, stream>>>(
        qbh, kbh, vbh, mask, ek + (size_t)i * D * 9, ev + (size_t)i * D * 9, hidh);
    // output projection: split-K2 atomic   (384 blocks)
    hipMemsetAsync(yb, 0, SZ_X * sizeof(float), stream);
    mfma_conv<1, 2, false, false, false, false>
        <<<dim3(8, 6, B * 2), blk, 0, stream>>>(
        hidh, wot, wot, wot, bo + i * C, bo + i * C, bo + i * C, mask,
        yb, yb, yb, C, C, 6);
    add_norm_kernel<false><<<dim3(T / 16, B), blk, 0, stream>>>(
        xs, yb, n1g + i * C, n1b + i * C, mask, xb, xbh);
    // FFN up: C->FF, 3 taps in-loop, GELU, bf16 out   (768 blocks)
    mfma_conv<3, 1, true, true, false, true>
        <<<dim3(8, 24, B), blk, 0, stream>>>(
        xbh, w1t, w1t, w1t, b1 + i * FF, b1 + i * FF, b1 + i * FF, mask,
        hidh, hidh, hidh, C, FF, 24);
    // FFN down: FF->C, 3 taps in-loop, split-K4 atomic   (768 blocks)
    hipMemsetAsync(yb, 0, SZ_X * sizeof(float), stream);
    mfma_conv<3, 4, false, true, true, false>
        <<<dim3(8, 6, B * 4), blk, 0, stream>>>(
        hidh, w2t, w2t, w2t, b2 + i * C, b2 + i * C, b2 + i * C, mask,
        yb, yb, yb, FF, C, 6);
    add_norm_kernel<true><<<dim3(T / 16, B), blk, 0, stream>>>(
        xb, yb, n2g + i * C, n2b + i * C, mask, (i == NL - 1) ? outp : xb, xbh);
  }
}

// Round 6
// 1594.691 us; speedup vs baseline: 1.4275x; 1.1571x over previous
//
#include <hip/hip_runtime.h>
#include <cstddef>

namespace {

constexpr int B  = 4;
constexpr int C  = 768;
constexpr int T  = 512;
constexpr int H  = 12;
constexpr int D  = 64;
constexpr int NL = 6;
constexpr int W  = 4;
constexpr int FF = 3072;

typedef __attribute__((ext_vector_type(8))) short sh8;
typedef __attribute__((ext_vector_type(4))) float f32x4;

__device__ inline float gelu_exact(float x) {
  return 0.5f * x * (1.0f + erff(x * 0.70710678118654752440f));
}
__device__ inline unsigned short f2b(float f) {
  unsigned u = __float_as_uint(f);
  unsigned r = (u + 0x7fffu + ((u >> 16) & 1u)) >> 16;
  return (unsigned short)r;
}
__device__ inline float b2f(unsigned short u) {
  return __uint_as_float((unsigned)u << 16);
}
__device__ inline void gload_lds16(const void* g, void* l) {
  __builtin_amdgcn_global_load_lds(
      (const __attribute__((address_space(1))) unsigned int*)g,
      (__attribute__((address_space(3))) unsigned int*)l, 16, 0, 0);
}

// ---------------------------------------------------------------------------
// Layer-0 input: x [B][C][T] fp32 -> [B][T][C] bf16 (tiled transpose)
__global__ __launch_bounds__(256) void transpose_cvt(
    const float* __restrict__ s, unsigned short* __restrict__ d)
{
  __shared__ unsigned short tile[32][33];
  const int b = blockIdx.z;
  const int c0 = blockIdx.y * 32, t0 = blockIdx.x * 32;
  const int tx = threadIdx.x & 31, ty = threadIdx.x >> 5;
  const float* sp = s + ((size_t)b * C + c0) * T + t0;
#pragma unroll
  for (int i = 0; i < 4; ++i)
    tile[ty + i * 8][tx] = f2b(sp[(size_t)(ty + i * 8) * T + tx]);
  __syncthreads();
  unsigned short* dp = d + ((size_t)b * T + t0) * C + c0;
#pragma unroll
  for (int i = 0; i < 4; ++i)
    dp[(size_t)(ty + i * 8) * C + tx] = tile[tx][ty + i * 8];
}

// QKVO weights fp32 [C][C] -> bf16 MFMA-fragment-tiled
__global__ __launch_bounds__(256) void cvt_qkvo_tiled(
    const float* __restrict__ q, const float* __restrict__ k,
    const float* __restrict__ v, const float* __restrict__ o,
    unsigned short* __restrict__ dq, unsigned short* __restrict__ dk,
    unsigned short* __restrict__ dv, unsigned short* __restrict__ dov)
{
  const int z = blockIdx.y;
  const float* s = z == 0 ? q : z == 1 ? k : z == 2 ? v : o;
  unsigned short* d = z == 0 ? dq : z == 1 ? dk : z == 2 ? dv : dov;
  const int flat = blockIdx.x * 256 + threadIdx.x;   // over C*C/8
  const int row = flat / (C / 8);
  const int c   = (flat % (C / 8)) * 8;
  const int ks = c >> 5, lhi = (c >> 3) & 3, mt = row >> 4, l15 = row & 15;
  const float* sp = s + (size_t)row * C + c;
  float4 a = *(const float4*)(sp);
  float4 b = *(const float4*)(sp + 4);
  sh8 u;
  u[0] = (short)f2b(a.x); u[1] = (short)f2b(a.y);
  u[2] = (short)f2b(a.z); u[3] = (short)f2b(a.w);
  u[4] = (short)f2b(b.x); u[5] = (short)f2b(b.y);
  u[6] = (short)f2b(b.z); u[7] = (short)f2b(b.w);
  *(sh8*)(d + ((size_t)(mt * (C / 32) + ks) * 64 + lhi * 16 + l15) * 8) = u;
}

// FFN weights [O][Ci][3] fp32 -> 3 tap planes, each fragment-tiled bf16.
__global__ __launch_bounds__(256) void cvt_ffn_tiled(
    const float* __restrict__ s1, const float* __restrict__ s2,
    unsigned short* __restrict__ d1, unsigned short* __restrict__ d2)
{
  const int z = blockIdx.y;
  const float* src = z ? s2 : s1;
  unsigned short* dst = z ? d2 : d1;
  const int O  = z ? C : FF;
  const int Ci = z ? FF : C;
  const int flat = blockIdx.x * 256 + threadIdx.x;   // over O*Ci/8
  const int row = flat / (Ci / 8);
  const int c   = (flat % (Ci / 8)) * 8;
  const int ks = c >> 5, lhi = (c >> 3) & 3, mt = row >> 4, l15 = row & 15;
  const float* sp = src + ((size_t)row * Ci + c) * 3;
  float f[24];
#pragma unroll
  for (int i = 0; i < 6; ++i) {
    float4 t4 = *(const float4*)(sp + i * 4);
    f[i * 4 + 0] = t4.x; f[i * 4 + 1] = t4.y; f[i * 4 + 2] = t4.z; f[i * 4 + 3] = t4.w;
  }
  const size_t fragoff =
      ((size_t)(mt * (Ci / 32) + ks) * 64 + lhi * 16 + l15) * 8;
#pragma unroll
  for (int tap = 0; tap < 3; ++tap) {
    sh8 u;
#pragma unroll
    for (int j = 0; j < 8; ++j) u[j] = (short)f2b(f[j * 3 + tap]);
    *(sh8*)(dst + (size_t)tap * O * Ci + fragoff) = u;
  }
}

// ---------------------------------------------------------------------------
// MFMA conv/GEMM. Input t-major bf16 [B][T][Cin]; weights fragment-tiled.
// out[b,o,t] = sum_{c,kk} w[kk][o][c] * in[b,t+kk-HP,c] (+bias)
// BM=128 x BN=64, BK=32; 4 waves 2x2. A: global_load_lds dwordx4 per frag tile.
// B: one dwordx4 + ds_write_b128 per thread per K-step (pitch-40 LDS).
// OBF16: bf16 t-major [B][T][O] out. Else fp32 partials [KSPLIT][B][T][O],
// slice kk non-atomic; bias added on kk==0; summed later in add_norm.
template <int TAPS, int KSPLIT, bool GELU, bool MASK_OUT, bool OBF16>
__global__ __launch_bounds__(256) void mfma_conv(
    const unsigned short* __restrict__ xin,
    const unsigned short* __restrict__ w0p, const unsigned short* __restrict__ w1p,
    const unsigned short* __restrict__ w2p,
    const float* __restrict__ b0, const float* __restrict__ b1,
    const float* __restrict__ b2,
    const float* __restrict__ mask,                // [B][T]
    void* __restrict__ o0p, void* __restrict__ o1p, void* __restrict__ o2p,
    int Cin, int O, int tilesPerPlane)
{
  constexpr int BN = 64;
  constexpr int ROWS_B = BN + TAPS - 1;
  constexpr int PB = 40;
  __shared__ unsigned short Aw[TAPS * 8 * 512];
  __shared__ unsigned short Bx[ROWS_B * PB];

  const int zz = blockIdx.z;
  const int b  = zz / KSPLIT;
  const int kk = zz % KSPLIT;
  const int TOFF = (TAPS == 3) ? -1 : 0;
  const int t0 = blockIdx.x * BN;
  const int plane = blockIdx.y / tilesPerPlane;
  const int mt0 = (blockIdx.y % tilesPerPlane) * 8;
  const int o0 = mt0 * 16;

  const int tid = threadIdx.x;
  const int lane = tid & 63, wid = tid >> 6;
  const int wm = wid >> 1, wn = wid & 1;
  const int l15 = lane & 15, lhi = lane >> 4;
  const int bmask = b * T;

  const unsigned short* wsel = plane == 0 ? w0p : (plane == 1 ? w1p : w2p);
  const float* bp = plane == 0 ? b0 : (plane == 1 ? b1 : b2);

  const int KST = Cin >> 5;
  const int kchunk = KST / KSPLIT;
  const int ks0 = kk * kchunk, ks1 = ks0 + kchunk;
  const int OT = O >> 4;

  const int brow = tid >> 2, bcl = (tid & 3) << 3;
  const unsigned short* xb_ = xin + (size_t)b * T * Cin;

  f32x4 acc[4][2] = {};

  for (int ks = ks0; ks < ks1; ++ks) {
    __syncthreads();
    // ---- stage A: one async 1024B burst per 16x32 fragment tile ----
#pragma unroll
    for (int tap = 0; tap < TAPS; ++tap) {
#pragma unroll
      for (int j = 0; j < 2; ++j) {
        const int rt = wid * 2 + j;
        const unsigned short* src =
            wsel + (((size_t)tap * OT + mt0 + rt) * KST + ks) * 512 + lane * 8;
        gload_lds16(src, &Aw[(tap * 8 + rt) * 512]);
      }
    }
    // ---- stage B: vectorized t-major reads, padded LDS rows ----
    {
      const int c0 = ks << 5;
      const unsigned short* xrow = xb_ + c0 + bcl;
      const int tsrc = t0 + brow + TOFF;
      sh8 u = (sh8)0;
      if ((unsigned)tsrc < (unsigned)T)
        u = *(const sh8*)(xrow + (size_t)tsrc * Cin);
      *(sh8*)&Bx[brow * PB + bcl] = u;
      if constexpr (TAPS == 3) {
        if (tid < 8) {
          const int r2 = 64 + (tid >> 2);
          const int ts2 = t0 + r2 + TOFF;
          sh8 u2 = (sh8)0;
          if ((unsigned)ts2 < (unsigned)T)
            u2 = *(const sh8*)(xrow + (size_t)ts2 * Cin);
          *(sh8*)&Bx[r2 * PB + bcl] = u2;
        }
      }
    }
    __syncthreads();
    // ---- MFMA ----
#pragma unroll
    for (int tap = 0; tap < TAPS; ++tap) {
      sh8 af[4], bfr[2];
#pragma unroll
      for (int m = 0; m < 4; ++m)
        af[m] = *(const sh8*)&Aw[(tap * 8 + wm * 4 + m) * 512 + lane * 8];
#pragma unroll
      for (int n = 0; n < 2; ++n)
        bfr[n] = *(const sh8*)&Bx[(wn * 32 + n * 16 + l15 + tap) * PB + lhi * 8];
#pragma unroll
      for (int m = 0; m < 4; ++m)
#pragma unroll
        for (int n = 0; n < 2; ++n)
          acc[m][n] = __builtin_amdgcn_mfma_f32_16x16x32_bf16(
              af[m], bfr[n], acc[m][n], 0, 0, 0);
    }
  }

  // ---- epilogue (t-major outputs) ----
  void* obase = plane == 0 ? o0p : (plane == 1 ? o1p : o2p);
  unsigned short* oph = (unsigned short*)obase + (size_t)b * T * O;
  float* opf = (float*)obase + ((size_t)kk * B + b) * (size_t)T * O;
#pragma unroll
  for (int m = 0; m < 4; ++m) {
    const int o = o0 + (wm * 4 + m) * 16 + (lhi << 2);
#pragma unroll
    for (int n = 0; n < 2; ++n) {
      const int t = t0 + wn * 32 + n * 16 + l15;
      const float mk = MASK_OUT ? mask[bmask + t] : 1.f;
      float v[4];
#pragma unroll
      for (int r = 0; r < 4; ++r) {
        float x = acc[m][n][r];
        if (KSPLIT > 1) {
          if (kk == 0) x += bp[o + r];
        } else {
          x += bp[o + r];
        }
        if (GELU) x = gelu_exact(x);
        if (MASK_OUT) x *= mk;
        v[r] = x;
      }
      if constexpr (OBF16) {
        ushort4 hz;
        hz.x = f2b(v[0]); hz.y = f2b(v[1]); hz.z = f2b(v[2]); hz.w = f2b(v[3]);
        *(ushort4*)(oph + (size_t)t * O + o) = hz;
      } else {
        *(float4*)(opf + (size_t)t * O + o) = make_float4(v[0], v[1], v[2], v[3]);
      }
    }
  }
}

// ---------------------------------------------------------------------------
// Fused attention. q/k/v t-major bf16 [B][T][C]; out t-major bf16 [B][T][C].
__global__ __launch_bounds__(256) void fused_attn(
    const unsigned short* __restrict__ qg,
    const unsigned short* __restrict__ kg,
    const unsigned short* __restrict__ vg,
    const float* __restrict__ mask,         // [B][T]
    const float* __restrict__ ek,           // [D][9]
    const float* __restrict__ ev,           // [D][9]
    unsigned short* __restrict__ outp)      // [B][T][C] bf16
{
  constexpr int PITCH = 72;
  __shared__ unsigned short Qs[64 * PITCH];  // [t][d] raw
  __shared__ unsigned short Ks[64 * PITCH];  // [s][d]
  __shared__ unsigned short Vs[64 * PITCH];  // [d][s]
  __shared__ unsigned short Ps[64 * PITCH];  // [t][s]
  __shared__ float eks[D * 9], evs[D * 9];
  __shared__ float qekl[64 * 12];
  __shared__ float mks[64];

  const int t0 = blockIdx.x * 64;
  const int bh = blockIdx.y;
  const int b = bh / H, h = bh % H;
  const int tid = threadIdx.x;
  const int lane = tid & 63, w = tid >> 6;
  const int l15 = lane & 15, lhi = lane >> 4;

  const size_t base = (size_t)b * T * C + h * D;
  const unsigned short* qh = qg + base;
  const unsigned short* kh = kg + base;
  const unsigned short* vh = vg + base;

  for (int e = tid; e < D * 9; e += 256) { eks[e] = ek[e]; evs[e] = ev[e]; }
  // stage Q [t][d] — pure vector copy (raw, scale applied later)
  {
    const int tl = tid & 63, d0 = (tid >> 6) << 4;
    const unsigned short* src = qh + (size_t)(t0 + tl) * C + d0;
    *(sh8*)&Qs[tl * PITCH + d0]     = *(const sh8*)(src);
    *(sh8*)&Qs[tl * PITCH + d0 + 8] = *(const sh8*)(src + 8);
  }
  __syncthreads();
  // rel-k logits: qekl[t][j] = 0.125 * sum_d Q[t][d] * ek[d][j]
  {
    const int tl = tid & 63, g = tid >> 6;
    for (int j = g; j < 9; j += 4) {
      float a = 0.f;
      for (int d = 0; d < D; ++d)
        a = fmaf(b2f(Qs[tl * PITCH + d]), eks[d * 9 + j], a);
      qekl[tl * 12 + j] = a * 0.125f;
    }
  }
  const int t_loc = w * 16 + l15;
  const int t = t0 + t_loc;
  const float mask_t = mask[b * T + t];
  const sh8 bq0 = *(const sh8*)&Qs[t_loc * PITCH + lhi * 8];
  const sh8 bq1 = *(const sh8*)&Qs[t_loc * PITCH + 32 + lhi * 8];

  float m_run = -1e30f, l_run = 0.f;
  f32x4 oacc[4] = {};

  for (int s0 = 0; s0 < T; s0 += 64) {
    __syncthreads();
    // stage K [s][d] — vector copy
    {
      const int sl = tid & 63, d0 = (tid >> 6) << 4;
      const unsigned short* src = kh + (size_t)(s0 + sl) * C + d0;
      *(sh8*)&Ks[sl * PITCH + d0]     = *(const sh8*)(src);
      *(sh8*)&Ks[sl * PITCH + d0 + 8] = *(const sh8*)(src + 8);
    }
    // stage V [d][s] — transpose from t-major (scalar)
    {
#pragma unroll
      for (int cc = 0; cc < 2; ++cc) {
        const int idx = tid + (cc << 8);
        const int dr = idx >> 3, s8 = (idx & 7) << 3;
        sh8 u;
#pragma unroll
        for (int j = 0; j < 8; ++j)
          u[j] = (short)vh[(size_t)(s0 + s8 + j) * C + dr];
        *(sh8*)&Vs[dr * PITCH + s8] = u;
      }
    }
    if (tid < 64) mks[tid] = mask[b * T + s0 + tid];
    __syncthreads();

    // QK^T (swapped): rows=s, cols=t; lane holds 16 s for ONE t
    float p[16];
#pragma unroll
    for (int n = 0; n < 4; ++n) {
      const sh8 a0 = *(const sh8*)&Ks[(n * 16 + l15) * PITCH + lhi * 8];
      const sh8 a1 = *(const sh8*)&Ks[(n * 16 + l15) * PITCH + 32 + lhi * 8];
      f32x4 acc = {};
      acc = __builtin_amdgcn_mfma_f32_16x16x32_bf16(a0, bq0, acc, 0, 0, 0);
      acc = __builtin_amdgcn_mfma_f32_16x16x32_bf16(a1, bq1, acc, 0, 0, 0);
#pragma unroll
      for (int r = 0; r < 4; ++r) {
        const int s = s0 + n * 16 + lhi * 4 + r;
        float v = acc[r] * 0.125f;
        const int j = s - t + 4;
        if ((unsigned)j < 9u) v += qekl[t_loc * 12 + j];
        if (mask_t * mks[s - s0] == 0.f) v = -10000.0f;
        p[n * 4 + r] = v;
      }
    }
    // online softmax
    float mloc = p[0];
#pragma unroll
    for (int i = 1; i < 16; ++i) mloc = fmaxf(mloc, p[i]);
    mloc = fmaxf(mloc, __shfl_xor(mloc, 16));
    mloc = fmaxf(mloc, __shfl_xor(mloc, 32));
    const float m_new = fmaxf(m_run, mloc);
    const float f = __expf(m_run - m_new);
    float sloc = 0.f;
#pragma unroll
    for (int i = 0; i < 16; ++i) { p[i] = __expf(p[i] - m_new); sloc += p[i]; }
    sloc += __shfl_xor(sloc, 16);
    sloc += __shfl_xor(sloc, 32);
    l_run = l_run * f + sloc;
    m_run = m_new;
#pragma unroll
    for (int m = 0; m < 4; ++m)
#pragma unroll
      for (int r = 0; r < 4; ++r) oacc[m][r] *= f;
#pragma unroll
    for (int n = 0; n < 4; ++n) {
      uint2 pk;
      pk.x = (unsigned)f2b(p[n * 4 + 0]) | ((unsigned)f2b(p[n * 4 + 1]) << 16);
      pk.y = (unsigned)f2b(p[n * 4 + 2]) | ((unsigned)f2b(p[n * 4 + 3]) << 16);
      *(uint2*)&Ps[t_loc * PITCH + n * 16 + lhi * 4] = pk;
    }
    asm volatile("s_waitcnt lgkmcnt(0)" ::: "memory");
    const sh8 bp0 = *(const sh8*)&Ps[t_loc * PITCH + lhi * 8];
    const sh8 bp1 = *(const sh8*)&Ps[t_loc * PITCH + 32 + lhi * 8];
#pragma unroll
    for (int m = 0; m < 4; ++m) {
      const sh8 a0 = *(const sh8*)&Vs[(m * 16 + l15) * PITCH + lhi * 8];
      const sh8 a1 = *(const sh8*)&Vs[(m * 16 + l15) * PITCH + 32 + lhi * 8];
      oacc[m] = __builtin_amdgcn_mfma_f32_16x16x32_bf16(a0, bp0, oacc[m], 0, 0, 0);
      oacc[m] = __builtin_amdgcn_mfma_f32_16x16x32_bf16(a1, bp1, oacc[m], 0, 0, 0);
    }
    // v-band epilogue
    if (t + 4 >= s0 && t < s0 + 68) {
#pragma unroll
      for (int j = 0; j < 9; ++j) {
        const int s = t + j - 4;
        if (s >= s0 && s < s0 + 64) {
          const float pv = b2f(Ps[t_loc * PITCH + (s - s0)]);
#pragma unroll
          for (int m = 0; m < 4; ++m)
#pragma unroll
            for (int r = 0; r < 4; ++r)
              oacc[m][r] = fmaf(pv, evs[(m * 16 + lhi * 4 + r) * 9 + j], oacc[m][r]);
        }
      }
    }
  }
  const float invl = 1.f / l_run;
  unsigned short* ob = outp + (size_t)(b * T + t) * C + h * D;
#pragma unroll
  for (int m = 0; m < 4; ++m) {
    ushort4 hz;
    hz.x = f2b(oacc[m][0] * invl);
    hz.y = f2b(oacc[m][1] * invl);
    hz.z = f2b(oacc[m][2] * invl);
    hz.w = f2b(oacc[m][3] * invl);
    *(ushort4*)(ob + m * 16 + lhi * 4) = hz;
  }
}

// ---------------------------------------------------------------------------
// dst = LayerNorm_C(x + sum_p y_p) ; y partials t-major [NP][B][T][C] fp32.
// dst fp32 [C][T] (optionally masked); dsth bf16 t-major [B][T][C] (masked).
template <int NP, bool MASKY, bool MASKF>
__global__ __launch_bounds__(256) void add_norm_kernel(
    const float* __restrict__ x, const float* __restrict__ ypart,
    const float* __restrict__ g, const float* __restrict__ bta,
    const float* __restrict__ mask, float* __restrict__ dst,
    unsigned short* __restrict__ dsth)
{
  constexpr int NQ = C / 16;  // 48
  const int b = blockIdx.y;
  const int t0 = blockIdx.x * 16;
  const int r = threadIdx.x >> 4, tc = threadIdx.x & 15;
  const int t = t0 + tc;
  const float* xb = x + (size_t)b * C * T;
  const float mkt = mask[b * T + t];
  float vv[NQ];
  float sum = 0.f, sq = 0.f;
#pragma unroll
  for (int q = 0; q < NQ; ++q) {
    const int ci = r + q * 16;
    float y = 0.f;
#pragma unroll
    for (int p = 0; p < NP; ++p)
      y += ypart[(((size_t)p * B + b) * T + t) * C + ci];
    if (MASKY) y *= mkt;
    const float v = xb[(size_t)ci * T + t] + y;
    vv[q] = v;
    sum += v;
    sq = fmaf(v, v, sq);
  }
  __shared__ float ssum[16][17], ssq[16][17];
  __shared__ float mean_s[16], rstd_s[16];
  ssum[r][tc] = sum;
  ssq[r][tc] = sq;
  __syncthreads();
  if (r == 0) {
    float s = 0.f, q2 = 0.f;
#pragma unroll
    for (int i = 0; i < 16; ++i) { s += ssum[i][tc]; q2 += ssq[i][tc]; }
    const float m = s / C;
    mean_s[tc] = m;
    rstd_s[tc] = rsqrtf(q2 / C - m * m + 1e-5f);
  }
  __syncthreads();
  const float m = mean_s[tc], rs = rstd_s[tc];
  float* db = dst + (size_t)b * C * T;
  unsigned short* dbh = dsth + ((size_t)b * T + t) * C;
#pragma unroll
  for (int q = 0; q < NQ; ++q) {
    const int ci = r + q * 16;
    float o = (vv[q] - m) * rs * g[ci] + bta[ci];
    if (MASKF) o *= mkt;
    db[(size_t)ci * T + t] = o;
    dbh[ci] = f2b(MASKF ? o : o * mkt);
  }
}

}  // namespace

extern "C" void kernel_launch(void* const* d_in, const int* in_sizes, int n_in,
                              void* d_out, int out_size, void* d_ws, size_t ws_size,
                              hipStream_t stream) {
  const float* x_in = (const float*)d_in[0];
  const float* mask = (const float*)d_in[1];
  const float* Wq = (const float*)d_in[2];
  const float* bq = (const float*)d_in[3];
  const float* Wk = (const float*)d_in[4];
  const float* bk = (const float*)d_in[5];
  const float* Wv = (const float*)d_in[6];
  const float* bv = (const float*)d_in[7];
  const float* Wo = (const float*)d_in[8];
  const float* bo = (const float*)d_in[9];
  const float* ek = (const float*)d_in[10];
  const float* ev = (const float*)d_in[11];
  const float* w1 = (const float*)d_in[12];
  const float* b1 = (const float*)d_in[13];
  const float* w2 = (const float*)d_in[14];
  const float* b2 = (const float*)d_in[15];
  const float* n1g = (const float*)d_in[16];
  const float* n1b = (const float*)d_in[17];
  const float* n2g = (const float*)d_in[18];
  const float* n2b = (const float*)d_in[19];

  float* ws = (float*)d_ws;
  const size_t SZ_X = (size_t)B * C * T;          // 1,572,864
  float* xb    = ws;                              // residual fp32 [B][C][T]
  float* ypart = xb + SZ_X;                       // [4][B][T][C] fp32 partials
  unsigned short* xbh = (unsigned short*)(ypart + 4 * SZ_X);  // QKV in [B][T][C]
  unsigned short* xfh = xbh + SZ_X;               // FFN-up in (masked)
  unsigned short* qbh = xfh + SZ_X;
  unsigned short* kbh = qbh + SZ_X;
  unsigned short* vbh = kbh + SZ_X;
  unsigned short* hidh = vbh + SZ_X;              // attn-out [B][T][C] / FFN hid [B][T][FF]
  unsigned short* w1t = hidh + (size_t)B * FF * T;
  unsigned short* w2t = w1t + (size_t)3 * FF * C;
  unsigned short* wqt = w2t + (size_t)3 * FF * C;
  unsigned short* wkt = wqt + (size_t)C * C;
  unsigned short* wvt = wkt + (size_t)C * C;
  unsigned short* wot = wvt + (size_t)C * C;
  float* outp = (float*)d_out;

  const dim3 blk(256);
  transpose_cvt<<<dim3(T / 32, C / 32, B), blk, 0, stream>>>(x_in, xbh);

  for (int i = 0; i < NL; ++i) {
    const float* xs = (i == 0) ? x_in : xb;
    const size_t wOff = (size_t)i * C * C;
    cvt_qkvo_tiled<<<dim3((C * C / 8) / 256, 4), blk, 0, stream>>>(
        Wq + wOff, Wk + wOff, Wv + wOff, Wo + wOff, wqt, wkt, wvt, wot);
    cvt_ffn_tiled<<<dim3((FF * C / 8) / 256, 2), blk, 0, stream>>>(
        w1 + (size_t)i * FF * C * 3, w2 + (size_t)i * C * FF * 3, w1t, w2t);
    // QKV projection -> bf16 t-major q,k,v   (576 blocks)
    mfma_conv<1, 1, false, false, true><<<dim3(8, 18, B), blk, 0, stream>>>(
        xbh, wqt, wkt, wvt, bq + i * C, bk + i * C, bv + i * C, mask,
        qbh, kbh, vbh, C, C, 6);
    // fused attention -> bf16 t-major
    fused_attn<<<dim3(T / 64, B * H), blk, 0, stream>>>(
        qbh, kbh, vbh, mask, ek + (size_t)i * D * 9, ev + (size_t)i * D * 9, hidh);
    // Wo projection: split-K2 -> fp32 partials   (384 blocks)
    mfma_conv<1, 2, false, false, false><<<dim3(8, 6, B * 2), blk, 0, stream>>>(
        hidh, wot, wot, wot, bo + i * C, bo + i * C, bo + i * C, mask,
        ypart, ypart, ypart, C, C, 6);
    add_norm_kernel<2, false, false><<<dim3(T / 16, B), blk, 0, stream>>>(
        xs, ypart, n1g + i * C, n1b + i * C, mask, xb, xfh);
    // FFN up: C->FF, 3 taps, GELU+mask, bf16 t-major out   (768 blocks)
    mfma_conv<3, 1, true, true, true><<<dim3(8, 24, B), blk, 0, stream>>>(
        xfh, w1t, w1t, w1t, b1 + i * FF, b1 + i * FF, b1 + i * FF, mask,
        hidh, hidh, hidh, C, FF, 24);
    // FFN down: FF->C, 3 taps, split-K4 -> fp32 partials   (768 blocks)
    mfma_conv<3, 4, false, false, false><<<dim3(8, 6, B * 4), blk, 0, stream>>>(
        hidh, w2t, w2t, w2t, b2 + i * C, b2 + i * C, b2 + i * C, mask,
        ypart, ypart, ypart, FF, C, 6);
    add_norm_kernel<4, true, true><<<dim3(T / 16, B), blk, 0, stream>>>(
        xb, ypart, n2g + i * C, n2b + i * C, mask, (i == NL - 1) ? outp : xb, xbh);
  }
}

// Round 7
// 1566.844 us; speedup vs baseline: 1.4528x; 1.0178x over previous
//
#include <hip/hip_runtime.h>
#include <cstddef>

namespace {

constexpr int B  = 4;
constexpr int C  = 768;
constexpr int T  = 512;
constexpr int H  = 12;
constexpr int D  = 64;
constexpr int NL = 6;
constexpr int W  = 4;
constexpr int FF = 3072;

typedef __attribute__((ext_vector_type(8))) short sh8;
typedef __attribute__((ext_vector_type(4))) float f32x4;

__device__ inline float gelu_exact(float x) {
  return 0.5f * x * (1.0f + erff(x * 0.70710678118654752440f));
}
__device__ inline unsigned short f2b(float f) {
  unsigned u = __float_as_uint(f);
  unsigned r = (u + 0x7fffu + ((u >> 16) & 1u)) >> 16;
  return (unsigned short)r;
}
__device__ inline float b2f(unsigned short u) {
  return __uint_as_float((unsigned)u << 16);
}
__device__ inline void gload_lds16(const void* g, void* l) {
  __builtin_amdgcn_global_load_lds(
      (const __attribute__((address_space(1))) unsigned int*)g,
      (__attribute__((address_space(3))) unsigned int*)l, 16, 0, 0);
}

// ---------------------------------------------------------------------------
// Layer-0 input: x [B][C][T] fp32 -> [B][T][C] bf16 (tiled transpose)
__global__ __launch_bounds__(256) void transpose_cvt(
    const float* __restrict__ s, unsigned short* __restrict__ d)
{
  __shared__ unsigned short tile[32][33];
  const int b = blockIdx.z;
  const int c0 = blockIdx.y * 32, t0 = blockIdx.x * 32;
  const int tx = threadIdx.x & 31, ty = threadIdx.x >> 5;
  const float* sp = s + ((size_t)b * C + c0) * T + t0;
#pragma unroll
  for (int i = 0; i < 4; ++i)
    tile[ty + i * 8][tx] = f2b(sp[(size_t)(ty + i * 8) * T + tx]);
  __syncthreads();
  unsigned short* dp = d + ((size_t)b * T + t0) * C + c0;
#pragma unroll
  for (int i = 0; i < 4; ++i)
    dp[(size_t)(ty + i * 8) * C + tx] = tile[tx][ty + i * 8];
}

// QKVO weights fp32 [C][C] -> bf16 MFMA-fragment-tiled
__global__ __launch_bounds__(256) void cvt_qkvo_tiled(
    const float* __restrict__ q, const float* __restrict__ k,
    const float* __restrict__ v, const float* __restrict__ o,
    unsigned short* __restrict__ dq, unsigned short* __restrict__ dk,
    unsigned short* __restrict__ dv, unsigned short* __restrict__ dov)
{
  const int z = blockIdx.y;
  const float* s = z == 0 ? q : z == 1 ? k : z == 2 ? v : o;
  unsigned short* d = z == 0 ? dq : z == 1 ? dk : z == 2 ? dv : dov;
  const int flat = blockIdx.x * 256 + threadIdx.x;   // over C*C/8
  const int row = flat / (C / 8);
  const int c   = (flat % (C / 8)) * 8;
  const int ks = c >> 5, lhi = (c >> 3) & 3, mt = row >> 4, l15 = row & 15;
  const float* sp = s + (size_t)row * C + c;
  float4 a = *(const float4*)(sp);
  float4 b = *(const float4*)(sp + 4);
  sh8 u;
  u[0] = (short)f2b(a.x); u[1] = (short)f2b(a.y);
  u[2] = (short)f2b(a.z); u[3] = (short)f2b(a.w);
  u[4] = (short)f2b(b.x); u[5] = (short)f2b(b.y);
  u[6] = (short)f2b(b.z); u[7] = (short)f2b(b.w);
  *(sh8*)(d + ((size_t)(mt * (C / 32) + ks) * 64 + lhi * 16 + l15) * 8) = u;
}

// FFN weights [O][Ci][3] fp32 -> 3 tap planes, each fragment-tiled bf16.
__global__ __launch_bounds__(256) void cvt_ffn_tiled(
    const float* __restrict__ s1, const float* __restrict__ s2,
    unsigned short* __restrict__ d1, unsigned short* __restrict__ d2)
{
  const int z = blockIdx.y;
  const float* src = z ? s2 : s1;
  unsigned short* dst = z ? d2 : d1;
  const int O  = z ? C : FF;
  const int Ci = z ? FF : C;
  const int flat = blockIdx.x * 256 + threadIdx.x;   // over O*Ci/8
  const int row = flat / (Ci / 8);
  const int c   = (flat % (Ci / 8)) * 8;
  const int ks = c >> 5, lhi = (c >> 3) & 3, mt = row >> 4, l15 = row & 15;
  const float* sp = src + ((size_t)row * Ci + c) * 3;
  float f[24];
#pragma unroll
  for (int i = 0; i < 6; ++i) {
    float4 t4 = *(const float4*)(sp + i * 4);
    f[i * 4 + 0] = t4.x; f[i * 4 + 1] = t4.y; f[i * 4 + 2] = t4.z; f[i * 4 + 3] = t4.w;
  }
  const size_t fragoff =
      ((size_t)(mt * (Ci / 32) + ks) * 64 + lhi * 16 + l15) * 8;
#pragma unroll
  for (int tap = 0; tap < 3; ++tap) {
    sh8 u;
#pragma unroll
    for (int j = 0; j < 8; ++j) u[j] = (short)f2b(f[j * 3 + tap]);
    *(sh8*)(dst + (size_t)tap * O * Ci + fragoff) = u;
  }
}

// ---------------------------------------------------------------------------
// 512-thread MFMA conv: BM=128 x BN=128, BK=32; 8 waves as 2(m)x4(n), each
// 64x32 out. Flat 1-D grid with XCD-chunked bijective swizzle (weight-sharing
// t-tiles land on one XCD's L2). Input t-major bf16; weights fragment-tiled.
template <int TAPS, int KSPLIT, bool GELU, bool MASK_OUT, bool OBF16>
__global__ __launch_bounds__(512) void mfma_conv512(
    const unsigned short* __restrict__ xin,
    const unsigned short* __restrict__ w0p, const unsigned short* __restrict__ w1p,
    const unsigned short* __restrict__ w2p,
    const float* __restrict__ b0, const float* __restrict__ b1,
    const float* __restrict__ b2,
    const float* __restrict__ mask,
    void* __restrict__ o0p, void* __restrict__ o1p, void* __restrict__ o2p,
    int Cin, int O, int tilesPerPlane, int ny)
{
  constexpr int BN = 128;
  constexpr int ROWS_B = BN + TAPS - 1;
  constexpr int PB = 40;
  __shared__ unsigned short Aw[TAPS * 8 * 512];
  __shared__ unsigned short Bx[ROWS_B * PB];

  // XCD-chunked bijective swizzle (m204)
  const int nwg = gridDim.x;
  const int orig = blockIdx.x;
  const int q = nwg >> 3, r = nwg & 7;
  const int xcd = orig & 7, idx = orig >> 3;
  const int wg = (xcd < r ? xcd * (q + 1) : r * (q + 1) + (xcd - r) * q) + idx;
  const int tx = wg & 3;              // T/128 = 4 t-tiles
  const int rest = wg >> 2;
  const int ty = rest % ny;
  const int tz = rest / ny;

  const int b  = tz / KSPLIT;
  const int kk = tz % KSPLIT;
  const int TOFF = (TAPS == 3) ? -1 : 0;
  const int t0 = tx * BN;
  const int plane = ty / tilesPerPlane;
  const int mt0 = (ty % tilesPerPlane) * 8;
  const int o0 = mt0 * 16;

  const int tid = threadIdx.x;
  const int lane = tid & 63, wid = tid >> 6;
  const int wm = wid >> 2, wn = wid & 3;
  const int l15 = lane & 15, lhi = lane >> 4;
  const int bmask = b * T;

  const unsigned short* wsel = plane == 0 ? w0p : (plane == 1 ? w1p : w2p);
  const float* bp = plane == 0 ? b0 : (plane == 1 ? b1 : b2);

  const int KST = Cin >> 5;
  const int kchunk = KST / KSPLIT;
  const int ks0 = kk * kchunk, ks1 = ks0 + kchunk;
  const int OT = O >> 4;

  const int brow = tid >> 2, bcl = (tid & 3) << 3;
  const unsigned short* xb_ = xin + (size_t)b * T * Cin;

  f32x4 acc[4][2] = {};

  for (int ks = ks0; ks < ks1; ++ks) {
    __syncthreads();
    // stage A: each wave stages frag-row-tile wid for all taps (1KB bursts)
#pragma unroll
    for (int tap = 0; tap < TAPS; ++tap) {
      const unsigned short* src =
          wsel + (((size_t)tap * OT + mt0 + wid) * KST + ks) * 512 + lane * 8;
      gload_lds16(src, &Aw[(tap * 8 + wid) * 512]);
    }
    // stage B: vectorized t-major reads -> padded LDS rows
    {
      const int c0 = ks << 5;
      const unsigned short* xrow = xb_ + c0 + bcl;
      const int tsrc = t0 + brow + TOFF;
      sh8 u = (sh8)0;
      if ((unsigned)tsrc < (unsigned)T)
        u = *(const sh8*)(xrow + (size_t)tsrc * Cin);
      *(sh8*)&Bx[brow * PB + bcl] = u;
      if constexpr (TAPS == 3) {
        if (tid < 12) {
          const int r2 = BN + (tid >> 2);
          const int ts2 = t0 + r2 + TOFF;
          sh8 u2 = (sh8)0;
          if ((unsigned)ts2 < (unsigned)T)
            u2 = *(const sh8*)(xrow + (size_t)ts2 * Cin);
          *(sh8*)&Bx[r2 * PB + bcl] = u2;
        }
      }
    }
    __syncthreads();
    // MFMA
#pragma unroll
    for (int tap = 0; tap < TAPS; ++tap) {
      sh8 af[4], bfr[2];
#pragma unroll
      for (int m = 0; m < 4; ++m)
        af[m] = *(const sh8*)&Aw[(tap * 8 + wm * 4 + m) * 512 + lane * 8];
#pragma unroll
      for (int n = 0; n < 2; ++n)
        bfr[n] = *(const sh8*)&Bx[(wn * 32 + n * 16 + l15 + tap) * PB + lhi * 8];
#pragma unroll
      for (int m = 0; m < 4; ++m)
#pragma unroll
        for (int n = 0; n < 2; ++n)
          acc[m][n] = __builtin_amdgcn_mfma_f32_16x16x32_bf16(
              af[m], bfr[n], acc[m][n], 0, 0, 0);
    }
  }

  // epilogue (t-major)
  void* obase = plane == 0 ? o0p : (plane == 1 ? o1p : o2p);
  unsigned short* oph = (unsigned short*)obase + (size_t)b * T * O;
  float* opf = (float*)obase + ((size_t)kk * B + b) * (size_t)T * O;
#pragma unroll
  for (int m = 0; m < 4; ++m) {
    const int o = o0 + (wm * 4 + m) * 16 + (lhi << 2);
#pragma unroll
    for (int n = 0; n < 2; ++n) {
      const int t = t0 + wn * 32 + n * 16 + l15;
      const float mk = MASK_OUT ? mask[bmask + t] : 1.f;
      float v[4];
#pragma unroll
      for (int r4 = 0; r4 < 4; ++r4) {
        float x = acc[m][n][r4];
        if (KSPLIT > 1) {
          if (kk == 0) x += bp[o + r4];
        } else {
          x += bp[o + r4];
        }
        if (GELU) x = gelu_exact(x);
        if (MASK_OUT) x *= mk;
        v[r4] = x;
      }
      if constexpr (OBF16) {
        ushort4 hz;
        hz.x = f2b(v[0]); hz.y = f2b(v[1]); hz.z = f2b(v[2]); hz.w = f2b(v[3]);
        *(ushort4*)(oph + (size_t)t * O + o) = hz;
      } else {
        *(float4*)(opf + (size_t)t * O + o) = make_float4(v[0], v[1], v[2], v[3]);
      }
    }
  }
}

// ---------------------------------------------------------------------------
// 256-thread MFMA conv (BM=128 x BN=64) — used for Wo projection.
template <int TAPS, int KSPLIT, bool GELU, bool MASK_OUT, bool OBF16>
__global__ __launch_bounds__(256) void mfma_conv(
    const unsigned short* __restrict__ xin,
    const unsigned short* __restrict__ w0p, const unsigned short* __restrict__ w1p,
    const unsigned short* __restrict__ w2p,
    const float* __restrict__ b0, const float* __restrict__ b1,
    const float* __restrict__ b2,
    const float* __restrict__ mask,
    void* __restrict__ o0p, void* __restrict__ o1p, void* __restrict__ o2p,
    int Cin, int O, int tilesPerPlane)
{
  constexpr int BN = 64;
  constexpr int ROWS_B = BN + TAPS - 1;
  constexpr int PB = 40;
  __shared__ unsigned short Aw[TAPS * 8 * 512];
  __shared__ unsigned short Bx[ROWS_B * PB];

  const int zz = blockIdx.z;
  const int b  = zz / KSPLIT;
  const int kk = zz % KSPLIT;
  const int TOFF = (TAPS == 3) ? -1 : 0;
  const int t0 = blockIdx.x * BN;
  const int plane = blockIdx.y / tilesPerPlane;
  const int mt0 = (blockIdx.y % tilesPerPlane) * 8;
  const int o0 = mt0 * 16;

  const int tid = threadIdx.x;
  const int lane = tid & 63, wid = tid >> 6;
  const int wm = wid >> 1, wn = wid & 1;
  const int l15 = lane & 15, lhi = lane >> 4;
  const int bmask = b * T;

  const unsigned short* wsel = plane == 0 ? w0p : (plane == 1 ? w1p : w2p);
  const float* bp = plane == 0 ? b0 : (plane == 1 ? b1 : b2);

  const int KST = Cin >> 5;
  const int kchunk = KST / KSPLIT;
  const int ks0 = kk * kchunk, ks1 = ks0 + kchunk;
  const int OT = O >> 4;

  const int brow = tid >> 2, bcl = (tid & 3) << 3;
  const unsigned short* xb_ = xin + (size_t)b * T * Cin;

  f32x4 acc[4][2] = {};

  for (int ks = ks0; ks < ks1; ++ks) {
    __syncthreads();
#pragma unroll
    for (int tap = 0; tap < TAPS; ++tap) {
#pragma unroll
      for (int j = 0; j < 2; ++j) {
        const int rt = wid * 2 + j;
        const unsigned short* src =
            wsel + (((size_t)tap * OT + mt0 + rt) * KST + ks) * 512 + lane * 8;
        gload_lds16(src, &Aw[(tap * 8 + rt) * 512]);
      }
    }
    {
      const int c0 = ks << 5;
      const unsigned short* xrow = xb_ + c0 + bcl;
      const int tsrc = t0 + brow + TOFF;
      sh8 u = (sh8)0;
      if ((unsigned)tsrc < (unsigned)T)
        u = *(const sh8*)(xrow + (size_t)tsrc * Cin);
      *(sh8*)&Bx[brow * PB + bcl] = u;
      if constexpr (TAPS == 3) {
        if (tid < 8) {
          const int r2 = 64 + (tid >> 2);
          const int ts2 = t0 + r2 + TOFF;
          sh8 u2 = (sh8)0;
          if ((unsigned)ts2 < (unsigned)T)
            u2 = *(const sh8*)(xrow + (size_t)ts2 * Cin);
          *(sh8*)&Bx[r2 * PB + bcl] = u2;
        }
      }
    }
    __syncthreads();
#pragma unroll
    for (int tap = 0; tap < TAPS; ++tap) {
      sh8 af[4], bfr[2];
#pragma unroll
      for (int m = 0; m < 4; ++m)
        af[m] = *(const sh8*)&Aw[(tap * 8 + wm * 4 + m) * 512 + lane * 8];
#pragma unroll
      for (int n = 0; n < 2; ++n)
        bfr[n] = *(const sh8*)&Bx[(wn * 32 + n * 16 + l15 + tap) * PB + lhi * 8];
#pragma unroll
      for (int m = 0; m < 4; ++m)
#pragma unroll
        for (int n = 0; n < 2; ++n)
          acc[m][n] = __builtin_amdgcn_mfma_f32_16x16x32_bf16(
              af[m], bfr[n], acc[m][n], 0, 0, 0);
    }
  }

  void* obase = plane == 0 ? o0p : (plane == 1 ? o1p : o2p);
  unsigned short* oph = (unsigned short*)obase + (size_t)b * T * O;
  float* opf = (float*)obase + ((size_t)kk * B + b) * (size_t)T * O;
#pragma unroll
  for (int m = 0; m < 4; ++m) {
    const int o = o0 + (wm * 4 + m) * 16 + (lhi << 2);
#pragma unroll
    for (int n = 0; n < 2; ++n) {
      const int t = t0 + wn * 32 + n * 16 + l15;
      const float mk = MASK_OUT ? mask[bmask + t] : 1.f;
      float v[4];
#pragma unroll
      for (int r4 = 0; r4 < 4; ++r4) {
        float x = acc[m][n][r4];
        if (KSPLIT > 1) {
          if (kk == 0) x += bp[o + r4];
        } else {
          x += bp[o + r4];
        }
        if (GELU) x = gelu_exact(x);
        if (MASK_OUT) x *= mk;
        v[r4] = x;
      }
      if constexpr (OBF16) {
        ushort4 hz;
        hz.x = f2b(v[0]); hz.y = f2b(v[1]); hz.z = f2b(v[2]); hz.w = f2b(v[3]);
        *(ushort4*)(oph + (size_t)t * O + o) = hz;
      } else {
        *(float4*)(opf + (size_t)t * O + o) = make_float4(v[0], v[1], v[2], v[3]);
      }
    }
  }
}

// ---------------------------------------------------------------------------
// Fused attention. q/k/v t-major bf16 [B][T][C]; out t-major bf16 [B][T][C].
__global__ __launch_bounds__(256) void fused_attn(
    const unsigned short* __restrict__ qg,
    const unsigned short* __restrict__ kg,
    const unsigned short* __restrict__ vg,
    const float* __restrict__ mask,
    const float* __restrict__ ek,
    const float* __restrict__ ev,
    unsigned short* __restrict__ outp)
{
  constexpr int PITCH = 72;
  __shared__ unsigned short Qs[64 * PITCH];  // [t][d]
  __shared__ unsigned short Ks[64 * PITCH];  // [s][d]
  __shared__ unsigned short Vs[64 * PITCH];  // [d][s]
  __shared__ unsigned short Ps[64 * PITCH];  // [t][s]
  __shared__ float eks[D * 9], evs[D * 9];
  __shared__ float qekl[64 * 12];
  __shared__ float mks[64];

  const int t0 = blockIdx.x * 64;
  const int bh = blockIdx.y;
  const int b = bh / H, h = bh % H;
  const int tid = threadIdx.x;
  const int lane = tid & 63, w = tid >> 6;
  const int l15 = lane & 15, lhi = lane >> 4;

  const size_t base = (size_t)b * T * C + h * D;
  const unsigned short* qh = qg + base;
  const unsigned short* kh = kg + base;
  const unsigned short* vh = vg + base;

  for (int e = tid; e < D * 9; e += 256) { eks[e] = ek[e]; evs[e] = ev[e]; }
  {
    const int tl = tid & 63, d0 = (tid >> 6) << 4;
    const unsigned short* src = qh + (size_t)(t0 + tl) * C + d0;
    *(sh8*)&Qs[tl * PITCH + d0]     = *(const sh8*)(src);
    *(sh8*)&Qs[tl * PITCH + d0 + 8] = *(const sh8*)(src + 8);
  }
  __syncthreads();
  {
    const int tl = tid & 63, g = tid >> 6;
    for (int j = g; j < 9; j += 4) {
      float a = 0.f;
      for (int d = 0; d < D; ++d)
        a = fmaf(b2f(Qs[tl * PITCH + d]), eks[d * 9 + j], a);
      qekl[tl * 12 + j] = a * 0.125f;
    }
  }
  const int t_loc = w * 16 + l15;
  const int t = t0 + t_loc;
  const float mask_t = mask[b * T + t];
  const sh8 bq0 = *(const sh8*)&Qs[t_loc * PITCH + lhi * 8];
  const sh8 bq1 = *(const sh8*)&Qs[t_loc * PITCH + 32 + lhi * 8];

  float m_run = -1e30f, l_run = 0.f;
  f32x4 oacc[4] = {};

  for (int s0 = 0; s0 < T; s0 += 64) {
    __syncthreads();
    // stage K [s][d] — vector copy
    {
      const int sl = tid & 63, d0 = (tid >> 6) << 4;
      const unsigned short* src = kh + (size_t)(s0 + sl) * C + d0;
      *(sh8*)&Ks[sl * PITCH + d0]     = *(const sh8*)(src);
      *(sh8*)&Ks[sl * PITCH + d0 + 8] = *(const sh8*)(src + 8);
    }
    // stage V [d][s] — vector global load + LDS scalar transpose (2 lanes/bank)
    {
      const int sl = tid & 63, d0 = (tid >> 6) << 4;
      const unsigned short* src = vh + (size_t)(s0 + sl) * C + d0;
      sh8 u0 = *(const sh8*)(src);
      sh8 u1 = *(const sh8*)(src + 8);
#pragma unroll
      for (int j = 0; j < 8; ++j) Vs[(d0 + j) * PITCH + sl] = (unsigned short)u0[j];
#pragma unroll
      for (int j = 0; j < 8; ++j) Vs[(d0 + 8 + j) * PITCH + sl] = (unsigned short)u1[j];
    }
    if (tid < 64) mks[tid] = mask[b * T + s0 + tid];
    __syncthreads();

    float p[16];
#pragma unroll
    for (int n = 0; n < 4; ++n) {
      const sh8 a0 = *(const sh8*)&Ks[(n * 16 + l15) * PITCH + lhi * 8];
      const sh8 a1 = *(const sh8*)&Ks[(n * 16 + l15) * PITCH + 32 + lhi * 8];
      f32x4 acc = {};
      acc = __builtin_amdgcn_mfma_f32_16x16x32_bf16(a0, bq0, acc, 0, 0, 0);
      acc = __builtin_amdgcn_mfma_f32_16x16x32_bf16(a1, bq1, acc, 0, 0, 0);
#pragma unroll
      for (int r = 0; r < 4; ++r) {
        const int s = s0 + n * 16 + lhi * 4 + r;
        float v = acc[r] * 0.125f;
        const int j = s - t + 4;
        if ((unsigned)j < 9u) v += qekl[t_loc * 12 + j];
        if (mask_t * mks[s - s0] == 0.f) v = -10000.0f;
        p[n * 4 + r] = v;
      }
    }
    float mloc = p[0];
#pragma unroll
    for (int i = 1; i < 16; ++i) mloc = fmaxf(mloc, p[i]);
    mloc = fmaxf(mloc, __shfl_xor(mloc, 16));
    mloc = fmaxf(mloc, __shfl_xor(mloc, 32));
    const float m_new = fmaxf(m_run, mloc);
    const float f = __expf(m_run - m_new);
    float sloc = 0.f;
#pragma unroll
    for (int i = 0; i < 16; ++i) { p[i] = __expf(p[i] - m_new); sloc += p[i]; }
    sloc += __shfl_xor(sloc, 16);
    sloc += __shfl_xor(sloc, 32);
    l_run = l_run * f + sloc;
    m_run = m_new;
#pragma unroll
    for (int m = 0; m < 4; ++m)
#pragma unroll
      for (int r = 0; r < 4; ++r) oacc[m][r] *= f;
#pragma unroll
    for (int n = 0; n < 4; ++n) {
      uint2 pk;
      pk.x = (unsigned)f2b(p[n * 4 + 0]) | ((unsigned)f2b(p[n * 4 + 1]) << 16);
      pk.y = (unsigned)f2b(p[n * 4 + 2]) | ((unsigned)f2b(p[n * 4 + 3]) << 16);
      *(uint2*)&Ps[t_loc * PITCH + n * 16 + lhi * 4] = pk;
    }
    asm volatile("s_waitcnt lgkmcnt(0)" ::: "memory");
    const sh8 bp0 = *(const sh8*)&Ps[t_loc * PITCH + lhi * 8];
    const sh8 bp1 = *(const sh8*)&Ps[t_loc * PITCH + 32 + lhi * 8];
#pragma unroll
    for (int m = 0; m < 4; ++m) {
      const sh8 a0 = *(const sh8*)&Vs[(m * 16 + l15) * PITCH + lhi * 8];
      const sh8 a1 = *(const sh8*)&Vs[(m * 16 + l15) * PITCH + 32 + lhi * 8];
      oacc[m] = __builtin_amdgcn_mfma_f32_16x16x32_bf16(a0, bp0, oacc[m], 0, 0, 0);
      oacc[m] = __builtin_amdgcn_mfma_f32_16x16x32_bf16(a1, bp1, oacc[m], 0, 0, 0);
    }
    if (t + 4 >= s0 && t < s0 + 68) {
#pragma unroll
      for (int j = 0; j < 9; ++j) {
        const int s = t + j - 4;
        if (s >= s0 && s < s0 + 64) {
          const float pv = b2f(Ps[t_loc * PITCH + (s - s0)]);
#pragma unroll
          for (int m = 0; m < 4; ++m)
#pragma unroll
            for (int r = 0; r < 4; ++r)
              oacc[m][r] = fmaf(pv, evs[(m * 16 + lhi * 4 + r) * 9 + j], oacc[m][r]);
        }
      }
    }
  }
  const float invl = 1.f / l_run;
  unsigned short* ob = outp + (size_t)(b * T + t) * C + h * D;
#pragma unroll
  for (int m = 0; m < 4; ++m) {
    ushort4 hz;
    hz.x = f2b(oacc[m][0] * invl);
    hz.y = f2b(oacc[m][1] * invl);
    hz.z = f2b(oacc[m][2] * invl);
    hz.w = f2b(oacc[m][3] * invl);
    *(ushort4*)(ob + m * 16 + lhi * 4) = hz;
  }
}

// ---------------------------------------------------------------------------
// dst = LayerNorm_C(x + sum_p y_p) ; y partials t-major [NP][B][T][C] fp32.
template <int NP, bool MASKY, bool MASKF>
__global__ __launch_bounds__(256) void add_norm_kernel(
    const float* __restrict__ x, const float* __restrict__ ypart,
    const float* __restrict__ g, const float* __restrict__ bta,
    const float* __restrict__ mask, float* __restrict__ dst,
    unsigned short* __restrict__ dsth)
{
  constexpr int NQ = C / 16;  // 48
  const int b = blockIdx.y;
  const int t0 = blockIdx.x * 16;
  const int r = threadIdx.x >> 4, tc = threadIdx.x & 15;
  const int t = t0 + tc;
  const float* xb = x + (size_t)b * C * T;
  const float mkt = mask[b * T + t];
  float vv[NQ];
  float sum = 0.f, sq = 0.f;
#pragma unroll
  for (int q = 0; q < NQ; ++q) {
    const int ci = r + q * 16;
    float y = 0.f;
#pragma unroll
    for (int p = 0; p < NP; ++p)
      y += ypart[(((size_t)p * B + b) * T + t) * C + ci];
    if (MASKY) y *= mkt;
    const float v = xb[(size_t)ci * T + t] + y;
    vv[q] = v;
    sum += v;
    sq = fmaf(v, v, sq);
  }
  __shared__ float ssum[16][17], ssq[16][17];
  __shared__ float mean_s[16], rstd_s[16];
  ssum[r][tc] = sum;
  ssq[r][tc] = sq;
  __syncthreads();
  if (r == 0) {
    float s = 0.f, q2 = 0.f;
#pragma unroll
    for (int i = 0; i < 16; ++i) { s += ssum[i][tc]; q2 += ssq[i][tc]; }
    const float m = s / C;
    mean_s[tc] = m;
    rstd_s[tc] = rsqrtf(q2 / C - m * m + 1e-5f);
  }
  __syncthreads();
  const float m = mean_s[tc], rs = rstd_s[tc];
  float* db = dst + (size_t)b * C * T;
  unsigned short* dbh = dsth + ((size_t)b * T + t) * C;
#pragma unroll
  for (int q = 0; q < NQ; ++q) {
    const int ci = r + q * 16;
    float o = (vv[q] - m) * rs * g[ci] + bta[ci];
    if (MASKF) o *= mkt;
    db[(size_t)ci * T + t] = o;
    dbh[ci] = f2b(MASKF ? o : o * mkt);
  }
}

}  // namespace

extern "C" void kernel_launch(void* const* d_in, const int* in_sizes, int n_in,
                              void* d_out, int out_size, void* d_ws, size_t ws_size,
                              hipStream_t stream) {
  const float* x_in = (const float*)d_in[0];
  const float* mask = (const float*)d_in[1];
  const float* Wq = (const float*)d_in[2];
  const float* bq = (const float*)d_in[3];
  const float* Wk = (const float*)d_in[4];
  const float* bk = (const float*)d_in[5];
  const float* Wv = (const float*)d_in[6];
  const float* bv = (const float*)d_in[7];
  const float* Wo = (const float*)d_in[8];
  const float* bo = (const float*)d_in[9];
  const float* ek = (const float*)d_in[10];
  const float* ev = (const float*)d_in[11];
  const float* w1 = (const float*)d_in[12];
  const float* b1 = (const float*)d_in[13];
  const float* w2 = (const float*)d_in[14];
  const float* b2 = (const float*)d_in[15];
  const float* n1g = (const float*)d_in[16];
  const float* n1b = (const float*)d_in[17];
  const float* n2g = (const float*)d_in[18];
  const float* n2b = (const float*)d_in[19];

  float* ws = (float*)d_ws;
  const size_t SZ_X = (size_t)B * C * T;
  float* xb    = ws;                              // residual fp32 [B][C][T]
  float* ypart = xb + SZ_X;                       // [4][B][T][C] fp32 partials
  unsigned short* xbh = (unsigned short*)(ypart + 4 * SZ_X);
  unsigned short* xfh = xbh + SZ_X;
  unsigned short* qbh = xfh + SZ_X;
  unsigned short* kbh = qbh + SZ_X;
  unsigned short* vbh = kbh + SZ_X;
  unsigned short* hidh = vbh + SZ_X;              // [B][T][FF]
  unsigned short* w1t = hidh + (size_t)B * FF * T;
  unsigned short* w2t = w1t + (size_t)3 * FF * C;
  unsigned short* wqt = w2t + (size_t)3 * FF * C;
  unsigned short* wkt = wqt + (size_t)C * C;
  unsigned short* wvt = wkt + (size_t)C * C;
  unsigned short* wot = wvt + (size_t)C * C;
  float* outp = (float*)d_out;

  const dim3 blk(256);
  const dim3 blk512(512);
  transpose_cvt<<<dim3(T / 32, C / 32, B), blk, 0, stream>>>(x_in, xbh);

  for (int i = 0; i < NL; ++i) {
    const float* xs = (i == 0) ? x_in : xb;
    const size_t wOff = (size_t)i * C * C;
    cvt_qkvo_tiled<<<dim3((C * C / 8) / 256, 4), blk, 0, stream>>>(
        Wq + wOff, Wk + wOff, Wv + wOff, Wo + wOff, wqt, wkt, wvt, wot);
    cvt_ffn_tiled<<<dim3((FF * C / 8) / 256, 2), blk, 0, stream>>>(
        w1 + (size_t)i * FF * C * 3, w2 + (size_t)i * C * FF * 3, w1t, w2t);
    // QKV projection (288 blocks x 512 thr, BN=128)
    mfma_conv512<1, 1, false, false, true><<<dim3(4 * 18 * B), blk512, 0, stream>>>(
        xbh, wqt, wkt, wvt, bq + i * C, bk + i * C, bv + i * C, mask,
        qbh, kbh, vbh, C, C, 6, 18);
    // fused attention
    fused_attn<<<dim3(T / 64, B * H), blk, 0, stream>>>(
        qbh, kbh, vbh, mask, ek + (size_t)i * D * 9, ev + (size_t)i * D * 9, hidh);
    // Wo projection: split-K2 -> fp32 partials (384 blocks x 256 thr)
    mfma_conv<1, 2, false, false, false><<<dim3(8, 6, B * 2), blk, 0, stream>>>(
        hidh, wot, wot, wot, bo + i * C, bo + i * C, bo + i * C, mask,
        ypart, ypart, ypart, C, C, 6);
    add_norm_kernel<2, false, false><<<dim3(T / 16, B), blk, 0, stream>>>(
        xs, ypart, n1g + i * C, n1b + i * C, mask, xb, xfh);
    // FFN up: 3 taps, GELU+mask, bf16 out (384 blocks x 512 thr)
    mfma_conv512<3, 1, true, true, true><<<dim3(4 * 24 * B), blk512, 0, stream>>>(
        xfh, w1t, w1t, w1t, b1 + i * FF, b1 + i * FF, b1 + i * FF, mask,
        hidh, hidh, hidh, C, FF, 24, 24);
    // FFN down: 3 taps, split-K4 -> fp32 partials (384 blocks x 512 thr)
    mfma_conv512<3, 4, false, false, false><<<dim3(4 * 6 * B * 4), blk512, 0, stream>>>(
        hidh, w2t, w2t, w2t, b2 + i * C, b2 + i * C, b2 + i * C, mask,
        ypart, ypart, ypart, FF, C, 6, 6);
    add_norm_kernel<4, true, true><<<dim3(T / 16, B), blk, 0, stream>>>(
        xb, ypart, n2g + i * C, n2b + i * C, mask, (i == NL - 1) ? outp : xb, xbh);
  }
}

// Round 8
// 1419.887 us; speedup vs baseline: 1.6032x; 1.1035x over previous
//
#include <hip/hip_runtime.h>
#include <cstddef>

namespace {

constexpr int B  = 4;
constexpr int C  = 768;
constexpr int T  = 512;
constexpr int H  = 12;
constexpr int D  = 64;
constexpr int NL = 6;
constexpr int W  = 4;
constexpr int FF = 3072;

typedef __attribute__((ext_vector_type(8))) short sh8;
typedef __attribute__((ext_vector_type(4))) float f32x4;

__device__ inline float gelu_exact(float x) {
  return 0.5f * x * (1.0f + erff(x * 0.70710678118654752440f));
}
__device__ inline unsigned short f2b(float f) {
  unsigned u = __float_as_uint(f);
  unsigned r = (u + 0x7fffu + ((u >> 16) & 1u)) >> 16;
  return (unsigned short)r;
}
__device__ inline float b2f(unsigned short u) {
  return __uint_as_float((unsigned)u << 16);
}
__device__ inline void gload_lds16(const void* g, void* l) {
  __builtin_amdgcn_global_load_lds(
      (const __attribute__((address_space(1))) unsigned int*)g,
      (__attribute__((address_space(3))) unsigned int*)l, 16, 0, 0);
}

// ---------------------------------------------------------------------------
// Layer-0 input: x [B][C][T] fp32 -> [B][T][C] bf16 (tiled transpose)
__global__ __launch_bounds__(256) void transpose_cvt(
    const float* __restrict__ s, unsigned short* __restrict__ d)
{
  __shared__ unsigned short tile[32][33];
  const int b = blockIdx.z;
  const int c0 = blockIdx.y * 32, t0 = blockIdx.x * 32;
  const int tx = threadIdx.x & 31, ty = threadIdx.x >> 5;
  const float* sp = s + ((size_t)b * C + c0) * T + t0;
#pragma unroll
  for (int i = 0; i < 4; ++i)
    tile[ty + i * 8][tx] = f2b(sp[(size_t)(ty + i * 8) * T + tx]);
  __syncthreads();
  unsigned short* dp = d + ((size_t)b * T + t0) * C + c0;
#pragma unroll
  for (int i = 0; i < 4; ++i)
    dp[(size_t)(ty + i * 8) * C + tx] = tile[tx][ty + i * 8];
}

// QKVO weights fp32 [C][C] -> bf16 MFMA-fragment-tiled
__global__ __launch_bounds__(256) void cvt_qkvo_tiled(
    const float* __restrict__ q, const float* __restrict__ k,
    const float* __restrict__ v, const float* __restrict__ o,
    unsigned short* __restrict__ dq, unsigned short* __restrict__ dk,
    unsigned short* __restrict__ dv, unsigned short* __restrict__ dov)
{
  const int z = blockIdx.y;
  const float* s = z == 0 ? q : z == 1 ? k : z == 2 ? v : o;
  unsigned short* d = z == 0 ? dq : z == 1 ? dk : z == 2 ? dv : dov;
  const int flat = blockIdx.x * 256 + threadIdx.x;   // over C*C/8
  const int row = flat / (C / 8);
  const int c   = (flat % (C / 8)) * 8;
  const int ks = c >> 5, lhi = (c >> 3) & 3, mt = row >> 4, l15 = row & 15;
  const float* sp = s + (size_t)row * C + c;
  float4 a = *(const float4*)(sp);
  float4 b = *(const float4*)(sp + 4);
  sh8 u;
  u[0] = (short)f2b(a.x); u[1] = (short)f2b(a.y);
  u[2] = (short)f2b(a.z); u[3] = (short)f2b(a.w);
  u[4] = (short)f2b(b.x); u[5] = (short)f2b(b.y);
  u[6] = (short)f2b(b.z); u[7] = (short)f2b(b.w);
  *(sh8*)(d + ((size_t)(mt * (C / 32) + ks) * 64 + lhi * 16 + l15) * 8) = u;
}

// FFN weights [O][Ci][3] fp32 -> 3 tap planes, each fragment-tiled bf16.
__global__ __launch_bounds__(256) void cvt_ffn_tiled(
    const float* __restrict__ s1, const float* __restrict__ s2,
    unsigned short* __restrict__ d1, unsigned short* __restrict__ d2)
{
  const int z = blockIdx.y;
  const float* src = z ? s2 : s1;
  unsigned short* dst = z ? d2 : d1;
  const int O  = z ? C : FF;
  const int Ci = z ? FF : C;
  const int flat = blockIdx.x * 256 + threadIdx.x;   // over O*Ci/8
  const int row = flat / (Ci / 8);
  const int c   = (flat % (Ci / 8)) * 8;
  const int ks = c >> 5, lhi = (c >> 3) & 3, mt = row >> 4, l15 = row & 15;
  const float* sp = src + ((size_t)row * Ci + c) * 3;
  float f[24];
#pragma unroll
  for (int i = 0; i < 6; ++i) {
    float4 t4 = *(const float4*)(sp + i * 4);
    f[i * 4 + 0] = t4.x; f[i * 4 + 1] = t4.y; f[i * 4 + 2] = t4.z; f[i * 4 + 3] = t4.w;
  }
  const size_t fragoff =
      ((size_t)(mt * (Ci / 32) + ks) * 64 + lhi * 16 + l15) * 8;
#pragma unroll
  for (int tap = 0; tap < 3; ++tap) {
    sh8 u;
#pragma unroll
    for (int j = 0; j < 8; ++j) u[j] = (short)f2b(f[j * 3 + tap]);
    *(sh8*)(dst + (size_t)tap * O * Ci + fragoff) = u;
  }
}

// ---------------------------------------------------------------------------
// 512-thread MFMA conv: BM=128 x BN=128, BK=32; 8 waves 2(m)x4(n).
// 2-phase double-buffered staging: prefetch next K-step (gload_lds A + reg B)
// before computing current; single barrier per K-step.
template <int TAPS, int KSPLIT, bool GELU, bool MASK_OUT, bool OBF16>
__global__ __launch_bounds__(512) void mfma_conv512(
    const unsigned short* __restrict__ xin,
    const unsigned short* __restrict__ w0p, const unsigned short* __restrict__ w1p,
    const unsigned short* __restrict__ w2p,
    const float* __restrict__ b0, const float* __restrict__ b1,
    const float* __restrict__ b2,
    const float* __restrict__ mask,
    void* __restrict__ o0p, void* __restrict__ o1p, void* __restrict__ o2p,
    int Cin, int O, int tilesPerPlane, int ny)
{
  constexpr int BN = 128;
  constexpr int ROWS_B = BN + TAPS - 1;
  constexpr int PB = 40;
  __shared__ unsigned short Aw[2][TAPS * 8 * 512];
  __shared__ unsigned short Bx[2][ROWS_B * PB];

  // XCD-chunked bijective swizzle (m204)
  const int nwg = gridDim.x;
  const int orig = blockIdx.x;
  const int q = nwg >> 3, r = nwg & 7;
  const int xcd = orig & 7, idx = orig >> 3;
  const int wg = (xcd < r ? xcd * (q + 1) : r * (q + 1) + (xcd - r) * q) + idx;
  const int tx = wg & 3;
  const int rest = wg >> 2;
  const int ty = rest % ny;
  const int tz = rest / ny;

  const int b  = tz / KSPLIT;
  const int kk = tz % KSPLIT;
  const int TOFF = (TAPS == 3) ? -1 : 0;
  const int t0 = tx * BN;
  const int plane = ty / tilesPerPlane;
  const int mt0 = (ty % tilesPerPlane) * 8;
  const int o0 = mt0 * 16;

  const int tid = threadIdx.x;
  const int lane = tid & 63, wid = tid >> 6;
  const int wm = wid >> 2, wn = wid & 3;
  const int l15 = lane & 15, lhi = lane >> 4;
  const int bmask = b * T;

  const unsigned short* wsel = plane == 0 ? w0p : (plane == 1 ? w1p : w2p);
  const float* bp = plane == 0 ? b0 : (plane == 1 ? b1 : b2);

  const int KST = Cin >> 5;
  const int kchunk = KST / KSPLIT;
  const int ks0 = kk * kchunk, ks1 = ks0 + kchunk;
  const int OT = O >> 4;

  const int brow = tid >> 2, bcl = (tid & 3) << 3;
  const unsigned short* xb_ = xin + (size_t)b * T * Cin;

  sh8 breg, breg2;
  auto stageA = [&](int ks, int buf) {
#pragma unroll
    for (int tap = 0; tap < TAPS; ++tap) {
      const unsigned short* src =
          wsel + (((size_t)tap * OT + mt0 + wid) * KST + ks) * 512 + lane * 8;
      gload_lds16(src, &Aw[buf][(tap * 8 + wid) * 512]);
    }
  };
  auto loadB = [&](int ks) {
    const int c0 = ks << 5;
    const unsigned short* xrow = xb_ + c0 + bcl;
    const int tsrc = t0 + brow + TOFF;
    breg = (sh8)0;
    if ((unsigned)tsrc < (unsigned)T)
      breg = *(const sh8*)(xrow + (size_t)tsrc * Cin);
    if constexpr (TAPS == 3) {
      breg2 = (sh8)0;
      if (tid < 8) {
        const int ts2 = t0 + BN + (tid >> 2) + TOFF;
        if ((unsigned)ts2 < (unsigned)T)
          breg2 = *(const sh8*)(xrow + (size_t)ts2 * Cin);
      }
    }
  };
  auto writeB = [&](int buf) {
    *(sh8*)&Bx[buf][brow * PB + bcl] = breg;
    if constexpr (TAPS == 3) {
      if (tid < 8)
        *(sh8*)&Bx[buf][(BN + (tid >> 2)) * PB + bcl] = breg2;
    }
  };

  f32x4 acc[4][2] = {};

  // prologue: stage first K-step into buf 0
  int cur = 0;
  stageA(ks0, 0);
  loadB(ks0);
  writeB(0);
  __syncthreads();

  for (int ks = ks0; ks < ks1; ++ks) {
    const int nxt = cur ^ 1;
    const bool more = (ks + 1 < ks1);
    if (more) { stageA(ks + 1, nxt); loadB(ks + 1); }
    // compute from buf[cur]
#pragma unroll
    for (int tap = 0; tap < TAPS; ++tap) {
      sh8 af[4], bfr[2];
#pragma unroll
      for (int m = 0; m < 4; ++m)
        af[m] = *(const sh8*)&Aw[cur][(tap * 8 + wm * 4 + m) * 512 + lane * 8];
#pragma unroll
      for (int n = 0; n < 2; ++n)
        bfr[n] = *(const sh8*)&Bx[cur][(wn * 32 + n * 16 + l15 + tap) * PB + lhi * 8];
#pragma unroll
      for (int m = 0; m < 4; ++m)
#pragma unroll
        for (int n = 0; n < 2; ++n)
          acc[m][n] = __builtin_amdgcn_mfma_f32_16x16x32_bf16(
              af[m], bfr[n], acc[m][n], 0, 0, 0);
    }
    if (more) writeB(nxt);
    __syncthreads();
    cur = nxt;
  }

  // epilogue (t-major)
  void* obase = plane == 0 ? o0p : (plane == 1 ? o1p : o2p);
  unsigned short* oph = (unsigned short*)obase + (size_t)b * T * O;
  float* opf = (float*)obase + ((size_t)kk * B + b) * (size_t)T * O;
#pragma unroll
  for (int m = 0; m < 4; ++m) {
    const int o = o0 + (wm * 4 + m) * 16 + (lhi << 2);
#pragma unroll
    for (int n = 0; n < 2; ++n) {
      const int t = t0 + wn * 32 + n * 16 + l15;
      const float mk = MASK_OUT ? mask[bmask + t] : 1.f;
      float v[4];
#pragma unroll
      for (int r4 = 0; r4 < 4; ++r4) {
        float x = acc[m][n][r4];
        if (KSPLIT > 1) {
          if (kk == 0) x += bp[o + r4];
        } else {
          x += bp[o + r4];
        }
        if (GELU) x = gelu_exact(x);
        if (MASK_OUT) x *= mk;
        v[r4] = x;
      }
      if constexpr (OBF16) {
        ushort4 hz;
        hz.x = f2b(v[0]); hz.y = f2b(v[1]); hz.z = f2b(v[2]); hz.w = f2b(v[3]);
        *(ushort4*)(oph + (size_t)t * O + o) = hz;
      } else {
        *(float4*)(opf + (size_t)t * O + o) = make_float4(v[0], v[1], v[2], v[3]);
      }
    }
  }
}

// ---------------------------------------------------------------------------
// 256-thread MFMA conv (BM=128 x BN=64), 2-phase dbuf — used for Wo.
template <int TAPS, int KSPLIT, bool GELU, bool MASK_OUT, bool OBF16>
__global__ __launch_bounds__(256) void mfma_conv(
    const unsigned short* __restrict__ xin,
    const unsigned short* __restrict__ w0p, const unsigned short* __restrict__ w1p,
    const unsigned short* __restrict__ w2p,
    const float* __restrict__ b0, const float* __restrict__ b1,
    const float* __restrict__ b2,
    const float* __restrict__ mask,
    void* __restrict__ o0p, void* __restrict__ o1p, void* __restrict__ o2p,
    int Cin, int O, int tilesPerPlane)
{
  constexpr int BN = 64;
  constexpr int ROWS_B = BN + TAPS - 1;
  constexpr int PB = 40;
  __shared__ unsigned short Aw[2][TAPS * 8 * 512];
  __shared__ unsigned short Bx[2][ROWS_B * PB];

  const int zz = blockIdx.z;
  const int b  = zz / KSPLIT;
  const int kk = zz % KSPLIT;
  const int TOFF = (TAPS == 3) ? -1 : 0;
  const int t0 = blockIdx.x * BN;
  const int plane = blockIdx.y / tilesPerPlane;
  const int mt0 = (blockIdx.y % tilesPerPlane) * 8;
  const int o0 = mt0 * 16;

  const int tid = threadIdx.x;
  const int lane = tid & 63, wid = tid >> 6;
  const int wm = wid >> 1, wn = wid & 1;
  const int l15 = lane & 15, lhi = lane >> 4;
  const int bmask = b * T;

  const unsigned short* wsel = plane == 0 ? w0p : (plane == 1 ? w1p : w2p);
  const float* bp = plane == 0 ? b0 : (plane == 1 ? b1 : b2);

  const int KST = Cin >> 5;
  const int kchunk = KST / KSPLIT;
  const int ks0 = kk * kchunk, ks1 = ks0 + kchunk;
  const int OT = O >> 4;

  const int brow = tid >> 2, bcl = (tid & 3) << 3;
  const unsigned short* xb_ = xin + (size_t)b * T * Cin;

  sh8 breg, breg2;
  auto stageA = [&](int ks, int buf) {
#pragma unroll
    for (int tap = 0; tap < TAPS; ++tap) {
#pragma unroll
      for (int j = 0; j < 2; ++j) {
        const int rt = wid * 2 + j;
        const unsigned short* src =
            wsel + (((size_t)tap * OT + mt0 + rt) * KST + ks) * 512 + lane * 8;
        gload_lds16(src, &Aw[buf][(tap * 8 + rt) * 512]);
      }
    }
  };
  auto loadB = [&](int ks) {
    const int c0 = ks << 5;
    const unsigned short* xrow = xb_ + c0 + bcl;
    const int tsrc = t0 + brow + TOFF;
    breg = (sh8)0;
    if ((unsigned)tsrc < (unsigned)T)
      breg = *(const sh8*)(xrow + (size_t)tsrc * Cin);
    if constexpr (TAPS == 3) {
      breg2 = (sh8)0;
      if (tid < 8) {
        const int ts2 = t0 + BN + (tid >> 2) + TOFF;
        if ((unsigned)ts2 < (unsigned)T)
          breg2 = *(const sh8*)(xrow + (size_t)ts2 * Cin);
      }
    }
  };
  auto writeB = [&](int buf) {
    *(sh8*)&Bx[buf][brow * PB + bcl] = breg;
    if constexpr (TAPS == 3) {
      if (tid < 8)
        *(sh8*)&Bx[buf][(BN + (tid >> 2)) * PB + bcl] = breg2;
    }
  };

  f32x4 acc[4][2] = {};

  int cur = 0;
  stageA(ks0, 0);
  loadB(ks0);
  writeB(0);
  __syncthreads();

  for (int ks = ks0; ks < ks1; ++ks) {
    const int nxt = cur ^ 1;
    const bool more = (ks + 1 < ks1);
    if (more) { stageA(ks + 1, nxt); loadB(ks + 1); }
#pragma unroll
    for (int tap = 0; tap < TAPS; ++tap) {
      sh8 af[4], bfr[2];
#pragma unroll
      for (int m = 0; m < 4; ++m)
        af[m] = *(const sh8*)&Aw[cur][(tap * 8 + wm * 4 + m) * 512 + lane * 8];
#pragma unroll
      for (int n = 0; n < 2; ++n)
        bfr[n] = *(const sh8*)&Bx[cur][(wn * 32 + n * 16 + l15 + tap) * PB + lhi * 8];
#pragma unroll
      for (int m = 0; m < 4; ++m)
#pragma unroll
        for (int n = 0; n < 2; ++n)
          acc[m][n] = __builtin_amdgcn_mfma_f32_16x16x32_bf16(
              af[m], bfr[n], acc[m][n], 0, 0, 0);
    }
    if (more) writeB(nxt);
    __syncthreads();
    cur = nxt;
  }

  void* obase = plane == 0 ? o0p : (plane == 1 ? o1p : o2p);
  unsigned short* oph = (unsigned short*)obase + (size_t)b * T * O;
  float* opf = (float*)obase + ((size_t)kk * B + b) * (size_t)T * O;
#pragma unroll
  for (int m = 0; m < 4; ++m) {
    const int o = o0 + (wm * 4 + m) * 16 + (lhi << 2);
#pragma unroll
    for (int n = 0; n < 2; ++n) {
      const int t = t0 + wn * 32 + n * 16 + l15;
      const float mk = MASK_OUT ? mask[bmask + t] : 1.f;
      float v[4];
#pragma unroll
      for (int r4 = 0; r4 < 4; ++r4) {
        float x = acc[m][n][r4];
        if (KSPLIT > 1) {
          if (kk == 0) x += bp[o + r4];
        } else {
          x += bp[o + r4];
        }
        if (GELU) x = gelu_exact(x);
        if (MASK_OUT) x *= mk;
        v[r4] = x;
      }
      if constexpr (OBF16) {
        ushort4 hz;
        hz.x = f2b(v[0]); hz.y = f2b(v[1]); hz.z = f2b(v[2]); hz.w = f2b(v[3]);
        *(ushort4*)(oph + (size_t)t * O + o) = hz;
      } else {
        *(float4*)(opf + (size_t)t * O + o) = make_float4(v[0], v[1], v[2], v[3]);
      }
    }
  }
}

// ---------------------------------------------------------------------------
// Fused attention with 2-phase K/V prefetch. q/k/v/out t-major bf16 [B][T][C].
__global__ __launch_bounds__(256) void fused_attn(
    const unsigned short* __restrict__ qg,
    const unsigned short* __restrict__ kg,
    const unsigned short* __restrict__ vg,
    const float* __restrict__ mask,
    const float* __restrict__ ek,
    const float* __restrict__ ev,
    unsigned short* __restrict__ outp)
{
  constexpr int PITCH = 72;
  __shared__ unsigned short Qs[64 * PITCH];     // [t][d]
  __shared__ unsigned short Ks[2][64 * PITCH];  // [s][d]
  __shared__ unsigned short Vs[2][64 * PITCH];  // [d][s]
  __shared__ unsigned short Ps[64 * PITCH];     // [t][s] (wave-private rows)
  __shared__ float eks[D * 9], evs[D * 9];
  __shared__ float qekl[64 * 12];
  __shared__ float mks[2][64];

  const int t0 = blockIdx.x * 64;
  const int bh = blockIdx.y;
  const int b = bh / H, h = bh % H;
  const int tid = threadIdx.x;
  const int lane = tid & 63, w = tid >> 6;
  const int l15 = lane & 15, lhi = lane >> 4;

  const size_t base = (size_t)b * T * C + h * D;
  const unsigned short* qh = qg + base;
  const unsigned short* kh = kg + base;
  const unsigned short* vh = vg + base;

  for (int e = tid; e < D * 9; e += 256) { eks[e] = ek[e]; evs[e] = ev[e]; }
  // stage Q [t][d]
  {
    const int tl = tid & 63, d0 = (tid >> 6) << 4;
    const unsigned short* src = qh + (size_t)(t0 + tl) * C + d0;
    *(sh8*)&Qs[tl * PITCH + d0]     = *(const sh8*)(src);
    *(sh8*)&Qs[tl * PITCH + d0 + 8] = *(const sh8*)(src + 8);
  }
  __syncthreads();
  // rel-k logits
  {
    const int tl = tid & 63, g = tid >> 6;
    for (int j = g; j < 9; j += 4) {
      float a = 0.f;
      for (int d = 0; d < D; ++d)
        a = fmaf(b2f(Qs[tl * PITCH + d]), eks[d * 9 + j], a);
      qekl[tl * 12 + j] = a * 0.125f;
    }
  }
  const int t_loc = w * 16 + l15;
  const int t = t0 + t_loc;
  const float mask_t = mask[b * T + t];
  const sh8 bq0 = *(const sh8*)&Qs[t_loc * PITCH + lhi * 8];
  const sh8 bq1 = *(const sh8*)&Qs[t_loc * PITCH + 32 + lhi * 8];

  const int sl = tid & 63, d0s = (tid >> 6) << 4;
  // prologue: stage s-tile 0 into buf 0
  {
    const unsigned short* srck = kh + (size_t)sl * C + d0s;
    *(sh8*)&Ks[0][sl * PITCH + d0s]     = *(const sh8*)(srck);
    *(sh8*)&Ks[0][sl * PITCH + d0s + 8] = *(const sh8*)(srck + 8);
    const unsigned short* srcv = vh + (size_t)sl * C + d0s;
    sh8 u0 = *(const sh8*)(srcv);
    sh8 u1 = *(const sh8*)(srcv + 8);
#pragma unroll
    for (int j = 0; j < 8; ++j) Vs[0][(d0s + j) * PITCH + sl] = (unsigned short)u0[j];
#pragma unroll
    for (int j = 0; j < 8; ++j) Vs[0][(d0s + 8 + j) * PITCH + sl] = (unsigned short)u1[j];
    if (tid < 64) mks[0][tid] = mask[b * T + tid];
  }
  __syncthreads();  // also publishes qekl

  float m_run = -1e30f, l_run = 0.f;
  f32x4 oacc[4] = {};
  int cur = 0;
  sh8 kr0, kr1, vr0, vr1;
  float mkr = 0.f;

  for (int s0 = 0; s0 < T; s0 += 64) {
    const int nxt = cur ^ 1;
    const bool more = (s0 + 64 < T);
    // prefetch next tile into registers (latency hides under compute)
    if (more) {
      const unsigned short* srck = kh + (size_t)(s0 + 64 + sl) * C + d0s;
      kr0 = *(const sh8*)(srck);
      kr1 = *(const sh8*)(srck + 8);
      const unsigned short* srcv = vh + (size_t)(s0 + 64 + sl) * C + d0s;
      vr0 = *(const sh8*)(srcv);
      vr1 = *(const sh8*)(srcv + 8);
      if (tid < 64) mkr = mask[b * T + s0 + 64 + tid];
    }

    // QK^T (swapped): rows=s, cols=t
    float p[16];
#pragma unroll
    for (int n = 0; n < 4; ++n) {
      const sh8 a0 = *(const sh8*)&Ks[cur][(n * 16 + l15) * PITCH + lhi * 8];
      const sh8 a1 = *(const sh8*)&Ks[cur][(n * 16 + l15) * PITCH + 32 + lhi * 8];
      f32x4 acc = {};
      acc = __builtin_amdgcn_mfma_f32_16x16x32_bf16(a0, bq0, acc, 0, 0, 0);
      acc = __builtin_amdgcn_mfma_f32_16x16x32_bf16(a1, bq1, acc, 0, 0, 0);
#pragma unroll
      for (int r = 0; r < 4; ++r) {
        const int s = s0 + n * 16 + lhi * 4 + r;
        float v = acc[r] * 0.125f;
        const int j = s - t + 4;
        if ((unsigned)j < 9u) v += qekl[t_loc * 12 + j];
        if (mask_t * mks[cur][s - s0] == 0.f) v = -10000.0f;
        p[n * 4 + r] = v;
      }
    }
    // online softmax
    float mloc = p[0];
#pragma unroll
    for (int i = 1; i < 16; ++i) mloc = fmaxf(mloc, p[i]);
    mloc = fmaxf(mloc, __shfl_xor(mloc, 16));
    mloc = fmaxf(mloc, __shfl_xor(mloc, 32));
    const float m_new = fmaxf(m_run, mloc);
    const float f = __expf(m_run - m_new);
    float sloc = 0.f;
#pragma unroll
    for (int i = 0; i < 16; ++i) { p[i] = __expf(p[i] - m_new); sloc += p[i]; }
    sloc += __shfl_xor(sloc, 16);
    sloc += __shfl_xor(sloc, 32);
    l_run = l_run * f + sloc;
    m_run = m_new;
#pragma unroll
    for (int m = 0; m < 4; ++m)
#pragma unroll
      for (int r = 0; r < 4; ++r) oacc[m][r] *= f;
#pragma unroll
    for (int n = 0; n < 4; ++n) {
      uint2 pk;
      pk.x = (unsigned)f2b(p[n * 4 + 0]) | ((unsigned)f2b(p[n * 4 + 1]) << 16);
      pk.y = (unsigned)f2b(p[n * 4 + 2]) | ((unsigned)f2b(p[n * 4 + 3]) << 16);
      *(uint2*)&Ps[t_loc * PITCH + n * 16 + lhi * 4] = pk;
    }
    asm volatile("s_waitcnt lgkmcnt(0)" ::: "memory");
    const sh8 bp0 = *(const sh8*)&Ps[t_loc * PITCH + lhi * 8];
    const sh8 bp1 = *(const sh8*)&Ps[t_loc * PITCH + 32 + lhi * 8];
#pragma unroll
    for (int m = 0; m < 4; ++m) {
      const sh8 a0 = *(const sh8*)&Vs[cur][(m * 16 + l15) * PITCH + lhi * 8];
      const sh8 a1 = *(const sh8*)&Vs[cur][(m * 16 + l15) * PITCH + 32 + lhi * 8];
      oacc[m] = __builtin_amdgcn_mfma_f32_16x16x32_bf16(a0, bp0, oacc[m], 0, 0, 0);
      oacc[m] = __builtin_amdgcn_mfma_f32_16x16x32_bf16(a1, bp1, oacc[m], 0, 0, 0);
    }
    // v-band epilogue
    if (t + 4 >= s0 && t < s0 + 68) {
#pragma unroll
      for (int j = 0; j < 9; ++j) {
        const int s = t + j - 4;
        if (s >= s0 && s < s0 + 64) {
          const float pv = b2f(Ps[t_loc * PITCH + (s - s0)]);
#pragma unroll
          for (int m = 0; m < 4; ++m)
#pragma unroll
            for (int r = 0; r < 4; ++r)
              oacc[m][r] = fmaf(pv, evs[(m * 16 + lhi * 4 + r) * 9 + j], oacc[m][r]);
        }
      }
    }
    // write prefetched tile into buf[nxt]
    if (more) {
      *(sh8*)&Ks[nxt][sl * PITCH + d0s]     = kr0;
      *(sh8*)&Ks[nxt][sl * PITCH + d0s + 8] = kr1;
#pragma unroll
      for (int j = 0; j < 8; ++j) Vs[nxt][(d0s + j) * PITCH + sl] = (unsigned short)vr0[j];
#pragma unroll
      for (int j = 0; j < 8; ++j) Vs[nxt][(d0s + 8 + j) * PITCH + sl] = (unsigned short)vr1[j];
      if (tid < 64) mks[nxt][tid] = mkr;
    }
    __syncthreads();
    cur = nxt;
  }
  const float invl = 1.f / l_run;
  unsigned short* ob = outp + (size_t)(b * T + t) * C + h * D;
#pragma unroll
  for (int m = 0; m < 4; ++m) {
    ushort4 hz;
    hz.x = f2b(oacc[m][0] * invl);
    hz.y = f2b(oacc[m][1] * invl);
    hz.z = f2b(oacc[m][2] * invl);
    hz.w = f2b(oacc[m][3] * invl);
    *(ushort4*)(ob + m * 16 + lhi * 4) = hz;
  }
}

// ---------------------------------------------------------------------------
// dst = LayerNorm_C(x + sum_p y_p) ; y partials t-major [NP][B][T][C] fp32.
template <int NP, bool MASKY, bool MASKF>
__global__ __launch_bounds__(256) void add_norm_kernel(
    const float* __restrict__ x, const float* __restrict__ ypart,
    const float* __restrict__ g, const float* __restrict__ bta,
    const float* __restrict__ mask, float* __restrict__ dst,
    unsigned short* __restrict__ dsth)
{
  constexpr int NQ = C / 16;  // 48
  const int b = blockIdx.y;
  const int t0 = blockIdx.x * 16;
  const int r = threadIdx.x >> 4, tc = threadIdx.x & 15;
  const int t = t0 + tc;
  const float* xb = x + (size_t)b * C * T;
  const float mkt = mask[b * T + t];
  float vv[NQ];
  float sum = 0.f, sq = 0.f;
#pragma unroll
  for (int q = 0; q < NQ; ++q) {
    const int ci = r + q * 16;
    float y = 0.f;
#pragma unroll
    for (int p = 0; p < NP; ++p)
      y += ypart[(((size_t)p * B + b) * T + t) * C + ci];
    if (MASKY) y *= mkt;
    const float v = xb[(size_t)ci * T + t] + y;
    vv[q] = v;
    sum += v;
    sq = fmaf(v, v, sq);
  }
  __shared__ float ssum[16][17], ssq[16][17];
  __shared__ float mean_s[16], rstd_s[16];
  ssum[r][tc] = sum;
  ssq[r][tc] = sq;
  __syncthreads();
  if (r == 0) {
    float s = 0.f, q2 = 0.f;
#pragma unroll
    for (int i = 0; i < 16; ++i) { s += ssum[i][tc]; q2 += ssq[i][tc]; }
    const float m = s / C;
    mean_s[tc] = m;
    rstd_s[tc] = rsqrtf(q2 / C - m * m + 1e-5f);
  }
  __syncthreads();
  const float m = mean_s[tc], rs = rstd_s[tc];
  float* db = dst + (size_t)b * C * T;
  unsigned short* dbh = dsth + ((size_t)b * T + t) * C;
#pragma unroll
  for (int q = 0; q < NQ; ++q) {
    const int ci = r + q * 16;
    float o = (vv[q] - m) * rs * g[ci] + bta[ci];
    if (MASKF) o *= mkt;
    db[(size_t)ci * T + t] = o;
    dbh[ci] = f2b(MASKF ? o : o * mkt);
  }
}

}  // namespace

extern "C" void kernel_launch(void* const* d_in, const int* in_sizes, int n_in,
                              void* d_out, int out_size, void* d_ws, size_t ws_size,
                              hipStream_t stream) {
  const float* x_in = (const float*)d_in[0];
  const float* mask = (const float*)d_in[1];
  const float* Wq = (const float*)d_in[2];
  const float* bq = (const float*)d_in[3];
  const float* Wk = (const float*)d_in[4];
  const float* bk = (const float*)d_in[5];
  const float* Wv = (const float*)d_in[6];
  const float* bv = (const float*)d_in[7];
  const float* Wo = (const float*)d_in[8];
  const float* bo = (const float*)d_in[9];
  const float* ek = (const float*)d_in[10];
  const float* ev = (const float*)d_in[11];
  const float* w1 = (const float*)d_in[12];
  const float* b1 = (const float*)d_in[13];
  const float* w2 = (const float*)d_in[14];
  const float* b2 = (const float*)d_in[15];
  const float* n1g = (const float*)d_in[16];
  const float* n1b = (const float*)d_in[17];
  const float* n2g = (const float*)d_in[18];
  const float* n2b = (const float*)d_in[19];

  float* ws = (float*)d_ws;
  const size_t SZ_X = (size_t)B * C * T;
  float* xb    = ws;                              // residual fp32 [B][C][T]
  float* ypart = xb + SZ_X;                       // [4][B][T][C] fp32 partials
  unsigned short* xbh = (unsigned short*)(ypart + 4 * SZ_X);
  unsigned short* xfh = xbh + SZ_X;
  unsigned short* qbh = xfh + SZ_X;
  unsigned short* kbh = qbh + SZ_X;
  unsigned short* vbh = kbh + SZ_X;
  unsigned short* hidh = vbh + SZ_X;              // [B][T][FF]
  unsigned short* w1t = hidh + (size_t)B * FF * T;
  unsigned short* w2t = w1t + (size_t)3 * FF * C;
  unsigned short* wqt = w2t + (size_t)3 * FF * C;
  unsigned short* wkt = wqt + (size_t)C * C;
  unsigned short* wvt = wkt + (size_t)C * C;
  unsigned short* wot = wvt + (size_t)C * C;
  float* outp = (float*)d_out;

  const dim3 blk(256);
  const dim3 blk512(512);
  transpose_cvt<<<dim3(T / 32, C / 32, B), blk, 0, stream>>>(x_in, xbh);

  for (int i = 0; i < NL; ++i) {
    const float* xs = (i == 0) ? x_in : xb;
    const size_t wOff = (size_t)i * C * C;
    cvt_qkvo_tiled<<<dim3((C * C / 8) / 256, 4), blk, 0, stream>>>(
        Wq + wOff, Wk + wOff, Wv + wOff, Wo + wOff, wqt, wkt, wvt, wot);
    cvt_ffn_tiled<<<dim3((FF * C / 8) / 256, 2), blk, 0, stream>>>(
        w1 + (size_t)i * FF * C * 3, w2 + (size_t)i * C * FF * 3, w1t, w2t);
    // QKV projection (288 blocks x 512 thr, BN=128)
    mfma_conv512<1, 1, false, false, true><<<dim3(4 * 18 * B), blk512, 0, stream>>>(
        xbh, wqt, wkt, wvt, bq + i * C, bk + i * C, bv + i * C, mask,
        qbh, kbh, vbh, C, C, 6, 18);
    // fused attention
    fused_attn<<<dim3(T / 64, B * H), blk, 0, stream>>>(
        qbh, kbh, vbh, mask, ek + (size_t)i * D * 9, ev + (size_t)i * D * 9, hidh);
    // Wo projection: split-K2 -> fp32 partials (384 blocks x 256 thr)
    mfma_conv<1, 2, false, false, false><<<dim3(8, 6, B * 2), blk, 0, stream>>>(
        hidh, wot, wot, wot, bo + i * C, bo + i * C, bo + i * C, mask,
        ypart, ypart, ypart, C, C, 6);
    add_norm_kernel<2, false, false><<<dim3(T / 16, B), blk, 0, stream>>>(
        xs, ypart, n1g + i * C, n1b + i * C, mask, xb, xfh);
    // FFN up: 3 taps, GELU+mask, bf16 out (384 blocks x 512 thr)
    mfma_conv512<3, 1, true, true, true><<<dim3(4 * 24 * B), blk512, 0, stream>>>(
        xfh, w1t, w1t, w1t, b1 + i * FF, b1 + i * FF, b1 + i * FF, mask,
        hidh, hidh, hidh, C, FF, 24, 24);
    // FFN down: 3 taps, split-K4 -> fp32 partials (384 blocks x 512 thr)
    mfma_conv512<3, 4, false, false, false><<<dim3(4 * 6 * B * 4), blk512, 0, stream>>>(
        hidh, w2t, w2t, w2t, b2 + i * C, b2 + i * C, b2 + i * C, mask,
        ypart, ypart, ypart, FF, C, 6, 6);
    add_norm_kernel<4, true, true><<<dim3(T / 16, B), blk, 0, stream>>>(
        xb, ypart, n2g + i * C, n2b + i * C, mask, (i == NL - 1) ? outp : xb, xbh);
  }
}

// Round 9
// 1370.125 us; speedup vs baseline: 1.6614x; 1.0363x over previous
//
#include <hip/hip_runtime.h>
#include <cstddef>

namespace {

constexpr int B  = 4;
constexpr int C  = 768;
constexpr int T  = 512;
constexpr int H  = 12;
constexpr int D  = 64;
constexpr int NL = 6;
constexpr int W  = 4;
constexpr int FF = 3072;

typedef __attribute__((ext_vector_type(8))) short sh8;
typedef __attribute__((ext_vector_type(4))) float f32x4;

__device__ inline float gelu_exact(float x) {
  return 0.5f * x * (1.0f + erff(x * 0.70710678118654752440f));
}
__device__ inline unsigned short f2b(float f) {
  unsigned u = __float_as_uint(f);
  unsigned r = (u + 0x7fffu + ((u >> 16) & 1u)) >> 16;
  return (unsigned short)r;
}
__device__ inline float b2f(unsigned short u) {
  return __uint_as_float((unsigned)u << 16);
}
__device__ inline void gload_lds16(const void* g, void* l) {
  __builtin_amdgcn_global_load_lds(
      (const __attribute__((address_space(1))) unsigned int*)g,
      (__attribute__((address_space(3))) unsigned int*)l, 16, 0, 0);
}

// ---------------------------------------------------------------------------
// Layer-0 input: x [B][C][T] fp32 c-major -> bf16 t-major + fp32 t-major
__global__ __launch_bounds__(256) void transpose_cvt_in(
    const float* __restrict__ s, unsigned short* __restrict__ dh,
    float* __restrict__ df)
{
  __shared__ float tile[32][33];
  const int b = blockIdx.z;
  const int c0 = blockIdx.y * 32, t0 = blockIdx.x * 32;
  const int tx = threadIdx.x & 31, ty = threadIdx.x >> 5;
  const float* sp = s + ((size_t)b * C + c0) * T + t0;
#pragma unroll
  for (int i = 0; i < 4; ++i)
    tile[ty + i * 8][tx] = sp[(size_t)(ty + i * 8) * T + tx];
  __syncthreads();
  unsigned short* dph = dh + ((size_t)b * T + t0) * C + c0;
  float* dpf = df + ((size_t)b * T + t0) * C + c0;
#pragma unroll
  for (int i = 0; i < 4; ++i) {
    const float v = tile[tx][ty + i * 8];
    dph[(size_t)(ty + i * 8) * C + tx] = f2b(v);
    dpf[(size_t)(ty + i * 8) * C + tx] = v;
  }
}

// Final residual: fp32 t-major [B][T][C] -> fp32 c-major [B][C][T]
__global__ __launch_bounds__(256) void transpose_out(
    const float* __restrict__ s, float* __restrict__ d)
{
  __shared__ float tile[32][33];
  const int b = blockIdx.z;
  const int c0 = blockIdx.y * 32, t0 = blockIdx.x * 32;
  const int tx = threadIdx.x & 31, ty = threadIdx.x >> 5;
  const float* sp = s + ((size_t)b * T + t0) * C + c0;
#pragma unroll
  for (int i = 0; i < 4; ++i)
    tile[ty + i * 8][tx] = sp[(size_t)(ty + i * 8) * C + tx];  // row=t, col=c
  __syncthreads();
  float* dp = d + ((size_t)b * C + c0) * T + t0;
#pragma unroll
  for (int i = 0; i < 4; ++i)
    dp[(size_t)(ty + i * 8) * T + tx] = tile[tx][ty + i * 8];
}

// QKVO weights fp32 [C][C] -> bf16 MFMA-fragment-tiled
__global__ __launch_bounds__(256) void cvt_qkvo_tiled(
    const float* __restrict__ q, const float* __restrict__ k,
    const float* __restrict__ v, const float* __restrict__ o,
    unsigned short* __restrict__ dq, unsigned short* __restrict__ dk,
    unsigned short* __restrict__ dv, unsigned short* __restrict__ dov)
{
  const int z = blockIdx.y;
  const float* s = z == 0 ? q : z == 1 ? k : z == 2 ? v : o;
  unsigned short* d = z == 0 ? dq : z == 1 ? dk : z == 2 ? dv : dov;
  const int flat = blockIdx.x * 256 + threadIdx.x;   // over C*C/8
  const int row = flat / (C / 8);
  const int c   = (flat % (C / 8)) * 8;
  const int ks = c >> 5, lhi = (c >> 3) & 3, mt = row >> 4, l15 = row & 15;
  const float* sp = s + (size_t)row * C + c;
  float4 a = *(const float4*)(sp);
  float4 b = *(const float4*)(sp + 4);
  sh8 u;
  u[0] = (short)f2b(a.x); u[1] = (short)f2b(a.y);
  u[2] = (short)f2b(a.z); u[3] = (short)f2b(a.w);
  u[4] = (short)f2b(b.x); u[5] = (short)f2b(b.y);
  u[6] = (short)f2b(b.z); u[7] = (short)f2b(b.w);
  *(sh8*)(d + ((size_t)(mt * (C / 32) + ks) * 64 + lhi * 16 + l15) * 8) = u;
}

// FFN weights [O][Ci][3] fp32 -> 3 tap planes, each fragment-tiled bf16.
__global__ __launch_bounds__(256) void cvt_ffn_tiled(
    const float* __restrict__ s1, const float* __restrict__ s2,
    unsigned short* __restrict__ d1, unsigned short* __restrict__ d2)
{
  const int z = blockIdx.y;
  const float* src = z ? s2 : s1;
  unsigned short* dst = z ? d2 : d1;
  const int O  = z ? C : FF;
  const int Ci = z ? FF : C;
  const int flat = blockIdx.x * 256 + threadIdx.x;   // over O*Ci/8
  const int row = flat / (Ci / 8);
  const int c   = (flat % (Ci / 8)) * 8;
  const int ks = c >> 5, lhi = (c >> 3) & 3, mt = row >> 4, l15 = row & 15;
  const float* sp = src + ((size_t)row * Ci + c) * 3;
  float f[24];
#pragma unroll
  for (int i = 0; i < 6; ++i) {
    float4 t4 = *(const float4*)(sp + i * 4);
    f[i * 4 + 0] = t4.x; f[i * 4 + 1] = t4.y; f[i * 4 + 2] = t4.z; f[i * 4 + 3] = t4.w;
  }
  const size_t fragoff =
      ((size_t)(mt * (Ci / 32) + ks) * 64 + lhi * 16 + l15) * 8;
#pragma unroll
  for (int tap = 0; tap < 3; ++tap) {
    sh8 u;
#pragma unroll
    for (int j = 0; j < 8; ++j) u[j] = (short)f2b(f[j * 3 + tap]);
    *(sh8*)(dst + (size_t)tap * O * Ci + fragoff) = u;
  }
}

// ---------------------------------------------------------------------------
// 256-thread MFMA conv (BM=128 x BN=64), 2-phase double-buffered.
template <int TAPS, int KSPLIT, bool GELU, bool MASK_OUT, bool OBF16>
__global__ __launch_bounds__(256) void mfma_conv(
    const unsigned short* __restrict__ xin,
    const unsigned short* __restrict__ w0p, const unsigned short* __restrict__ w1p,
    const unsigned short* __restrict__ w2p,
    const float* __restrict__ b0, const float* __restrict__ b1,
    const float* __restrict__ b2,
    const float* __restrict__ mask,
    void* __restrict__ o0p, void* __restrict__ o1p, void* __restrict__ o2p,
    int Cin, int O, int tilesPerPlane)
{
  constexpr int BN = 64;
  constexpr int ROWS_B = BN + TAPS - 1;
  constexpr int PB = 40;
  __shared__ unsigned short Aw[2][TAPS * 8 * 512];
  __shared__ unsigned short Bx[2][ROWS_B * PB];

  const int zz = blockIdx.z;
  const int b  = zz / KSPLIT;
  const int kk = zz % KSPLIT;
  const int TOFF = (TAPS == 3) ? -1 : 0;
  const int t0 = blockIdx.x * BN;
  const int plane = blockIdx.y / tilesPerPlane;
  const int mt0 = (blockIdx.y % tilesPerPlane) * 8;
  const int o0 = mt0 * 16;

  const int tid = threadIdx.x;
  const int lane = tid & 63, wid = tid >> 6;
  const int wm = wid >> 1, wn = wid & 1;
  const int l15 = lane & 15, lhi = lane >> 4;
  const int bmask = b * T;

  const unsigned short* wsel = plane == 0 ? w0p : (plane == 1 ? w1p : w2p);
  const float* bp = plane == 0 ? b0 : (plane == 1 ? b1 : b2);

  const int KST = Cin >> 5;
  const int kchunk = KST / KSPLIT;
  const int ks0 = kk * kchunk, ks1 = ks0 + kchunk;
  const int OT = O >> 4;

  const int brow = tid >> 2, bcl = (tid & 3) << 3;
  const unsigned short* xb_ = xin + (size_t)b * T * Cin;

  sh8 breg, breg2;
  auto stageA = [&](int ks, int buf) {
#pragma unroll
    for (int tap = 0; tap < TAPS; ++tap) {
#pragma unroll
      for (int j = 0; j < 2; ++j) {
        const int rt = wid * 2 + j;
        const unsigned short* src =
            wsel + (((size_t)tap * OT + mt0 + rt) * KST + ks) * 512 + lane * 8;
        gload_lds16(src, &Aw[buf][(tap * 8 + rt) * 512]);
      }
    }
  };
  auto loadB = [&](int ks) {
    const int c0 = ks << 5;
    const unsigned short* xrow = xb_ + c0 + bcl;
    const int tsrc = t0 + brow + TOFF;
    breg = (sh8)0;
    if ((unsigned)tsrc < (unsigned)T)
      breg = *(const sh8*)(xrow + (size_t)tsrc * Cin);
    if constexpr (TAPS == 3) {
      breg2 = (sh8)0;
      if (tid < 8) {
        const int ts2 = t0 + BN + (tid >> 2) + TOFF;
        if ((unsigned)ts2 < (unsigned)T)
          breg2 = *(const sh8*)(xrow + (size_t)ts2 * Cin);
      }
    }
  };
  auto writeB = [&](int buf) {
    *(sh8*)&Bx[buf][brow * PB + bcl] = breg;
    if constexpr (TAPS == 3) {
      if (tid < 8)
        *(sh8*)&Bx[buf][(BN + (tid >> 2)) * PB + bcl] = breg2;
    }
  };

  f32x4 acc[4][2] = {};

  int cur = 0;
  stageA(ks0, 0);
  loadB(ks0);
  writeB(0);
  __syncthreads();

  for (int ks = ks0; ks < ks1; ++ks) {
    const int nxt = cur ^ 1;
    const bool more = (ks + 1 < ks1);
    if (more) { stageA(ks + 1, nxt); loadB(ks + 1); }
#pragma unroll
    for (int tap = 0; tap < TAPS; ++tap) {
      sh8 af[4], bfr[2];
#pragma unroll
      for (int m = 0; m < 4; ++m)
        af[m] = *(const sh8*)&Aw[cur][(tap * 8 + wm * 4 + m) * 512 + lane * 8];
#pragma unroll
      for (int n = 0; n < 2; ++n)
        bfr[n] = *(const sh8*)&Bx[cur][(wn * 32 + n * 16 + l15 + tap) * PB + lhi * 8];
#pragma unroll
      for (int m = 0; m < 4; ++m)
#pragma unroll
        for (int n = 0; n < 2; ++n)
          acc[m][n] = __builtin_amdgcn_mfma_f32_16x16x32_bf16(
              af[m], bfr[n], acc[m][n], 0, 0, 0);
    }
    if (more) writeB(nxt);
    __syncthreads();
    cur = nxt;
  }

  void* obase = plane == 0 ? o0p : (plane == 1 ? o1p : o2p);
  unsigned short* oph = (unsigned short*)obase + (size_t)b * T * O;
  float* opf = (float*)obase + ((size_t)kk * B + b) * (size_t)T * O;
#pragma unroll
  for (int m = 0; m < 4; ++m) {
    const int o = o0 + (wm * 4 + m) * 16 + (lhi << 2);
#pragma unroll
    for (int n = 0; n < 2; ++n) {
      const int t = t0 + wn * 32 + n * 16 + l15;
      const float mk = MASK_OUT ? mask[bmask + t] : 1.f;
      float v[4];
#pragma unroll
      for (int r4 = 0; r4 < 4; ++r4) {
        float x = acc[m][n][r4];
        if (KSPLIT > 1) {
          if (kk == 0) x += bp[o + r4];
        } else {
          x += bp[o + r4];
        }
        if (GELU) x = gelu_exact(x);
        if (MASK_OUT) x *= mk;
        v[r4] = x;
      }
      if constexpr (OBF16) {
        ushort4 hz;
        hz.x = f2b(v[0]); hz.y = f2b(v[1]); hz.z = f2b(v[2]); hz.w = f2b(v[3]);
        *(ushort4*)(oph + (size_t)t * O + o) = hz;
      } else {
        *(float4*)(opf + (size_t)t * O + o) = make_float4(v[0], v[1], v[2], v[3]);
      }
    }
  }
}

// ---------------------------------------------------------------------------
// Fused attention with 2-phase K/V prefetch. q/k/v/out t-major bf16 [B][T][C].
__global__ __launch_bounds__(256) void fused_attn(
    const unsigned short* __restrict__ qg,
    const unsigned short* __restrict__ kg,
    const unsigned short* __restrict__ vg,
    const float* __restrict__ mask,
    const float* __restrict__ ek,
    const float* __restrict__ ev,
    unsigned short* __restrict__ outp)
{
  constexpr int PITCH = 72;
  __shared__ unsigned short Qs[64 * PITCH];     // [t][d]
  __shared__ unsigned short Ks[2][64 * PITCH];  // [s][d]
  __shared__ unsigned short Vs[2][64 * PITCH];  // [d][s]
  __shared__ unsigned short Ps[64 * PITCH];     // [t][s]
  __shared__ float eks[D * 9], evs[D * 9];
  __shared__ float qekl[64 * 12];
  __shared__ float mks[2][64];

  const int t0 = blockIdx.x * 64;
  const int bh = blockIdx.y;
  const int b = bh / H, h = bh % H;
  const int tid = threadIdx.x;
  const int lane = tid & 63, w = tid >> 6;
  const int l15 = lane & 15, lhi = lane >> 4;

  const size_t base = (size_t)b * T * C + h * D;
  const unsigned short* qh = qg + base;
  const unsigned short* kh = kg + base;
  const unsigned short* vh = vg + base;

  for (int e = tid; e < D * 9; e += 256) { eks[e] = ek[e]; evs[e] = ev[e]; }
  {
    const int tl = tid & 63, d0 = (tid >> 6) << 4;
    const unsigned short* src = qh + (size_t)(t0 + tl) * C + d0;
    *(sh8*)&Qs[tl * PITCH + d0]     = *(const sh8*)(src);
    *(sh8*)&Qs[tl * PITCH + d0 + 8] = *(const sh8*)(src + 8);
  }
  __syncthreads();
  {
    const int tl = tid & 63, g = tid >> 6;
    for (int j = g; j < 9; j += 4) {
      float a = 0.f;
      for (int d = 0; d < D; ++d)
        a = fmaf(b2f(Qs[tl * PITCH + d]), eks[d * 9 + j], a);
      qekl[tl * 12 + j] = a * 0.125f;
    }
  }
  const int t_loc = w * 16 + l15;
  const int t = t0 + t_loc;
  const float mask_t = mask[b * T + t];
  const sh8 bq0 = *(const sh8*)&Qs[t_loc * PITCH + lhi * 8];
  const sh8 bq1 = *(const sh8*)&Qs[t_loc * PITCH + 32 + lhi * 8];

  const int sl = tid & 63, d0s = (tid >> 6) << 4;
  {
    const unsigned short* srck = kh + (size_t)sl * C + d0s;
    *(sh8*)&Ks[0][sl * PITCH + d0s]     = *(const sh8*)(srck);
    *(sh8*)&Ks[0][sl * PITCH + d0s + 8] = *(const sh8*)(srck + 8);
    const unsigned short* srcv = vh + (size_t)sl * C + d0s;
    sh8 u0 = *(const sh8*)(srcv);
    sh8 u1 = *(const sh8*)(srcv + 8);
#pragma unroll
    for (int j = 0; j < 8; ++j) Vs[0][(d0s + j) * PITCH + sl] = (unsigned short)u0[j];
#pragma unroll
    for (int j = 0; j < 8; ++j) Vs[0][(d0s + 8 + j) * PITCH + sl] = (unsigned short)u1[j];
    if (tid < 64) mks[0][tid] = mask[b * T + tid];
  }
  __syncthreads();

  float m_run = -1e30f, l_run = 0.f;
  f32x4 oacc[4] = {};
  int cur = 0;
  sh8 kr0, kr1, vr0, vr1;
  float mkr = 0.f;

  for (int s0 = 0; s0 < T; s0 += 64) {
    const int nxt = cur ^ 1;
    const bool more = (s0 + 64 < T);
    if (more) {
      const unsigned short* srck = kh + (size_t)(s0 + 64 + sl) * C + d0s;
      kr0 = *(const sh8*)(srck);
      kr1 = *(const sh8*)(srck + 8);
      const unsigned short* srcv = vh + (size_t)(s0 + 64 + sl) * C + d0s;
      vr0 = *(const sh8*)(srcv);
      vr1 = *(const sh8*)(srcv + 8);
      if (tid < 64) mkr = mask[b * T + s0 + 64 + tid];
    }

    float p[16];
#pragma unroll
    for (int n = 0; n < 4; ++n) {
      const sh8 a0 = *(const sh8*)&Ks[cur][(n * 16 + l15) * PITCH + lhi * 8];
      const sh8 a1 = *(const sh8*)&Ks[cur][(n * 16 + l15) * PITCH + 32 + lhi * 8];
      f32x4 acc = {};
      acc = __builtin_amdgcn_mfma_f32_16x16x32_bf16(a0, bq0, acc, 0, 0, 0);
      acc = __builtin_amdgcn_mfma_f32_16x16x32_bf16(a1, bq1, acc, 0, 0, 0);
#pragma unroll
      for (int r = 0; r < 4; ++r) {
        const int s = s0 + n * 16 + lhi * 4 + r;
        float v = acc[r] * 0.125f;
        const int j = s - t + 4;
        if ((unsigned)j < 9u) v += qekl[t_loc * 12 + j];
        if (mask_t * mks[cur][s - s0] == 0.f) v = -10000.0f;
        p[n * 4 + r] = v;
      }
    }
    float mloc = p[0];
#pragma unroll
    for (int i = 1; i < 16; ++i) mloc = fmaxf(mloc, p[i]);
    mloc = fmaxf(mloc, __shfl_xor(mloc, 16));
    mloc = fmaxf(mloc, __shfl_xor(mloc, 32));
    const float m_new = fmaxf(m_run, mloc);
    const float f = __expf(m_run - m_new);
    float sloc = 0.f;
#pragma unroll
    for (int i = 0; i < 16; ++i) { p[i] = __expf(p[i] - m_new); sloc += p[i]; }
    sloc += __shfl_xor(sloc, 16);
    sloc += __shfl_xor(sloc, 32);
    l_run = l_run * f + sloc;
    m_run = m_new;
#pragma unroll
    for (int m = 0; m < 4; ++m)
#pragma unroll
      for (int r = 0; r < 4; ++r) oacc[m][r] *= f;
#pragma unroll
    for (int n = 0; n < 4; ++n) {
      uint2 pk;
      pk.x = (unsigned)f2b(p[n * 4 + 0]) | ((unsigned)f2b(p[n * 4 + 1]) << 16);
      pk.y = (unsigned)f2b(p[n * 4 + 2]) | ((unsigned)f2b(p[n * 4 + 3]) << 16);
      *(uint2*)&Ps[t_loc * PITCH + n * 16 + lhi * 4] = pk;
    }
    asm volatile("s_waitcnt lgkmcnt(0)" ::: "memory");
    const sh8 bp0 = *(const sh8*)&Ps[t_loc * PITCH + lhi * 8];
    const sh8 bp1 = *(const sh8*)&Ps[t_loc * PITCH + 32 + lhi * 8];
#pragma unroll
    for (int m = 0; m < 4; ++m) {
      const sh8 a0 = *(const sh8*)&Vs[cur][(m * 16 + l15) * PITCH + lhi * 8];
      const sh8 a1 = *(const sh8*)&Vs[cur][(m * 16 + l15) * PITCH + 32 + lhi * 8];
      oacc[m] = __builtin_amdgcn_mfma_f32_16x16x32_bf16(a0, bp0, oacc[m], 0, 0, 0);
      oacc[m] = __builtin_amdgcn_mfma_f32_16x16x32_bf16(a1, bp1, oacc[m], 0, 0, 0);
    }
    if (t + 4 >= s0 && t < s0 + 68) {
#pragma unroll
      for (int j = 0; j < 9; ++j) {
        const int s = t + j - 4;
        if (s >= s0 && s < s0 + 64) {
          const float pv = b2f(Ps[t_loc * PITCH + (s - s0)]);
#pragma unroll
          for (int m = 0; m < 4; ++m)
#pragma unroll
            for (int r = 0; r < 4; ++r)
              oacc[m][r] = fmaf(pv, evs[(m * 16 + lhi * 4 + r) * 9 + j], oacc[m][r]);
        }
      }
    }
    if (more) {
      *(sh8*)&Ks[nxt][sl * PITCH + d0s]     = kr0;
      *(sh8*)&Ks[nxt][sl * PITCH + d0s + 8] = kr1;
#pragma unroll
      for (int j = 0; j < 8; ++j) Vs[nxt][(d0s + j) * PITCH + sl] = (unsigned short)vr0[j];
#pragma unroll
      for (int j = 0; j < 8; ++j) Vs[nxt][(d0s + 8 + j) * PITCH + sl] = (unsigned short)vr1[j];
      if (tid < 64) mks[nxt][tid] = mkr;
    }
    __syncthreads();
    cur = nxt;
  }
  const float invl = 1.f / l_run;
  unsigned short* ob = outp + (size_t)(b * T + t) * C + h * D;
#pragma unroll
  for (int m = 0; m < 4; ++m) {
    ushort4 hz;
    hz.x = f2b(oacc[m][0] * invl);
    hz.y = f2b(oacc[m][1] * invl);
    hz.z = f2b(oacc[m][2] * invl);
    hz.w = f2b(oacc[m][3] * invl);
    *(ushort4*)(ob + m * 16 + lhi * 4) = hz;
  }
}

// ---------------------------------------------------------------------------
// Wave-per-t add+layernorm, everything t-major.
// dst = LN_C(x + sum_p y_p); y partials [NP][B][T][C] fp32; x [B][T][C] fp32.
// dst fp32 t-major; dsth bf16 t-major (mask pre-applied when !MASKF).
template <int NP, bool MASKY, bool MASKF>
__global__ __launch_bounds__(256) void add_norm_wave(
    const float* __restrict__ xr, const float* __restrict__ ypart,
    const float* __restrict__ g, const float* __restrict__ bta,
    const float* __restrict__ mask, float* __restrict__ dst,
    unsigned short* __restrict__ dsth)
{
  const int b = blockIdx.y;
  const int t = blockIdx.x * 4 + (threadIdx.x >> 6);
  const int lane = threadIdx.x & 63;
  const float mkt = mask[b * T + t];
  const size_t rowoff = ((size_t)b * T + t) * C;
  const int ci0 = lane * 12;

  float vv[12];
  float sum = 0.f, sq = 0.f;
#pragma unroll
  for (int q = 0; q < 3; ++q) {
    const int ci = ci0 + q * 4;
    float4 xv = *(const float4*)(xr + rowoff + ci);
    float4 yv = make_float4(0.f, 0.f, 0.f, 0.f);
#pragma unroll
    for (int p = 0; p < NP; ++p) {
      float4 t4 = *(const float4*)(ypart + (size_t)p * B * T * C + rowoff + ci);
      yv.x += t4.x; yv.y += t4.y; yv.z += t4.z; yv.w += t4.w;
    }
    if (MASKY) { yv.x *= mkt; yv.y *= mkt; yv.z *= mkt; yv.w *= mkt; }
    const float v0 = xv.x + yv.x, v1 = xv.y + yv.y;
    const float v2 = xv.z + yv.z, v3 = xv.w + yv.w;
    vv[q * 4 + 0] = v0; vv[q * 4 + 1] = v1; vv[q * 4 + 2] = v2; vv[q * 4 + 3] = v3;
    sum += v0 + v1 + v2 + v3;
    sq = fmaf(v0, v0, fmaf(v1, v1, fmaf(v2, v2, fmaf(v3, v3, sq))));
  }
#pragma unroll
  for (int o = 32; o > 0; o >>= 1) {
    sum += __shfl_xor(sum, o);
    sq += __shfl_xor(sq, o);
  }
  const float m = sum * (1.f / C);
  const float rs = rsqrtf(sq * (1.f / C) - m * m + 1e-5f);
#pragma unroll
  for (int q = 0; q < 3; ++q) {
    const int ci = ci0 + q * 4;
    float4 gv = *(const float4*)(g + ci);
    float4 bv = *(const float4*)(bta + ci);
    float o0 = (vv[q * 4 + 0] - m) * rs * gv.x + bv.x;
    float o1 = (vv[q * 4 + 1] - m) * rs * gv.y + bv.y;
    float o2 = (vv[q * 4 + 2] - m) * rs * gv.z + bv.z;
    float o3 = (vv[q * 4 + 3] - m) * rs * gv.w + bv.w;
    if (MASKF) { o0 *= mkt; o1 *= mkt; o2 *= mkt; o3 *= mkt; }
    *(float4*)(dst + rowoff + ci) = make_float4(o0, o1, o2, o3);
    const float hm = MASKF ? 1.f : mkt;
    ushort4 hz;
    hz.x = f2b(o0 * hm); hz.y = f2b(o1 * hm); hz.z = f2b(o2 * hm); hz.w = f2b(o3 * hm);
    *(ushort4*)(dsth + rowoff + ci) = hz;
  }
}

}  // namespace

extern "C" void kernel_launch(void* const* d_in, const int* in_sizes, int n_in,
                              void* d_out, int out_size, void* d_ws, size_t ws_size,
                              hipStream_t stream) {
  const float* x_in = (const float*)d_in[0];
  const float* mask = (const float*)d_in[1];
  const float* Wq = (const float*)d_in[2];
  const float* bq = (const float*)d_in[3];
  const float* Wk = (const float*)d_in[4];
  const float* bk = (const float*)d_in[5];
  const float* Wv = (const float*)d_in[6];
  const float* bv = (const float*)d_in[7];
  const float* Wo = (const float*)d_in[8];
  const float* bo = (const float*)d_in[9];
  const float* ek = (const float*)d_in[10];
  const float* ev = (const float*)d_in[11];
  const float* w1 = (const float*)d_in[12];
  const float* b1 = (const float*)d_in[13];
  const float* w2 = (const float*)d_in[14];
  const float* b2 = (const float*)d_in[15];
  const float* n1g = (const float*)d_in[16];
  const float* n1b = (const float*)d_in[17];
  const float* n2g = (const float*)d_in[18];
  const float* n2b = (const float*)d_in[19];

  float* ws = (float*)d_ws;
  const size_t SZ_X = (size_t)B * C * T;
  float* xr    = ws;                              // residual fp32 [B][T][C]
  float* xr1   = xr + SZ_X;                       // post-norm1 fp32 [B][T][C]
  float* ypart = xr1 + SZ_X;                      // [4][B][T][C] fp32 partials
  unsigned short* xbh = (unsigned short*)(ypart + 4 * SZ_X);  // QKV input bf16
  unsigned short* xfh = xbh + SZ_X;               // FFN-up input bf16 (masked)
  unsigned short* qbh = xfh + SZ_X;
  unsigned short* kbh = qbh + SZ_X;
  unsigned short* vbh = kbh + SZ_X;
  unsigned short* hidh = vbh + SZ_X;              // [B][T][FF]
  unsigned short* w1t = hidh + (size_t)B * FF * T;
  unsigned short* w2t = w1t + (size_t)3 * FF * C;
  unsigned short* wqt = w2t + (size_t)3 * FF * C;
  unsigned short* wkt = wqt + (size_t)C * C;
  unsigned short* wvt = wkt + (size_t)C * C;
  unsigned short* wot = wvt + (size_t)C * C;
  float* outp = (float*)d_out;

  const dim3 blk(256);
  transpose_cvt_in<<<dim3(T / 32, C / 32, B), blk, 0, stream>>>(x_in, xbh, xr);

  for (int i = 0; i < NL; ++i) {
    const size_t wOff = (size_t)i * C * C;
    cvt_qkvo_tiled<<<dim3((C * C / 8) / 256, 4), blk, 0, stream>>>(
        Wq + wOff, Wk + wOff, Wv + wOff, Wo + wOff, wqt, wkt, wvt, wot);
    cvt_ffn_tiled<<<dim3((FF * C / 8) / 256, 2), blk, 0, stream>>>(
        w1 + (size_t)i * FF * C * 3, w2 + (size_t)i * C * FF * 3, w1t, w2t);
    // QKV projection -> bf16 q,k,v   (576 blocks, 2.25/CU)
    mfma_conv<1, 1, false, false, true><<<dim3(8, 18, B), blk, 0, stream>>>(
        xbh, wqt, wkt, wvt, bq + i * C, bk + i * C, bv + i * C, mask,
        qbh, kbh, vbh, C, C, 6);
    // fused attention -> bf16
    fused_attn<<<dim3(T / 64, B * H), blk, 0, stream>>>(
        qbh, kbh, vbh, mask, ek + (size_t)i * D * 9, ev + (size_t)i * D * 9, hidh);
    // Wo projection: split-K3 -> fp32 partials   (576 blocks)
    mfma_conv<1, 3, false, false, false><<<dim3(8, 6, B * 3), blk, 0, stream>>>(
        hidh, wot, wot, wot, bo + i * C, bo + i * C, bo + i * C, mask,
        ypart, ypart, ypart, C, C, 6);
    add_norm_wave<3, false, false><<<dim3(T / 4, B), blk, 0, stream>>>(
        xr, ypart, n1g + i * C, n1b + i * C, mask, xr1, xfh);
    // FFN up: 3 taps, GELU+mask, bf16 out   (768 blocks, 3/CU balanced)
    mfma_conv<3, 1, true, true, true><<<dim3(8, 24, B), blk, 0, stream>>>(
        xfh, w1t, w1t, w1t, b1 + i * FF, b1 + i * FF, b1 + i * FF, mask,
        hidh, hidh, hidh, C, FF, 24);
    // FFN down: 3 taps, split-K4 -> fp32 partials   (768 blocks)
    mfma_conv<3, 4, false, false, false><<<dim3(8, 6, B * 4), blk, 0, stream>>>(
        hidh, w2t, w2t, w2t, b2 + i * C, b2 + i * C, b2 + i * C, mask,
        ypart, ypart, ypart, FF, C, 6);
    add_norm_wave<4, true, true><<<dim3(T / 4, B), blk, 0, stream>>>(
        xr1, ypart, n2g + i * C, n2b + i * C, mask, xr, xbh);
  }
  transpose_out<<<dim3(T / 32, C / 32, B), blk, 0, stream>>>(xr, outp);
}

// Round 10
// 1326.592 us; speedup vs baseline: 1.7159x; 1.0328x over previous
//
#include <hip/hip_runtime.h>
#include <cstddef>

namespace {

constexpr int B  = 4;
constexpr int C  = 768;
constexpr int T  = 512;
constexpr int H  = 12;
constexpr int D  = 64;
constexpr int NL = 6;
constexpr int W  = 4;
constexpr int FF = 3072;

typedef __attribute__((ext_vector_type(8))) short sh8;
typedef __attribute__((ext_vector_type(4))) float f32x4;

__device__ inline float gelu_exact(float x) {
  return 0.5f * x * (1.0f + erff(x * 0.70710678118654752440f));
}
__device__ inline unsigned short f2b(float f) {
  unsigned u = __float_as_uint(f);
  unsigned r = (u + 0x7fffu + ((u >> 16) & 1u)) >> 16;
  return (unsigned short)r;
}
__device__ inline float b2f(unsigned short u) {
  return __uint_as_float((unsigned)u << 16);
}
__device__ inline void gload_lds16(const void* g, void* l) {
  __builtin_amdgcn_global_load_lds(
      (const __attribute__((address_space(1))) unsigned int*)g,
      (__attribute__((address_space(3))) unsigned int*)l, 16, 0, 0);
}

// ---------------------------------------------------------------------------
// Layer-0 input: x [B][C][T] fp32 c-major -> bf16 t-major + fp32 t-major
__global__ __launch_bounds__(256) void transpose_cvt_in(
    const float* __restrict__ s, unsigned short* __restrict__ dh,
    float* __restrict__ df)
{
  __shared__ float tile[32][33];
  const int b = blockIdx.z;
  const int c0 = blockIdx.y * 32, t0 = blockIdx.x * 32;
  const int tx = threadIdx.x & 31, ty = threadIdx.x >> 5;
  const float* sp = s + ((size_t)b * C + c0) * T + t0;
#pragma unroll
  for (int i = 0; i < 4; ++i)
    tile[ty + i * 8][tx] = sp[(size_t)(ty + i * 8) * T + tx];
  __syncthreads();
  unsigned short* dph = dh + ((size_t)b * T + t0) * C + c0;
  float* dpf = df + ((size_t)b * T + t0) * C + c0;
#pragma unroll
  for (int i = 0; i < 4; ++i) {
    const float v = tile[tx][ty + i * 8];
    dph[(size_t)(ty + i * 8) * C + tx] = f2b(v);
    dpf[(size_t)(ty + i * 8) * C + tx] = v;
  }
}

// Final residual: fp32 t-major [B][T][C] -> fp32 c-major [B][C][T]
__global__ __launch_bounds__(256) void transpose_out(
    const float* __restrict__ s, float* __restrict__ d)
{
  __shared__ float tile[32][33];
  const int b = blockIdx.z;
  const int c0 = blockIdx.y * 32, t0 = blockIdx.x * 32;
  const int tx = threadIdx.x & 31, ty = threadIdx.x >> 5;
  const float* sp = s + ((size_t)b * T + t0) * C + c0;
#pragma unroll
  for (int i = 0; i < 4; ++i)
    tile[ty + i * 8][tx] = sp[(size_t)(ty + i * 8) * C + tx];
  __syncthreads();
  float* dp = d + ((size_t)b * C + c0) * T + t0;
#pragma unroll
  for (int i = 0; i < 4; ++i)
    dp[(size_t)(ty + i * 8) * T + tx] = tile[tx][ty + i * 8];
}

// QKVO weights fp32 [C][C] -> bf16 MFMA-fragment-tiled
__global__ __launch_bounds__(256) void cvt_qkvo_tiled(
    const float* __restrict__ q, const float* __restrict__ k,
    const float* __restrict__ v, const float* __restrict__ o,
    unsigned short* __restrict__ dq, unsigned short* __restrict__ dk,
    unsigned short* __restrict__ dv, unsigned short* __restrict__ dov)
{
  const int z = blockIdx.y;
  const float* s = z == 0 ? q : z == 1 ? k : z == 2 ? v : o;
  unsigned short* d = z == 0 ? dq : z == 1 ? dk : z == 2 ? dv : dov;
  const int flat = blockIdx.x * 256 + threadIdx.x;
  const int row = flat / (C / 8);
  const int c   = (flat % (C / 8)) * 8;
  const int ks = c >> 5, lhi = (c >> 3) & 3, mt = row >> 4, l15 = row & 15;
  const float* sp = s + (size_t)row * C + c;
  float4 a = *(const float4*)(sp);
  float4 b = *(const float4*)(sp + 4);
  sh8 u;
  u[0] = (short)f2b(a.x); u[1] = (short)f2b(a.y);
  u[2] = (short)f2b(a.z); u[3] = (short)f2b(a.w);
  u[4] = (short)f2b(b.x); u[5] = (short)f2b(b.y);
  u[6] = (short)f2b(b.z); u[7] = (short)f2b(b.w);
  *(sh8*)(d + ((size_t)(mt * (C / 32) + ks) * 64 + lhi * 16 + l15) * 8) = u;
}

// FFN weights [O][Ci][3] fp32 -> 3 tap planes, each fragment-tiled bf16.
__global__ __launch_bounds__(256) void cvt_ffn_tiled(
    const float* __restrict__ s1, const float* __restrict__ s2,
    unsigned short* __restrict__ d1, unsigned short* __restrict__ d2)
{
  const int z = blockIdx.y;
  const float* src = z ? s2 : s1;
  unsigned short* dst = z ? d2 : d1;
  const int O  = z ? C : FF;
  const int Ci = z ? FF : C;
  const int flat = blockIdx.x * 256 + threadIdx.x;
  const int row = flat / (Ci / 8);
  const int c   = (flat % (Ci / 8)) * 8;
  const int ks = c >> 5, lhi = (c >> 3) & 3, mt = row >> 4, l15 = row & 15;
  const float* sp = src + ((size_t)row * Ci + c) * 3;
  float f[24];
#pragma unroll
  for (int i = 0; i < 6; ++i) {
    float4 t4 = *(const float4*)(sp + i * 4);
    f[i * 4 + 0] = t4.x; f[i * 4 + 1] = t4.y; f[i * 4 + 2] = t4.z; f[i * 4 + 3] = t4.w;
  }
  const size_t fragoff =
      ((size_t)(mt * (Ci / 32) + ks) * 64 + lhi * 16 + l15) * 8;
#pragma unroll
  for (int tap = 0; tap < 3; ++tap) {
    sh8 u;
#pragma unroll
    for (int j = 0; j < 8; ++j) u[j] = (short)f2b(f[j * 3 + tap]);
    *(sh8*)(dst + (size_t)tap * O * Ci + fragoff) = u;
  }
}

// ---------------------------------------------------------------------------
// 256-thread MFMA conv (BM=128 x BN=64), 2-phase double-buffered.
// 1-D grid, XCD-chunked swizzle: wg = ((ty*NZ+zz)*8)+tx so that the blocks
// sharing one weight panel (all tx, nearby zz) land on ONE XCD's L2.
template <int TAPS, int KSPLIT, bool GELU, bool MASK_OUT, bool OBF16>
__global__ __launch_bounds__(256) void mfma_conv(
    const unsigned short* __restrict__ xin,
    const unsigned short* __restrict__ w0p, const unsigned short* __restrict__ w1p,
    const unsigned short* __restrict__ w2p,
    const float* __restrict__ b0, const float* __restrict__ b1,
    const float* __restrict__ b2,
    const float* __restrict__ mask,
    void* __restrict__ o0p, void* __restrict__ o1p, void* __restrict__ o2p,
    int Cin, int O, int tilesPerPlane, int nz)
{
  constexpr int BN = 64;
  constexpr int ROWS_B = BN + TAPS - 1;
  constexpr int PB = 40;
  __shared__ unsigned short Aw[2][TAPS * 8 * 512];
  __shared__ unsigned short Bx[2][ROWS_B * PB];

  // XCD-chunked bijective swizzle (nwg % 8 == 0 for all launches)
  const int nwg = gridDim.x;
  const int orig = blockIdx.x;
  const int wg = (orig & 7) * (nwg >> 3) + (orig >> 3);
  const int txt = wg & 7;
  const int rest = wg >> 3;
  const int zz = rest % nz;
  const int ty = rest / nz;

  const int b  = zz / KSPLIT;
  const int kk = zz % KSPLIT;
  const int TOFF = (TAPS == 3) ? -1 : 0;
  const int t0 = txt * BN;
  const int plane = ty / tilesPerPlane;
  const int mt0 = (ty % tilesPerPlane) * 8;
  const int o0 = mt0 * 16;

  const int tid = threadIdx.x;
  const int lane = tid & 63, wid = tid >> 6;
  const int wm = wid >> 1, wn = wid & 1;
  const int l15 = lane & 15, lhi = lane >> 4;
  const int bmask = b * T;

  const unsigned short* wsel = plane == 0 ? w0p : (plane == 1 ? w1p : w2p);
  const float* bp = plane == 0 ? b0 : (plane == 1 ? b1 : b2);

  const int KST = Cin >> 5;
  const int kchunk = KST / KSPLIT;
  const int ks0 = kk * kchunk, ks1 = ks0 + kchunk;
  const int OT = O >> 4;

  const int brow = tid >> 2, bcl = (tid & 3) << 3;
  const unsigned short* xb_ = xin + (size_t)b * T * Cin;

  sh8 breg, breg2;
  auto stageA = [&](int ks, int buf) {
#pragma unroll
    for (int tap = 0; tap < TAPS; ++tap) {
#pragma unroll
      for (int j = 0; j < 2; ++j) {
        const int rt = wid * 2 + j;
        const unsigned short* src =
            wsel + (((size_t)tap * OT + mt0 + rt) * KST + ks) * 512 + lane * 8;
        gload_lds16(src, &Aw[buf][(tap * 8 + rt) * 512]);
      }
    }
  };
  auto loadB = [&](int ks) {
    const int c0 = ks << 5;
    const unsigned short* xrow = xb_ + c0 + bcl;
    const int tsrc = t0 + brow + TOFF;
    breg = (sh8)0;
    if ((unsigned)tsrc < (unsigned)T)
      breg = *(const sh8*)(xrow + (size_t)tsrc * Cin);
    if constexpr (TAPS == 3) {
      breg2 = (sh8)0;
      if (tid < 8) {
        const int ts2 = t0 + BN + (tid >> 2) + TOFF;
        if ((unsigned)ts2 < (unsigned)T)
          breg2 = *(const sh8*)(xrow + (size_t)ts2 * Cin);
      }
    }
  };
  auto writeB = [&](int buf) {
    *(sh8*)&Bx[buf][brow * PB + bcl] = breg;
    if constexpr (TAPS == 3) {
      if (tid < 8)
        *(sh8*)&Bx[buf][(BN + (tid >> 2)) * PB + bcl] = breg2;
    }
  };

  f32x4 acc[4][2] = {};

  int cur = 0;
  stageA(ks0, 0);
  loadB(ks0);
  writeB(0);
  __syncthreads();

  for (int ks = ks0; ks < ks1; ++ks) {
    const int nxt = cur ^ 1;
    const bool more = (ks + 1 < ks1);
    if (more) { stageA(ks + 1, nxt); loadB(ks + 1); }
#pragma unroll
    for (int tap = 0; tap < TAPS; ++tap) {
      sh8 af[4], bfr[2];
#pragma unroll
      for (int m = 0; m < 4; ++m)
        af[m] = *(const sh8*)&Aw[cur][(tap * 8 + wm * 4 + m) * 512 + lane * 8];
#pragma unroll
      for (int n = 0; n < 2; ++n)
        bfr[n] = *(const sh8*)&Bx[cur][(wn * 32 + n * 16 + l15 + tap) * PB + lhi * 8];
#pragma unroll
      for (int m = 0; m < 4; ++m)
#pragma unroll
        for (int n = 0; n < 2; ++n)
          acc[m][n] = __builtin_amdgcn_mfma_f32_16x16x32_bf16(
              af[m], bfr[n], acc[m][n], 0, 0, 0);
    }
    if (more) writeB(nxt);
    __syncthreads();
    cur = nxt;
  }

  void* obase = plane == 0 ? o0p : (plane == 1 ? o1p : o2p);
  unsigned short* oph = (unsigned short*)obase + (size_t)b * T * O;
  float* opf = (float*)obase + ((size_t)kk * B + b) * (size_t)T * O;
#pragma unroll
  for (int m = 0; m < 4; ++m) {
    const int o = o0 + (wm * 4 + m) * 16 + (lhi << 2);
#pragma unroll
    for (int n = 0; n < 2; ++n) {
      const int t = t0 + wn * 32 + n * 16 + l15;
      const float mk = MASK_OUT ? mask[bmask + t] : 1.f;
      float v[4];
#pragma unroll
      for (int r4 = 0; r4 < 4; ++r4) {
        float x = acc[m][n][r4];
        if (KSPLIT > 1) {
          if (kk == 0) x += bp[o + r4];
        } else {
          x += bp[o + r4];
        }
        if (GELU) x = gelu_exact(x);
        if (MASK_OUT) x *= mk;
        v[r4] = x;
      }
      if constexpr (OBF16) {
        ushort4 hz;
        hz.x = f2b(v[0]); hz.y = f2b(v[1]); hz.z = f2b(v[2]); hz.w = f2b(v[3]);
        *(ushort4*)(oph + (size_t)t * O + o) = hz;
      } else {
        *(float4*)(opf + (size_t)t * O + o) = make_float4(v[0], v[1], v[2], v[3]);
      }
    }
  }
}

// ---------------------------------------------------------------------------
// Fused attention with 2-phase K/V prefetch. q/k/v/out t-major bf16 [B][T][C].
__global__ __launch_bounds__(256) void fused_attn(
    const unsigned short* __restrict__ qg,
    const unsigned short* __restrict__ kg,
    const unsigned short* __restrict__ vg,
    const float* __restrict__ mask,
    const float* __restrict__ ek,
    const float* __restrict__ ev,
    unsigned short* __restrict__ outp)
{
  constexpr int PITCH = 72;
  __shared__ unsigned short Qs[64 * PITCH];
  __shared__ unsigned short Ks[2][64 * PITCH];
  __shared__ unsigned short Vs[2][64 * PITCH];
  __shared__ unsigned short Ps[64 * PITCH];
  __shared__ float eks[D * 9], evs[D * 9];
  __shared__ float qekl[64 * 12];
  __shared__ float mks[2][64];

  const int t0 = blockIdx.x * 64;
  const int bh = blockIdx.y;
  const int b = bh / H, h = bh % H;
  const int tid = threadIdx.x;
  const int lane = tid & 63, w = tid >> 6;
  const int l15 = lane & 15, lhi = lane >> 4;

  const size_t base = (size_t)b * T * C + h * D;
  const unsigned short* qh = qg + base;
  const unsigned short* kh = kg + base;
  const unsigned short* vh = vg + base;

  for (int e = tid; e < D * 9; e += 256) { eks[e] = ek[e]; evs[e] = ev[e]; }
  {
    const int tl = tid & 63, d0 = (tid >> 6) << 4;
    const unsigned short* src = qh + (size_t)(t0 + tl) * C + d0;
    *(sh8*)&Qs[tl * PITCH + d0]     = *(const sh8*)(src);
    *(sh8*)&Qs[tl * PITCH + d0 + 8] = *(const sh8*)(src + 8);
  }
  __syncthreads();
  {
    const int tl = tid & 63, g = tid >> 6;
    for (int j = g; j < 9; j += 4) {
      float a = 0.f;
      for (int d = 0; d < D; ++d)
        a = fmaf(b2f(Qs[tl * PITCH + d]), eks[d * 9 + j], a);
      qekl[tl * 12 + j] = a * 0.125f;
    }
  }
  const int t_loc = w * 16 + l15;
  const int t = t0 + t_loc;
  const float mask_t = mask[b * T + t];
  const sh8 bq0 = *(const sh8*)&Qs[t_loc * PITCH + lhi * 8];
  const sh8 bq1 = *(const sh8*)&Qs[t_loc * PITCH + 32 + lhi * 8];

  const int sl = tid & 63, d0s = (tid >> 6) << 4;
  {
    const unsigned short* srck = kh + (size_t)sl * C + d0s;
    *(sh8*)&Ks[0][sl * PITCH + d0s]     = *(const sh8*)(srck);
    *(sh8*)&Ks[0][sl * PITCH + d0s + 8] = *(const sh8*)(srck + 8);
    const unsigned short* srcv = vh + (size_t)sl * C + d0s;
    sh8 u0 = *(const sh8*)(srcv);
    sh8 u1 = *(const sh8*)(srcv + 8);
#pragma unroll
    for (int j = 0; j < 8; ++j) Vs[0][(d0s + j) * PITCH + sl] = (unsigned short)u0[j];
#pragma unroll
    for (int j = 0; j < 8; ++j) Vs[0][(d0s + 8 + j) * PITCH + sl] = (unsigned short)u1[j];
    if (tid < 64) mks[0][tid] = mask[b * T + tid];
  }
  __syncthreads();

  float m_run = -1e30f, l_run = 0.f;
  f32x4 oacc[4] = {};
  int cur = 0;
  sh8 kr0, kr1, vr0, vr1;
  float mkr = 0.f;

  for (int s0 = 0; s0 < T; s0 += 64) {
    const int nxt = cur ^ 1;
    const bool more = (s0 + 64 < T);
    if (more) {
      const unsigned short* srck = kh + (size_t)(s0 + 64 + sl) * C + d0s;
      kr0 = *(const sh8*)(srck);
      kr1 = *(const sh8*)(srck + 8);
      const unsigned short* srcv = vh + (size_t)(s0 + 64 + sl) * C + d0s;
      vr0 = *(const sh8*)(srcv);
      vr1 = *(const sh8*)(srcv + 8);
      if (tid < 64) mkr = mask[b * T + s0 + 64 + tid];
    }

    float p[16];
#pragma unroll
    for (int n = 0; n < 4; ++n) {
      const sh8 a0 = *(const sh8*)&Ks[cur][(n * 16 + l15) * PITCH + lhi * 8];
      const sh8 a1 = *(const sh8*)&Ks[cur][(n * 16 + l15) * PITCH + 32 + lhi * 8];
      f32x4 acc = {};
      acc = __builtin_amdgcn_mfma_f32_16x16x32_bf16(a0, bq0, acc, 0, 0, 0);
      acc = __builtin_amdgcn_mfma_f32_16x16x32_bf16(a1, bq1, acc, 0, 0, 0);
#pragma unroll
      for (int r = 0; r < 4; ++r) {
        const int s = s0 + n * 16 + lhi * 4 + r;
        float v = acc[r] * 0.125f;
        const int j = s - t + 4;
        if ((unsigned)j < 9u) v += qekl[t_loc * 12 + j];
        if (mask_t * mks[cur][s - s0] == 0.f) v = -10000.0f;
        p[n * 4 + r] = v;
      }
    }
    float mloc = p[0];
#pragma unroll
    for (int i = 1; i < 16; ++i) mloc = fmaxf(mloc, p[i]);
    mloc = fmaxf(mloc, __shfl_xor(mloc, 16));
    mloc = fmaxf(mloc, __shfl_xor(mloc, 32));
    const float m_new = fmaxf(m_run, mloc);
    const float f = __expf(m_run - m_new);
    float sloc = 0.f;
#pragma unroll
    for (int i = 0; i < 16; ++i) { p[i] = __expf(p[i] - m_new); sloc += p[i]; }
    sloc += __shfl_xor(sloc, 16);
    sloc += __shfl_xor(sloc, 32);
    l_run = l_run * f + sloc;
    m_run = m_new;
#pragma unroll
    for (int m = 0; m < 4; ++m)
#pragma unroll
      for (int r = 0; r < 4; ++r) oacc[m][r] *= f;
#pragma unroll
    for (int n = 0; n < 4; ++n) {
      uint2 pk;
      pk.x = (unsigned)f2b(p[n * 4 + 0]) | ((unsigned)f2b(p[n * 4 + 1]) << 16);
      pk.y = (unsigned)f2b(p[n * 4 + 2]) | ((unsigned)f2b(p[n * 4 + 3]) << 16);
      *(uint2*)&Ps[t_loc * PITCH + n * 16 + lhi * 4] = pk;
    }
    asm volatile("s_waitcnt lgkmcnt(0)" ::: "memory");
    const sh8 bp0 = *(const sh8*)&Ps[t_loc * PITCH + lhi * 8];
    const sh8 bp1 = *(const sh8*)&Ps[t_loc * PITCH + 32 + lhi * 8];
#pragma unroll
    for (int m = 0; m < 4; ++m) {
      const sh8 a0 = *(const sh8*)&Vs[cur][(m * 16 + l15) * PITCH + lhi * 8];
      const sh8 a1 = *(const sh8*)&Vs[cur][(m * 16 + l15) * PITCH + 32 + lhi * 8];
      oacc[m] = __builtin_amdgcn_mfma_f32_16x16x32_bf16(a0, bp0, oacc[m], 0, 0, 0);
      oacc[m] = __builtin_amdgcn_mfma_f32_16x16x32_bf16(a1, bp1, oacc[m], 0, 0, 0);
    }
    if (t + 4 >= s0 && t < s0 + 68) {
#pragma unroll
      for (int j = 0; j < 9; ++j) {
        const int s = t + j - 4;
        if (s >= s0 && s < s0 + 64) {
          const float pv = b2f(Ps[t_loc * PITCH + (s - s0)]);
#pragma unroll
          for (int m = 0; m < 4; ++m)
#pragma unroll
            for (int r = 0; r < 4; ++r)
              oacc[m][r] = fmaf(pv, evs[(m * 16 + lhi * 4 + r) * 9 + j], oacc[m][r]);
        }
      }
    }
    if (more) {
      *(sh8*)&Ks[nxt][sl * PITCH + d0s]     = kr0;
      *(sh8*)&Ks[nxt][sl * PITCH + d0s + 8] = kr1;
#pragma unroll
      for (int j = 0; j < 8; ++j) Vs[nxt][(d0s + j) * PITCH + sl] = (unsigned short)vr0[j];
#pragma unroll
      for (int j = 0; j < 8; ++j) Vs[nxt][(d0s + 8 + j) * PITCH + sl] = (unsigned short)vr1[j];
      if (tid < 64) mks[nxt][tid] = mkr;
    }
    __syncthreads();
    cur = nxt;
  }
  const float invl = 1.f / l_run;
  unsigned short* ob = outp + (size_t)(b * T + t) * C + h * D;
#pragma unroll
  for (int m = 0; m < 4; ++m) {
    ushort4 hz;
    hz.x = f2b(oacc[m][0] * invl);
    hz.y = f2b(oacc[m][1] * invl);
    hz.z = f2b(oacc[m][2] * invl);
    hz.w = f2b(oacc[m][3] * invl);
    *(ushort4*)(ob + m * 16 + lhi * 4) = hz;
  }
}

// ---------------------------------------------------------------------------
// Wave-per-t add+layernorm, everything t-major.
template <int NP, bool MASKY, bool MASKF>
__global__ __launch_bounds__(256) void add_norm_wave(
    const float* __restrict__ xr, const float* __restrict__ ypart,
    const float* __restrict__ g, const float* __restrict__ bta,
    const float* __restrict__ mask, float* __restrict__ dst,
    unsigned short* __restrict__ dsth)
{
  const int b = blockIdx.y;
  const int t = blockIdx.x * 4 + (threadIdx.x >> 6);
  const int lane = threadIdx.x & 63;
  const float mkt = mask[b * T + t];
  const size_t rowoff = ((size_t)b * T + t) * C;
  const int ci0 = lane * 12;

  float vv[12];
  float sum = 0.f, sq = 0.f;
#pragma unroll
  for (int q = 0; q < 3; ++q) {
    const int ci = ci0 + q * 4;
    float4 xv = *(const float4*)(xr + rowoff + ci);
    float4 yv = make_float4(0.f, 0.f, 0.f, 0.f);
#pragma unroll
    for (int p = 0; p < NP; ++p) {
      float4 t4 = *(const float4*)(ypart + (size_t)p * B * T * C + rowoff + ci);
      yv.x += t4.x; yv.y += t4.y; yv.z += t4.z; yv.w += t4.w;
    }
    if (MASKY) { yv.x *= mkt; yv.y *= mkt; yv.z *= mkt; yv.w *= mkt; }
    const float v0 = xv.x + yv.x, v1 = xv.y + yv.y;
    const float v2 = xv.z + yv.z, v3 = xv.w + yv.w;
    vv[q * 4 + 0] = v0; vv[q * 4 + 1] = v1; vv[q * 4 + 2] = v2; vv[q * 4 + 3] = v3;
    sum += v0 + v1 + v2 + v3;
    sq = fmaf(v0, v0, fmaf(v1, v1, fmaf(v2, v2, fmaf(v3, v3, sq))));
  }
#pragma unroll
  for (int o = 32; o > 0; o >>= 1) {
    sum += __shfl_xor(sum, o);
    sq += __shfl_xor(sq, o);
  }
  const float m = sum * (1.f / C);
  const float rs = rsqrtf(sq * (1.f / C) - m * m + 1e-5f);
#pragma unroll
  for (int q = 0; q < 3; ++q) {
    const int ci = ci0 + q * 4;
    float4 gv = *(const float4*)(g + ci);
    float4 bv = *(const float4*)(bta + ci);
    float o0 = (vv[q * 4 + 0] - m) * rs * gv.x + bv.x;
    float o1 = (vv[q * 4 + 1] - m) * rs * gv.y + bv.y;
    float o2 = (vv[q * 4 + 2] - m) * rs * gv.z + bv.z;
    float o3 = (vv[q * 4 + 3] - m) * rs * gv.w + bv.w;
    if (MASKF) { o0 *= mkt; o1 *= mkt; o2 *= mkt; o3 *= mkt; }
    *(float4*)(dst + rowoff + ci) = make_float4(o0, o1, o2, o3);
    const float hm = MASKF ? 1.f : mkt;
    ushort4 hz;
    hz.x = f2b(o0 * hm); hz.y = f2b(o1 * hm); hz.z = f2b(o2 * hm); hz.w = f2b(o3 * hm);
    *(ushort4*)(dsth + rowoff + ci) = hz;
  }
}

}  // namespace

extern "C" void kernel_launch(void* const* d_in, const int* in_sizes, int n_in,
                              void* d_out, int out_size, void* d_ws, size_t ws_size,
                              hipStream_t stream) {
  const float* x_in = (const float*)d_in[0];
  const float* mask = (const float*)d_in[1];
  const float* Wq = (const float*)d_in[2];
  const float* bq = (const float*)d_in[3];
  const float* Wk = (const float*)d_in[4];
  const float* bk = (const float*)d_in[5];
  const float* Wv = (const float*)d_in[6];
  const float* bv = (const float*)d_in[7];
  const float* Wo = (const float*)d_in[8];
  const float* bo = (const float*)d_in[9];
  const float* ek = (const float*)d_in[10];
  const float* ev = (const float*)d_in[11];
  const float* w1 = (const float*)d_in[12];
  const float* b1 = (const float*)d_in[13];
  const float* w2 = (const float*)d_in[14];
  const float* b2 = (const float*)d_in[15];
  const float* n1g = (const float*)d_in[16];
  const float* n1b = (const float*)d_in[17];
  const float* n2g = (const float*)d_in[18];
  const float* n2b = (const float*)d_in[19];

  float* ws = (float*)d_ws;
  const size_t SZ_X = (size_t)B * C * T;
  float* xr    = ws;
  float* xr1   = xr + SZ_X;
  float* ypart = xr1 + SZ_X;
  unsigned short* xbh = (unsigned short*)(ypart + 4 * SZ_X);
  unsigned short* xfh = xbh + SZ_X;
  unsigned short* qbh = xfh + SZ_X;
  unsigned short* kbh = qbh + SZ_X;
  unsigned short* vbh = kbh + SZ_X;
  unsigned short* hidh = vbh + SZ_X;
  unsigned short* w1t = hidh + (size_t)B * FF * T;
  unsigned short* w2t = w1t + (size_t)3 * FF * C;
  unsigned short* wqt = w2t + (size_t)3 * FF * C;
  unsigned short* wkt = wqt + (size_t)C * C;
  unsigned short* wvt = wkt + (size_t)C * C;
  unsigned short* wot = wvt + (size_t)C * C;
  float* outp = (float*)d_out;

  const dim3 blk(256);
  transpose_cvt_in<<<dim3(T / 32, C / 32, B), blk, 0, stream>>>(x_in, xbh, xr);

  for (int i = 0; i < NL; ++i) {
    const size_t wOff = (size_t)i * C * C;
    cvt_qkvo_tiled<<<dim3((C * C / 8) / 256, 4), blk, 0, stream>>>(
        Wq + wOff, Wk + wOff, Wv + wOff, Wo + wOff, wqt, wkt, wvt, wot);
    cvt_ffn_tiled<<<dim3((FF * C / 8) / 256, 2), blk, 0, stream>>>(
        w1 + (size_t)i * FF * C * 3, w2 + (size_t)i * C * FF * 3, w1t, w2t);
    // QKV projection -> bf16 q,k,v   (576 blocks, XCD-swizzled)
    mfma_conv<1, 1, false, false, true><<<dim3(8 * 18 * 4), blk, 0, stream>>>(
        xbh, wqt, wkt, wvt, bq + i * C, bk + i * C, bv + i * C, mask,
        qbh, kbh, vbh, C, C, 6, 4);
    // fused attention -> bf16
    fused_attn<<<dim3(T / 64, B * H), blk, 0, stream>>>(
        qbh, kbh, vbh, mask, ek + (size_t)i * D * 9, ev + (size_t)i * D * 9, hidh);
    // Wo projection: split-K3 -> fp32 partials   (576 blocks)
    mfma_conv<1, 3, false, false, false><<<dim3(8 * 6 * 12), blk, 0, stream>>>(
        hidh, wot, wot, wot, bo + i * C, bo + i * C, bo + i * C, mask,
        ypart, ypart, ypart, C, C, 6, 12);
    add_norm_wave<3, false, false><<<dim3(T / 4, B), blk, 0, stream>>>(
        xr, ypart, n1g + i * C, n1b + i * C, mask, xr1, xfh);
    // FFN up: 3 taps, GELU+mask, bf16 out   (768 blocks)
    mfma_conv<3, 1, true, true, true><<<dim3(8 * 24 * 4), blk, 0, stream>>>(
        xfh, w1t, w1t, w1t, b1 + i * FF, b1 + i * FF, b1 + i * FF, mask,
        hidh, hidh, hidh, C, FF, 24, 4);
    // FFN down: 3 taps, split-K4 -> fp32 partials   (768 blocks)
    mfma_conv<3, 4, false, false, false><<<dim3(8 * 6 * 16), blk, 0, stream>>>(
        hidh, w2t, w2t, w2t, b2 + i * C, b2 + i * C, b2 + i * C, mask,
        ypart, ypart, ypart, FF, C, 6, 16);
    add_norm_wave<4, true, true><<<dim3(T / 4, B), blk, 0, stream>>>(
        xr1, ypart, n2g + i * C, n2b + i * C, mask, xr, xbh);
  }
  transpose_out<<<dim3(T / 32, C / 32, B), blk, 0, stream>>>(xr, outp);
}

// Round 11
// 1275.274 us; speedup vs baseline: 1.7850x; 1.0402x over previous
//
#include <hip/hip_runtime.h>
#include <cstddef>

namespace {

constexpr int B  = 4;
constexpr int C  = 768;
constexpr int T  = 512;
constexpr int H  = 12;
constexpr int D  = 64;
constexpr int NL = 6;
constexpr int W  = 4;
constexpr int FF = 3072;

typedef __attribute__((ext_vector_type(8))) short sh8;
typedef __attribute__((ext_vector_type(4))) float f32x4;

__device__ inline float gelu_exact(float x) {
  return 0.5f * x * (1.0f + erff(x * 0.70710678118654752440f));
}
__device__ inline unsigned short f2b(float f) {
  unsigned u = __float_as_uint(f);
  unsigned r = (u + 0x7fffu + ((u >> 16) & 1u)) >> 16;
  return (unsigned short)r;
}
__device__ inline float b2f(unsigned short u) {
  return __uint_as_float((unsigned)u << 16);
}
__device__ inline void gload_lds16(const void* g, void* l) {
  __builtin_amdgcn_global_load_lds(
      (const __attribute__((address_space(1))) unsigned int*)g,
      (__attribute__((address_space(3))) unsigned int*)l, 16, 0, 0);
}

// ---------------------------------------------------------------------------
// Layer-0 input: x [B][C][T] fp32 c-major -> bf16 t-major + fp32 t-major
__global__ __launch_bounds__(256) void transpose_cvt_in(
    const float* __restrict__ s, unsigned short* __restrict__ dh,
    float* __restrict__ df)
{
  __shared__ float tile[32][33];
  const int b = blockIdx.z;
  const int c0 = blockIdx.y * 32, t0 = blockIdx.x * 32;
  const int tx = threadIdx.x & 31, ty = threadIdx.x >> 5;
  const float* sp = s + ((size_t)b * C + c0) * T + t0;
#pragma unroll
  for (int i = 0; i < 4; ++i)
    tile[ty + i * 8][tx] = sp[(size_t)(ty + i * 8) * T + tx];
  __syncthreads();
  unsigned short* dph = dh + ((size_t)b * T + t0) * C + c0;
  float* dpf = df + ((size_t)b * T + t0) * C + c0;
#pragma unroll
  for (int i = 0; i < 4; ++i) {
    const float v = tile[tx][ty + i * 8];
    dph[(size_t)(ty + i * 8) * C + tx] = f2b(v);
    dpf[(size_t)(ty + i * 8) * C + tx] = v;
  }
}

// Final residual: fp32 t-major [B][T][C] -> fp32 c-major [B][C][T]
__global__ __launch_bounds__(256) void transpose_out(
    const float* __restrict__ s, float* __restrict__ d)
{
  __shared__ float tile[32][33];
  const int b = blockIdx.z;
  const int c0 = blockIdx.y * 32, t0 = blockIdx.x * 32;
  const int tx = threadIdx.x & 31, ty = threadIdx.x >> 5;
  const float* sp = s + ((size_t)b * T + t0) * C + c0;
#pragma unroll
  for (int i = 0; i < 4; ++i)
    tile[ty + i * 8][tx] = sp[(size_t)(ty + i * 8) * C + tx];
  __syncthreads();
  float* dp = d + ((size_t)b * C + c0) * T + t0;
#pragma unroll
  for (int i = 0; i < 4; ++i)
    dp[(size_t)(ty + i * 8) * T + tx] = tile[tx][ty + i * 8];
}

// QKVO weights fp32 [C][C] -> bf16 MFMA-fragment-tiled (all layers upfront).
__global__ __launch_bounds__(256) void cvt_qkvo_tiled(
    const float* __restrict__ q, const float* __restrict__ k,
    const float* __restrict__ v, const float* __restrict__ o,
    unsigned short* __restrict__ dq, unsigned short* __restrict__ dk,
    unsigned short* __restrict__ dv, unsigned short* __restrict__ dov)
{
  const int z = blockIdx.y;
  const size_t loff = (size_t)blockIdx.z * C * C;
  const float* s = (z == 0 ? q : z == 1 ? k : z == 2 ? v : o) + loff;
  unsigned short* d = (z == 0 ? dq : z == 1 ? dk : z == 2 ? dv : dov) + loff;
  const int flat = blockIdx.x * 256 + threadIdx.x;
  const int row = flat / (C / 8);
  const int c   = (flat % (C / 8)) * 8;
  const int ks = c >> 5, lhi = (c >> 3) & 3, mt = row >> 4, l15 = row & 15;
  const float* sp = s + (size_t)row * C + c;
  float4 a = *(const float4*)(sp);
  float4 b = *(const float4*)(sp + 4);
  sh8 u;
  u[0] = (short)f2b(a.x); u[1] = (short)f2b(a.y);
  u[2] = (short)f2b(a.z); u[3] = (short)f2b(a.w);
  u[4] = (short)f2b(b.x); u[5] = (short)f2b(b.y);
  u[6] = (short)f2b(b.z); u[7] = (short)f2b(b.w);
  *(sh8*)(d + ((size_t)(mt * (C / 32) + ks) * 64 + lhi * 16 + l15) * 8) = u;
}

// FFN weights [O][Ci][3] fp32 -> 3 tap planes fragment-tiled (all layers).
__global__ __launch_bounds__(256) void cvt_ffn_tiled(
    const float* __restrict__ s1, const float* __restrict__ s2,
    unsigned short* __restrict__ d1, unsigned short* __restrict__ d2)
{
  const int z = blockIdx.y;
  const int layer = blockIdx.z;
  const float* src = (z ? s2 : s1) + (size_t)layer * FF * C * 3;
  unsigned short* dst = (z ? d2 : d1) + (size_t)layer * 3 * FF * C;
  const int O  = z ? C : FF;
  const int Ci = z ? FF : C;
  const int flat = blockIdx.x * 256 + threadIdx.x;
  const int row = flat / (Ci / 8);
  const int c   = (flat % (Ci / 8)) * 8;
  const int ks = c >> 5, lhi = (c >> 3) & 3, mt = row >> 4, l15 = row & 15;
  const float* sp = src + ((size_t)row * Ci + c) * 3;
  float f[24];
#pragma unroll
  for (int i = 0; i < 6; ++i) {
    float4 t4 = *(const float4*)(sp + i * 4);
    f[i * 4 + 0] = t4.x; f[i * 4 + 1] = t4.y; f[i * 4 + 2] = t4.z; f[i * 4 + 3] = t4.w;
  }
  const size_t fragoff =
      ((size_t)(mt * (Ci / 32) + ks) * 64 + lhi * 16 + l15) * 8;
#pragma unroll
  for (int tap = 0; tap < 3; ++tap) {
    sh8 u;
#pragma unroll
    for (int j = 0; j < 8; ++j) u[j] = (short)f2b(f[j * 3 + tap]);
    *(sh8*)(dst + (size_t)tap * O * Ci + fragoff) = u;
  }
}

// ---------------------------------------------------------------------------
// 256-thread MFMA conv (BM=128 x BN∈{64,128}), 2-phase double-buffered.
// BN=128: 4 waves 2x2, each wave 64x64 out (acc[4][4]) — m93 ladder step.
// 1-D grid, XCD-chunked swizzle: blocks sharing a weight panel co-locate.
template <int TAPS, int BN, int KSPLIT, bool GELU, bool MASK_OUT, bool OBF16>
__global__ __launch_bounds__(256) void mfma_conv(
    const unsigned short* __restrict__ xin,
    const unsigned short* __restrict__ w0p, const unsigned short* __restrict__ w1p,
    const unsigned short* __restrict__ w2p,
    const float* __restrict__ b0, const float* __restrict__ b1,
    const float* __restrict__ b2,
    const float* __restrict__ mask,
    void* __restrict__ o0p, void* __restrict__ o1p, void* __restrict__ o2p,
    int Cin, int O, int tilesPerPlane, int nz)
{
  constexpr int ROWS_B = BN + TAPS - 1;
  constexpr int PB = 40;
  constexpr int NPASS = BN / 64;   // sh8-chunks per thread for the B-tile
  constexpr int NF = BN / 32;      // per-wave N fragments
  constexpr int NT = T / BN;       // t-tiles per batch
  __shared__ unsigned short Aw[2][TAPS * 8 * 512];
  __shared__ unsigned short Bx[2][ROWS_B * PB];

  // XCD-chunked bijective swizzle (nwg % 8 == 0 for all launches)
  const int nwg = gridDim.x;
  const int orig = blockIdx.x;
  const int wg = (orig & 7) * (nwg >> 3) + (orig >> 3);
  const int txt = wg % NT;
  const int rest = wg / NT;
  const int zz = rest % nz;
  const int ty = rest / nz;

  const int b  = zz / KSPLIT;
  const int kk = zz % KSPLIT;
  const int TOFF = (TAPS == 3) ? -1 : 0;
  const int t0 = txt * BN;
  const int plane = ty / tilesPerPlane;
  const int mt0 = (ty % tilesPerPlane) * 8;
  const int o0 = mt0 * 16;

  const int tid = threadIdx.x;
  const int lane = tid & 63, wid = tid >> 6;
  const int wm = wid >> 1, wn = wid & 1;
  const int l15 = lane & 15, lhi = lane >> 4;
  const int bmask = b * T;

  const unsigned short* wsel = plane == 0 ? w0p : (plane == 1 ? w1p : w2p);
  const float* bp = plane == 0 ? b0 : (plane == 1 ? b1 : b2);

  const int KST = Cin >> 5;
  const int kchunk = KST / KSPLIT;
  const int ks0 = kk * kchunk, ks1 = ks0 + kchunk;
  const int OT = O >> 4;

  const unsigned short* xb_ = xin + (size_t)b * T * Cin;

  sh8 breg[NPASS], breg2;
  auto stageA = [&](int ks, int buf) {
#pragma unroll
    for (int tap = 0; tap < TAPS; ++tap) {
#pragma unroll
      for (int j = 0; j < 2; ++j) {
        const int rt = wid * 2 + j;
        const unsigned short* src =
            wsel + (((size_t)tap * OT + mt0 + rt) * KST + ks) * 512 + lane * 8;
        gload_lds16(src, &Aw[buf][(tap * 8 + rt) * 512]);
      }
    }
  };
  auto loadB = [&](int ks) {
    const int c0 = ks << 5;
#pragma unroll
    for (int p = 0; p < NPASS; ++p) {
      const int idx = tid + p * 256;
      const int row = idx >> 2, c8 = (idx & 3) << 3;
      const int tsrc = t0 + row + TOFF;
      breg[p] = (sh8)0;
      if ((unsigned)tsrc < (unsigned)T)
        breg[p] = *(const sh8*)(xb_ + (size_t)tsrc * Cin + c0 + c8);
    }
    if constexpr (TAPS == 3) {
      breg2 = (sh8)0;
      if (tid < 8) {
        const int row = BN + (tid >> 2), c8 = (tid & 3) << 3;
        const int ts2 = t0 + row + TOFF;
        if ((unsigned)ts2 < (unsigned)T)
          breg2 = *(const sh8*)(xb_ + (size_t)ts2 * Cin + c0 + c8);
      }
    }
  };
  auto writeB = [&](int buf) {
#pragma unroll
    for (int p = 0; p < NPASS; ++p) {
      const int idx = tid + p * 256;
      *(sh8*)&Bx[buf][(idx >> 2) * PB + ((idx & 3) << 3)] = breg[p];
    }
    if constexpr (TAPS == 3) {
      if (tid < 8)
        *(sh8*)&Bx[buf][(BN + (tid >> 2)) * PB + ((tid & 3) << 3)] = breg2;
    }
  };

  f32x4 acc[4][NF] = {};

  int cur = 0;
  stageA(ks0, 0);
  loadB(ks0);
  writeB(0);
  __syncthreads();

  for (int ks = ks0; ks < ks1; ++ks) {
    const int nxt = cur ^ 1;
    const bool more = (ks + 1 < ks1);
    if (more) { stageA(ks + 1, nxt); loadB(ks + 1); }
#pragma unroll
    for (int tap = 0; tap < TAPS; ++tap) {
      sh8 af[4], bfr[NF];
#pragma unroll
      for (int m = 0; m < 4; ++m)
        af[m] = *(const sh8*)&Aw[cur][(tap * 8 + wm * 4 + m) * 512 + lane * 8];
#pragma unroll
      for (int n = 0; n < NF; ++n)
        bfr[n] = *(const sh8*)&Bx[cur][(wn * (NF * 16) + n * 16 + l15 + tap) * PB + lhi * 8];
#pragma unroll
      for (int m = 0; m < 4; ++m)
#pragma unroll
        for (int n = 0; n < NF; ++n)
          acc[m][n] = __builtin_amdgcn_mfma_f32_16x16x32_bf16(
              af[m], bfr[n], acc[m][n], 0, 0, 0);
    }
    if (more) writeB(nxt);
    __syncthreads();
    cur = nxt;
  }

  void* obase = plane == 0 ? o0p : (plane == 1 ? o1p : o2p);
  unsigned short* oph = (unsigned short*)obase + (size_t)b * T * O;
  float* opf = (float*)obase + ((size_t)kk * B + b) * (size_t)T * O;
#pragma unroll
  for (int m = 0; m < 4; ++m) {
    const int o = o0 + (wm * 4 + m) * 16 + (lhi << 2);
#pragma unroll
    for (int n = 0; n < NF; ++n) {
      const int t = t0 + wn * (NF * 16) + n * 16 + l15;
      const float mk = MASK_OUT ? mask[bmask + t] : 1.f;
      float v[4];
#pragma unroll
      for (int r4 = 0; r4 < 4; ++r4) {
        float x = acc[m][n][r4];
        if (KSPLIT > 1) {
          if (kk == 0) x += bp[o + r4];
        } else {
          x += bp[o + r4];
        }
        if (GELU) x = gelu_exact(x);
        if (MASK_OUT) x *= mk;
        v[r4] = x;
      }
      if constexpr (OBF16) {
        ushort4 hz;
        hz.x = f2b(v[0]); hz.y = f2b(v[1]); hz.z = f2b(v[2]); hz.w = f2b(v[3]);
        *(ushort4*)(oph + (size_t)t * O + o) = hz;
      } else {
        *(float4*)(opf + (size_t)t * O + o) = make_float4(v[0], v[1], v[2], v[3]);
      }
    }
  }
}

// ---------------------------------------------------------------------------
// Fused attention with 2-phase K/V prefetch. q/k/v/out t-major bf16 [B][T][C].
__global__ __launch_bounds__(256) void fused_attn(
    const unsigned short* __restrict__ qg,
    const unsigned short* __restrict__ kg,
    const unsigned short* __restrict__ vg,
    const float* __restrict__ mask,
    const float* __restrict__ ek,
    const float* __restrict__ ev,
    unsigned short* __restrict__ outp)
{
  constexpr int PITCH = 72;
  __shared__ unsigned short Qs[64 * PITCH];
  __shared__ unsigned short Ks[2][64 * PITCH];
  __shared__ unsigned short Vs[2][64 * PITCH];
  __shared__ unsigned short Ps[64 * PITCH];
  __shared__ float eks[D * 9], evs[D * 9];
  __shared__ float qekl[64 * 12];
  __shared__ float mks[2][64];

  const int t0 = blockIdx.x * 64;
  const int bh = blockIdx.y;
  const int b = bh / H, h = bh % H;
  const int tid = threadIdx.x;
  const int lane = tid & 63, w = tid >> 6;
  const int l15 = lane & 15, lhi = lane >> 4;

  const size_t base = (size_t)b * T * C + h * D;
  const unsigned short* qh = qg + base;
  const unsigned short* kh = kg + base;
  const unsigned short* vh = vg + base;

  for (int e = tid; e < D * 9; e += 256) { eks[e] = ek[e]; evs[e] = ev[e]; }
  {
    const int tl = tid & 63, d0 = (tid >> 6) << 4;
    const unsigned short* src = qh + (size_t)(t0 + tl) * C + d0;
    *(sh8*)&Qs[tl * PITCH + d0]     = *(const sh8*)(src);
    *(sh8*)&Qs[tl * PITCH + d0 + 8] = *(const sh8*)(src + 8);
  }
  __syncthreads();
  {
    const int tl = tid & 63, g = tid >> 6;
    for (int j = g; j < 9; j += 4) {
      float a = 0.f;
      for (int d = 0; d < D; ++d)
        a = fmaf(b2f(Qs[tl * PITCH + d]), eks[d * 9 + j], a);
      qekl[tl * 12 + j] = a * 0.125f;
    }
  }
  const int t_loc = w * 16 + l15;
  const int t = t0 + t_loc;
  const float mask_t = mask[b * T + t];
  const sh8 bq0 = *(const sh8*)&Qs[t_loc * PITCH + lhi * 8];
  const sh8 bq1 = *(const sh8*)&Qs[t_loc * PITCH + 32 + lhi * 8];

  const int sl = tid & 63, d0s = (tid >> 6) << 4;
  {
    const unsigned short* srck = kh + (size_t)sl * C + d0s;
    *(sh8*)&Ks[0][sl * PITCH + d0s]     = *(const sh8*)(srck);
    *(sh8*)&Ks[0][sl * PITCH + d0s + 8] = *(const sh8*)(srck + 8);
    const unsigned short* srcv = vh + (size_t)sl * C + d0s;
    sh8 u0 = *(const sh8*)(srcv);
    sh8 u1 = *(const sh8*)(srcv + 8);
#pragma unroll
    for (int j = 0; j < 8; ++j) Vs[0][(d0s + j) * PITCH + sl] = (unsigned short)u0[j];
#pragma unroll
    for (int j = 0; j < 8; ++j) Vs[0][(d0s + 8 + j) * PITCH + sl] = (unsigned short)u1[j];
    if (tid < 64) mks[0][tid] = mask[b * T + tid];
  }
  __syncthreads();

  float m_run = -1e30f, l_run = 0.f;
  f32x4 oacc[4] = {};
  int cur = 0;
  sh8 kr0, kr1, vr0, vr1;
  float mkr = 0.f;

  for (int s0 = 0; s0 < T; s0 += 64) {
    const int nxt = cur ^ 1;
    const bool more = (s0 + 64 < T);
    if (more) {
      const unsigned short* srck = kh + (size_t)(s0 + 64 + sl) * C + d0s;
      kr0 = *(const sh8*)(srck);
      kr1 = *(const sh8*)(srck + 8);
      const unsigned short* srcv = vh + (size_t)(s0 + 64 + sl) * C + d0s;
      vr0 = *(const sh8*)(srcv);
      vr1 = *(const sh8*)(srcv + 8);
      if (tid < 64) mkr = mask[b * T + s0 + 64 + tid];
    }

    float p[16];
#pragma unroll
    for (int n = 0; n < 4; ++n) {
      const sh8 a0 = *(const sh8*)&Ks[cur][(n * 16 + l15) * PITCH + lhi * 8];
      const sh8 a1 = *(const sh8*)&Ks[cur][(n * 16 + l15) * PITCH + 32 + lhi * 8];
      f32x4 acc = {};
      acc = __builtin_amdgcn_mfma_f32_16x16x32_bf16(a0, bq0, acc, 0, 0, 0);
      acc = __builtin_amdgcn_mfma_f32_16x16x32_bf16(a1, bq1, acc, 0, 0, 0);
#pragma unroll
      for (int r = 0; r < 4; ++r) {
        const int s = s0 + n * 16 + lhi * 4 + r;
        float v = acc[r] * 0.125f;
        const int j = s - t + 4;
        if ((unsigned)j < 9u) v += qekl[t_loc * 12 + j];
        if (mask_t * mks[cur][s - s0] == 0.f) v = -10000.0f;
        p[n * 4 + r] = v;
      }
    }
    float mloc = p[0];
#pragma unroll
    for (int i = 1; i < 16; ++i) mloc = fmaxf(mloc, p[i]);
    mloc = fmaxf(mloc, __shfl_xor(mloc, 16));
    mloc = fmaxf(mloc, __shfl_xor(mloc, 32));
    const float m_new = fmaxf(m_run, mloc);
    const float f = __expf(m_run - m_new);
    float sloc = 0.f;
#pragma unroll
    for (int i = 0; i < 16; ++i) { p[i] = __expf(p[i] - m_new); sloc += p[i]; }
    sloc += __shfl_xor(sloc, 16);
    sloc += __shfl_xor(sloc, 32);
    l_run = l_run * f + sloc;
    m_run = m_new;
#pragma unroll
    for (int m = 0; m < 4; ++m)
#pragma unroll
      for (int r = 0; r < 4; ++r) oacc[m][r] *= f;
#pragma unroll
    for (int n = 0; n < 4; ++n) {
      uint2 pk;
      pk.x = (unsigned)f2b(p[n * 4 + 0]) | ((unsigned)f2b(p[n * 4 + 1]) << 16);
      pk.y = (unsigned)f2b(p[n * 4 + 2]) | ((unsigned)f2b(p[n * 4 + 3]) << 16);
      *(uint2*)&Ps[t_loc * PITCH + n * 16 + lhi * 4] = pk;
    }
    asm volatile("s_waitcnt lgkmcnt(0)" ::: "memory");
    const sh8 bp0 = *(const sh8*)&Ps[t_loc * PITCH + lhi * 8];
    const sh8 bp1 = *(const sh8*)&Ps[t_loc * PITCH + 32 + lhi * 8];
#pragma unroll
    for (int m = 0; m < 4; ++m) {
      const sh8 a0 = *(const sh8*)&Vs[cur][(m * 16 + l15) * PITCH + lhi * 8];
      const sh8 a1 = *(const sh8*)&Vs[cur][(m * 16 + l15) * PITCH + 32 + lhi * 8];
      oacc[m] = __builtin_amdgcn_mfma_f32_16x16x32_bf16(a0, bp0, oacc[m], 0, 0, 0);
      oacc[m] = __builtin_amdgcn_mfma_f32_16x16x32_bf16(a1, bp1, oacc[m], 0, 0, 0);
    }
    if (t + 4 >= s0 && t < s0 + 68) {
#pragma unroll
      for (int j = 0; j < 9; ++j) {
        const int s = t + j - 4;
        if (s >= s0 && s < s0 + 64) {
          const float pv = b2f(Ps[t_loc * PITCH + (s - s0)]);
#pragma unroll
          for (int m = 0; m < 4; ++m)
#pragma unroll
            for (int r = 0; r < 4; ++r)
              oacc[m][r] = fmaf(pv, evs[(m * 16 + lhi * 4 + r) * 9 + j], oacc[m][r]);
        }
      }
    }
    if (more) {
      *(sh8*)&Ks[nxt][sl * PITCH + d0s]     = kr0;
      *(sh8*)&Ks[nxt][sl * PITCH + d0s + 8] = kr1;
#pragma unroll
      for (int j = 0; j < 8; ++j) Vs[nxt][(d0s + j) * PITCH + sl] = (unsigned short)vr0[j];
#pragma unroll
      for (int j = 0; j < 8; ++j) Vs[nxt][(d0s + 8 + j) * PITCH + sl] = (unsigned short)vr1[j];
      if (tid < 64) mks[nxt][tid] = mkr;
    }
    __syncthreads();
    cur = nxt;
  }
  const float invl = 1.f / l_run;
  unsigned short* ob = outp + (size_t)(b * T + t) * C + h * D;
#pragma unroll
  for (int m = 0; m < 4; ++m) {
    ushort4 hz;
    hz.x = f2b(oacc[m][0] * invl);
    hz.y = f2b(oacc[m][1] * invl);
    hz.z = f2b(oacc[m][2] * invl);
    hz.w = f2b(oacc[m][3] * invl);
    *(ushort4*)(ob + m * 16 + lhi * 4) = hz;
  }
}

// ---------------------------------------------------------------------------
// Wave-per-t add+layernorm, everything t-major.
template <int NP, bool MASKY, bool MASKF>
__global__ __launch_bounds__(256) void add_norm_wave(
    const float* __restrict__ xr, const float* __restrict__ ypart,
    const float* __restrict__ g, const float* __restrict__ bta,
    const float* __restrict__ mask, float* __restrict__ dst,
    unsigned short* __restrict__ dsth)
{
  const int b = blockIdx.y;
  const int t = blockIdx.x * 4 + (threadIdx.x >> 6);
  const int lane = threadIdx.x & 63;
  const float mkt = mask[b * T + t];
  const size_t rowoff = ((size_t)b * T + t) * C;
  const int ci0 = lane * 12;

  float vv[12];
  float sum = 0.f, sq = 0.f;
#pragma unroll
  for (int q = 0; q < 3; ++q) {
    const int ci = ci0 + q * 4;
    float4 xv = *(const float4*)(xr + rowoff + ci);
    float4 yv = make_float4(0.f, 0.f, 0.f, 0.f);
#pragma unroll
    for (int p = 0; p < NP; ++p) {
      float4 t4 = *(const float4*)(ypart + (size_t)p * B * T * C + rowoff + ci);
      yv.x += t4.x; yv.y += t4.y; yv.z += t4.z; yv.w += t4.w;
    }
    if (MASKY) { yv.x *= mkt; yv.y *= mkt; yv.z *= mkt; yv.w *= mkt; }
    const float v0 = xv.x + yv.x, v1 = xv.y + yv.y;
    const float v2 = xv.z + yv.z, v3 = xv.w + yv.w;
    vv[q * 4 + 0] = v0; vv[q * 4 + 1] = v1; vv[q * 4 + 2] = v2; vv[q * 4 + 3] = v3;
    sum += v0 + v1 + v2 + v3;
    sq = fmaf(v0, v0, fmaf(v1, v1, fmaf(v2, v2, fmaf(v3, v3, sq))));
  }
#pragma unroll
  for (int o = 32; o > 0; o >>= 1) {
    sum += __shfl_xor(sum, o);
    sq += __shfl_xor(sq, o);
  }
  const float m = sum * (1.f / C);
  const float rs = rsqrtf(sq * (1.f / C) - m * m + 1e-5f);
#pragma unroll
  for (int q = 0; q < 3; ++q) {
    const int ci = ci0 + q * 4;
    float4 gv = *(const float4*)(g + ci);
    float4 bv = *(const float4*)(bta + ci);
    float o0 = (vv[q * 4 + 0] - m) * rs * gv.x + bv.x;
    float o1 = (vv[q * 4 + 1] - m) * rs * gv.y + bv.y;
    float o2 = (vv[q * 4 + 2] - m) * rs * gv.z + bv.z;
    float o3 = (vv[q * 4 + 3] - m) * rs * gv.w + bv.w;
    if (MASKF) { o0 *= mkt; o1 *= mkt; o2 *= mkt; o3 *= mkt; }
    *(float4*)(dst + rowoff + ci) = make_float4(o0, o1, o2, o3);
    const float hm = MASKF ? 1.f : mkt;
    ushort4 hz;
    hz.x = f2b(o0 * hm); hz.y = f2b(o1 * hm); hz.z = f2b(o2 * hm); hz.w = f2b(o3 * hm);
    *(ushort4*)(dsth + rowoff + ci) = hz;
  }
}

}  // namespace

extern "C" void kernel_launch(void* const* d_in, const int* in_sizes, int n_in,
                              void* d_out, int out_size, void* d_ws, size_t ws_size,
                              hipStream_t stream) {
  const float* x_in = (const float*)d_in[0];
  const float* mask = (const float*)d_in[1];
  const float* Wq = (const float*)d_in[2];
  const float* bq = (const float*)d_in[3];
  const float* Wk = (const float*)d_in[4];
  const float* bk = (const float*)d_in[5];
  const float* Wv = (const float*)d_in[6];
  const float* bv = (const float*)d_in[7];
  const float* Wo = (const float*)d_in[8];
  const float* bo = (const float*)d_in[9];
  const float* ek = (const float*)d_in[10];
  const float* ev = (const float*)d_in[11];
  const float* w1 = (const float*)d_in[12];
  const float* b1 = (const float*)d_in[13];
  const float* w2 = (const float*)d_in[14];
  const float* b2 = (const float*)d_in[15];
  const float* n1g = (const float*)d_in[16];
  const float* n1b = (const float*)d_in[17];
  const float* n2g = (const float*)d_in[18];
  const float* n2b = (const float*)d_in[19];

  float* ws = (float*)d_ws;
  const size_t SZ_X = (size_t)B * C * T;
  const size_t SZ_W1 = (size_t)3 * FF * C;        // per-layer tiled FFN weights
  float* xr    = ws;
  float* xr1   = xr + SZ_X;
  float* ypart = xr1 + SZ_X;
  unsigned short* xbh = (unsigned short*)(ypart + 4 * SZ_X);
  unsigned short* xfh = xbh + SZ_X;
  unsigned short* qbh = xfh + SZ_X;
  unsigned short* kbh = qbh + SZ_X;
  unsigned short* vbh = kbh + SZ_X;
  unsigned short* hidh = vbh + SZ_X;              // [B][T][FF]
  unsigned short* w1t = hidh + (size_t)B * FF * T;        // [NL][3][FF*C]
  unsigned short* w2t = w1t + (size_t)NL * SZ_W1;         // [NL][3][C*FF]
  unsigned short* wqt = w2t + (size_t)NL * SZ_W1;         // [NL][C*C]
  unsigned short* wkt = wqt + (size_t)NL * C * C;
  unsigned short* wvt = wkt + (size_t)NL * C * C;
  unsigned short* wot = wvt + (size_t)NL * C * C;
  float* outp = (float*)d_out;

  const dim3 blk(256);
  // upfront: input transpose + ALL layers' weight conversion (2 big launches)
  transpose_cvt_in<<<dim3(T / 32, C / 32, B), blk, 0, stream>>>(x_in, xbh, xr);
  cvt_qkvo_tiled<<<dim3((C * C / 8) / 256, 4, NL), blk, 0, stream>>>(
      Wq, Wk, Wv, Wo, wqt, wkt, wvt, wot);
  cvt_ffn_tiled<<<dim3((FF * C / 8) / 256, 2, NL), blk, 0, stream>>>(
      w1, w2, w1t, w2t);

  for (int i = 0; i < NL; ++i) {
    const size_t wOff = (size_t)i * C * C;
    const unsigned short* w1l = w1t + (size_t)i * SZ_W1;
    const unsigned short* w2l = w2t + (size_t)i * SZ_W1;
    // QKV projection -> bf16 q,k,v   (576 blocks, BN=64)
    mfma_conv<1, 64, 1, false, false, true><<<dim3(8 * 18 * 4), blk, 0, stream>>>(
        xbh, wqt + wOff, wkt + wOff, wvt + wOff,
        bq + i * C, bk + i * C, bv + i * C, mask,
        qbh, kbh, vbh, C, C, 6, 4);
    // fused attention -> bf16
    fused_attn<<<dim3(T / 64, B * H), blk, 0, stream>>>(
        qbh, kbh, vbh, mask, ek + (size_t)i * D * 9, ev + (size_t)i * D * 9, hidh);
    // Wo projection: split-K3 -> fp32 partials   (576 blocks, BN=64)
    mfma_conv<1, 64, 3, false, false, false><<<dim3(8 * 6 * 12), blk, 0, stream>>>(
        hidh, wot + wOff, wot + wOff, wot + wOff,
        bo + i * C, bo + i * C, bo + i * C, mask,
        ypart, ypart, ypart, C, C, 6, 12);
    add_norm_wave<3, false, false><<<dim3(T / 4, B), blk, 0, stream>>>(
        xr, ypart, n1g + i * C, n1b + i * C, mask, xr1, xfh);
    // FFN up: BN=128 (wave 64x64), GELU+mask, bf16 out   (384 blocks)
    mfma_conv<3, 128, 1, true, true, true><<<dim3(4 * 24 * 4), blk, 0, stream>>>(
        xfh, w1l, w1l, w1l, b1 + i * FF, b1 + i * FF, b1 + i * FF, mask,
        hidh, hidh, hidh, C, FF, 24, 4);
    // FFN down: BN=128, split-K4 -> fp32 partials   (384 blocks)
    mfma_conv<3, 128, 4, false, false, false><<<dim3(4 * 6 * 16), blk, 0, stream>>>(
        hidh, w2l, w2l, w2l, b2 + i * C, b2 + i * C, b2 + i * C, mask,
        ypart, ypart, ypart, FF, C, 6, 16);
    add_norm_wave<4, true, true><<<dim3(T / 4, B), blk, 0, stream>>>(
        xr1, ypart, n2g + i * C, n2b + i * C, mask, xr, xbh);
  }
  transpose_out<<<dim3(T / 32, C / 32, B), blk, 0, stream>>>(xr, outp);
}

// Round 12
// 1181.780 us; speedup vs baseline: 1.9262x; 1.0791x over previous
//
#include <hip/hip_runtime.h>
#include <cstddef>

namespace {

constexpr int B  = 4;
constexpr int C  = 768;
constexpr int T  = 512;
constexpr int H  = 12;
constexpr int D  = 64;
constexpr int NL = 6;
constexpr int W  = 4;
constexpr int FF = 3072;

typedef __attribute__((ext_vector_type(8))) short sh8;
typedef __attribute__((ext_vector_type(4))) float f32x4;

__device__ inline float gelu_exact(float x) {
  return 0.5f * x * (1.0f + erff(x * 0.70710678118654752440f));
}
__device__ inline unsigned short f2b(float f) {
  unsigned u = __float_as_uint(f);
  unsigned r = (u + 0x7fffu + ((u >> 16) & 1u)) >> 16;
  return (unsigned short)r;
}
__device__ inline float b2f(unsigned short u) {
  return __uint_as_float((unsigned)u << 16);
}
__device__ inline void gload_lds16(const void* g, void* l) {
  __builtin_amdgcn_global_load_lds(
      (const __attribute__((address_space(1))) unsigned int*)g,
      (__attribute__((address_space(3))) unsigned int*)l, 16, 0, 0);
}

// ---------------------------------------------------------------------------
// Layer-0 input: x [B][C][T] fp32 c-major -> bf16 t-major + fp32 t-major
__global__ __launch_bounds__(256) void transpose_cvt_in(
    const float* __restrict__ s, unsigned short* __restrict__ dh,
    float* __restrict__ df)
{
  __shared__ float tile[32][33];
  const int b = blockIdx.z;
  const int c0 = blockIdx.y * 32, t0 = blockIdx.x * 32;
  const int tx = threadIdx.x & 31, ty = threadIdx.x >> 5;
  const float* sp = s + ((size_t)b * C + c0) * T + t0;
#pragma unroll
  for (int i = 0; i < 4; ++i)
    tile[ty + i * 8][tx] = sp[(size_t)(ty + i * 8) * T + tx];
  __syncthreads();
  unsigned short* dph = dh + ((size_t)b * T + t0) * C + c0;
  float* dpf = df + ((size_t)b * T + t0) * C + c0;
#pragma unroll
  for (int i = 0; i < 4; ++i) {
    const float v = tile[tx][ty + i * 8];
    dph[(size_t)(ty + i * 8) * C + tx] = f2b(v);
    dpf[(size_t)(ty + i * 8) * C + tx] = v;
  }
}

// Final residual: fp32 t-major [B][T][C] -> fp32 c-major [B][C][T]
__global__ __launch_bounds__(256) void transpose_out(
    const float* __restrict__ s, float* __restrict__ d)
{
  __shared__ float tile[32][33];
  const int b = blockIdx.z;
  const int c0 = blockIdx.y * 32, t0 = blockIdx.x * 32;
  const int tx = threadIdx.x & 31, ty = threadIdx.x >> 5;
  const float* sp = s + ((size_t)b * T + t0) * C + c0;
#pragma unroll
  for (int i = 0; i < 4; ++i)
    tile[ty + i * 8][tx] = sp[(size_t)(ty + i * 8) * C + tx];
  __syncthreads();
  float* dp = d + ((size_t)b * C + c0) * T + t0;
#pragma unroll
  for (int i = 0; i < 4; ++i)
    dp[(size_t)(ty + i * 8) * T + tx] = tile[tx][ty + i * 8];
}

// ---------------------------------------------------------------------------
// QKVO weights fp32 [C][C] -> bf16 fragment-tiled, LDS-staged (both phases
// coalesced). Block = one (mt, 4-ks) region: 16 rows x 128 cols.
__global__ __launch_bounds__(256) void cvt_qkvo_tiled(
    const float* __restrict__ q, const float* __restrict__ k,
    const float* __restrict__ v, const float* __restrict__ o,
    unsigned short* __restrict__ dq, unsigned short* __restrict__ dk,
    unsigned short* __restrict__ dv, unsigned short* __restrict__ dov)
{
  __shared__ float lds[16][132];   // pitch 132 f32: 16B-aligned rows, +4 banks
  const int z = blockIdx.y;
  const size_t loff = (size_t)blockIdx.z * C * C;
  const float* s = (z == 0 ? q : z == 1 ? k : z == 2 ? v : o) + loff;
  unsigned short* d = (z == 0 ? dq : z == 1 ? dk : z == 2 ? dv : dov) + loff;
  constexpr int KST = C / 32;      // 24
  constexpr int KSG = KST / 4;     // 6
  const int mt = blockIdx.x / KSG;
  const int ksg = blockIdx.x % KSG;
  const int tid = threadIdx.x;
  // load: 16 rows x 32 float4 (coalesced)
#pragma unroll
  for (int p = 0; p < 2; ++p) {
    const int f = tid + p * 256;
    const int row = f >> 5, c4 = f & 31;
    float4 vv = *(const float4*)(s + (size_t)(mt * 16 + row) * C + ksg * 128 + c4 * 4);
    *(float4*)&lds[row][c4 * 4] = vv;
  }
  __syncthreads();
  // write: 256 chunks of 16B, contiguous per (ksl,lane) (coalesced)
  const int ksl = tid >> 6, lane = tid & 63;
  const int l15 = lane & 15, lhi = lane >> 4;
  sh8 u;
#pragma unroll
  for (int j = 0; j < 8; ++j)
    u[j] = (short)f2b(lds[l15][ksl * 32 + lhi * 8 + j]);
  *(sh8*)(d + ((size_t)(mt * KST + ksg * 4 + ksl) * 64 + lane) * 8) = u;
}

// FFN weights [O][Ci][3] fp32 -> 3 tap planes fragment-tiled, LDS-staged.
// Block = one (mt, 4-ks) region: 16 rows x 128 cols x 3 taps = 384 f32/row.
__global__ __launch_bounds__(256) void cvt_ffn_tiled(
    const float* __restrict__ s1, const float* __restrict__ s2,
    unsigned short* __restrict__ d1, unsigned short* __restrict__ d2)
{
  __shared__ float lds[16][388];   // pitch 388 f32: 16B-aligned rows, +4 banks
  const int z = blockIdx.y;
  const int layer = blockIdx.z;
  const float* src = (z ? s2 : s1) + (size_t)layer * FF * C * 3;
  unsigned short* dst = (z ? d2 : d1) + (size_t)layer * 3 * FF * C;
  const int O  = z ? C : FF;
  const int Ci = z ? FF : C;
  const int KST = Ci >> 5;
  const int KSG = KST >> 2;        // ks-groups of 4 (w1: 6, w2: 24)
  const int mt = blockIdx.x / KSG;
  const int ksg = blockIdx.x % KSG;
  const int tid = threadIdx.x;
  const size_t rowlen = (size_t)Ci * 3;
  // load: 16 rows x 96 float4 = 1536 float4 (coalesced)
#pragma unroll
  for (int p = 0; p < 6; ++p) {
    const int f = tid + p * 256;
    const int row = f / 96, c4 = f % 96;
    float4 vv = *(const float4*)(src + (size_t)(mt * 16 + row) * rowlen +
                                 ksg * 384 + c4 * 4);
    *(float4*)&lds[row][c4 * 4] = vv;
  }
  __syncthreads();
  // write: 768 chunks of 16B; per tap a contiguous 4KB run (coalesced)
#pragma unroll
  for (int qq = 0; qq < 3; ++qq) {
    const int oc = tid + qq * 256;
    const int tap = oc >> 8, rem = oc & 255;
    const int ksl = rem >> 6, lane = rem & 63;
    const int l15 = lane & 15, lhi = lane >> 4;
    sh8 u;
#pragma unroll
    for (int j = 0; j < 8; ++j)
      u[j] = (short)f2b(lds[l15][(ksl * 32 + lhi * 8 + j) * 3 + tap]);
    *(sh8*)(dst + (size_t)tap * O * Ci +
            ((size_t)(mt * KST + ksg * 4 + ksl) * 64 + lane) * 8) = u;
  }
}

// ---------------------------------------------------------------------------
// 256-thread MFMA conv (BM=128 x BN∈{64,128}), 2-phase double-buffered.
// BN=128: 4 waves 2x2, each wave 64x64 out (acc[4][4]).
// 1-D grid, XCD-chunked swizzle: blocks sharing a weight panel co-locate.
template <int TAPS, int BN, int KSPLIT, bool GELU, bool MASK_OUT, bool OBF16>
__global__ __launch_bounds__(256) void mfma_conv(
    const unsigned short* __restrict__ xin,
    const unsigned short* __restrict__ w0p, const unsigned short* __restrict__ w1p,
    const unsigned short* __restrict__ w2p,
    const float* __restrict__ b0, const float* __restrict__ b1,
    const float* __restrict__ b2,
    const float* __restrict__ mask,
    void* __restrict__ o0p, void* __restrict__ o1p, void* __restrict__ o2p,
    int Cin, int O, int tilesPerPlane, int nz)
{
  constexpr int ROWS_B = BN + TAPS - 1;
  constexpr int PB = 40;
  constexpr int NPASS = BN / 64;
  constexpr int NF = BN / 32;
  constexpr int NT = T / BN;
  __shared__ unsigned short Aw[2][TAPS * 8 * 512];
  __shared__ unsigned short Bx[2][ROWS_B * PB];

  const int nwg = gridDim.x;
  const int orig = blockIdx.x;
  const int wg = (orig & 7) * (nwg >> 3) + (orig >> 3);
  const int txt = wg % NT;
  const int rest = wg / NT;
  const int zz = rest % nz;
  const int ty = rest / nz;

  const int b  = zz / KSPLIT;
  const int kk = zz % KSPLIT;
  const int TOFF = (TAPS == 3) ? -1 : 0;
  const int t0 = txt * BN;
  const int plane = ty / tilesPerPlane;
  const int mt0 = (ty % tilesPerPlane) * 8;
  const int o0 = mt0 * 16;

  const int tid = threadIdx.x;
  const int lane = tid & 63, wid = tid >> 6;
  const int wm = wid >> 1, wn = wid & 1;
  const int l15 = lane & 15, lhi = lane >> 4;
  const int bmask = b * T;

  const unsigned short* wsel = plane == 0 ? w0p : (plane == 1 ? w1p : w2p);
  const float* bp = plane == 0 ? b0 : (plane == 1 ? b1 : b2);

  const int KST = Cin >> 5;
  const int kchunk = KST / KSPLIT;
  const int ks0 = kk * kchunk, ks1 = ks0 + kchunk;
  const int OT = O >> 4;

  const unsigned short* xb_ = xin + (size_t)b * T * Cin;

  sh8 breg[NPASS], breg2;
  auto stageA = [&](int ks, int buf) {
#pragma unroll
    for (int tap = 0; tap < TAPS; ++tap) {
#pragma unroll
      for (int j = 0; j < 2; ++j) {
        const int rt = wid * 2 + j;
        const unsigned short* src =
            wsel + (((size_t)tap * OT + mt0 + rt) * KST + ks) * 512 + lane * 8;
        gload_lds16(src, &Aw[buf][(tap * 8 + rt) * 512]);
      }
    }
  };
  auto loadB = [&](int ks) {
    const int c0 = ks << 5;
#pragma unroll
    for (int p = 0; p < NPASS; ++p) {
      const int idx = tid + p * 256;
      const int row = idx >> 2, c8 = (idx & 3) << 3;
      const int tsrc = t0 + row + TOFF;
      breg[p] = (sh8)0;
      if ((unsigned)tsrc < (unsigned)T)
        breg[p] = *(const sh8*)(xb_ + (size_t)tsrc * Cin + c0 + c8);
    }
    if constexpr (TAPS == 3) {
      breg2 = (sh8)0;
      if (tid < 8) {
        const int row = BN + (tid >> 2), c8 = (tid & 3) << 3;
        const int ts2 = t0 + row + TOFF;
        if ((unsigned)ts2 < (unsigned)T)
          breg2 = *(const sh8*)(xb_ + (size_t)ts2 * Cin + c0 + c8);
      }
    }
  };
  auto writeB = [&](int buf) {
#pragma unroll
    for (int p = 0; p < NPASS; ++p) {
      const int idx = tid + p * 256;
      *(sh8*)&Bx[buf][(idx >> 2) * PB + ((idx & 3) << 3)] = breg[p];
    }
    if constexpr (TAPS == 3) {
      if (tid < 8)
        *(sh8*)&Bx[buf][(BN + (tid >> 2)) * PB + ((tid & 3) << 3)] = breg2;
    }
  };

  f32x4 acc[4][NF] = {};

  int cur = 0;
  stageA(ks0, 0);
  loadB(ks0);
  writeB(0);
  __syncthreads();

  for (int ks = ks0; ks < ks1; ++ks) {
    const int nxt = cur ^ 1;
    const bool more = (ks + 1 < ks1);
    if (more) { stageA(ks + 1, nxt); loadB(ks + 1); }
#pragma unroll
    for (int tap = 0; tap < TAPS; ++tap) {
      sh8 af[4], bfr[NF];
#pragma unroll
      for (int m = 0; m < 4; ++m)
        af[m] = *(const sh8*)&Aw[cur][(tap * 8 + wm * 4 + m) * 512 + lane * 8];
#pragma unroll
      for (int n = 0; n < NF; ++n)
        bfr[n] = *(const sh8*)&Bx[cur][(wn * (NF * 16) + n * 16 + l15 + tap) * PB + lhi * 8];
#pragma unroll
      for (int m = 0; m < 4; ++m)
#pragma unroll
        for (int n = 0; n < NF; ++n)
          acc[m][n] = __builtin_amdgcn_mfma_f32_16x16x32_bf16(
              af[m], bfr[n], acc[m][n], 0, 0, 0);
    }
    if (more) writeB(nxt);
    __syncthreads();
    cur = nxt;
  }

  void* obase = plane == 0 ? o0p : (plane == 1 ? o1p : o2p);
  unsigned short* oph = (unsigned short*)obase + (size_t)b * T * O;
  float* opf = (float*)obase + ((size_t)kk * B + b) * (size_t)T * O;
#pragma unroll
  for (int m = 0; m < 4; ++m) {
    const int o = o0 + (wm * 4 + m) * 16 + (lhi << 2);
#pragma unroll
    for (int n = 0; n < NF; ++n) {
      const int t = t0 + wn * (NF * 16) + n * 16 + l15;
      const float mk = MASK_OUT ? mask[bmask + t] : 1.f;
      float v[4];
#pragma unroll
      for (int r4 = 0; r4 < 4; ++r4) {
        float x = acc[m][n][r4];
        if (KSPLIT > 1) {
          if (kk == 0) x += bp[o + r4];
        } else {
          x += bp[o + r4];
        }
        if (GELU) x = gelu_exact(x);
        if (MASK_OUT) x *= mk;
        v[r4] = x;
      }
      if constexpr (OBF16) {
        ushort4 hz;
        hz.x = f2b(v[0]); hz.y = f2b(v[1]); hz.z = f2b(v[2]); hz.w = f2b(v[3]);
        *(ushort4*)(oph + (size_t)t * O + o) = hz;
      } else {
        *(float4*)(opf + (size_t)t * O + o) = make_float4(v[0], v[1], v[2], v[3]);
      }
    }
  }
}

// ---------------------------------------------------------------------------
// Fused attention with 2-phase K/V prefetch. q/k/v/out t-major bf16 [B][T][C].
__global__ __launch_bounds__(256) void fused_attn(
    const unsigned short* __restrict__ qg,
    const unsigned short* __restrict__ kg,
    const unsigned short* __restrict__ vg,
    const float* __restrict__ mask,
    const float* __restrict__ ek,
    const float* __restrict__ ev,
    unsigned short* __restrict__ outp)
{
  constexpr int PITCH = 72;
  __shared__ unsigned short Qs[64 * PITCH];
  __shared__ unsigned short Ks[2][64 * PITCH];
  __shared__ unsigned short Vs[2][64 * PITCH];
  __shared__ unsigned short Ps[64 * PITCH];
  __shared__ float eks[D * 9], evs[D * 9];
  __shared__ float qekl[64 * 12];
  __shared__ float mks[2][64];

  const int t0 = blockIdx.x * 64;
  const int bh = blockIdx.y;
  const int b = bh / H, h = bh % H;
  const int tid = threadIdx.x;
  const int lane = tid & 63, w = tid >> 6;
  const int l15 = lane & 15, lhi = lane >> 4;

  const size_t base = (size_t)b * T * C + h * D;
  const unsigned short* qh = qg + base;
  const unsigned short* kh = kg + base;
  const unsigned short* vh = vg + base;

  for (int e = tid; e < D * 9; e += 256) { eks[e] = ek[e]; evs[e] = ev[e]; }
  {
    const int tl = tid & 63, d0 = (tid >> 6) << 4;
    const unsigned short* src = qh + (size_t)(t0 + tl) * C + d0;
    *(sh8*)&Qs[tl * PITCH + d0]     = *(const sh8*)(src);
    *(sh8*)&Qs[tl * PITCH + d0 + 8] = *(const sh8*)(src + 8);
  }
  __syncthreads();
  {
    const int tl = tid & 63, g = tid >> 6;
    for (int j = g; j < 9; j += 4) {
      float a = 0.f;
      for (int d = 0; d < D; ++d)
        a = fmaf(b2f(Qs[tl * PITCH + d]), eks[d * 9 + j], a);
      qekl[tl * 12 + j] = a * 0.125f;
    }
  }
  const int t_loc = w * 16 + l15;
  const int t = t0 + t_loc;
  const float mask_t = mask[b * T + t];
  const sh8 bq0 = *(const sh8*)&Qs[t_loc * PITCH + lhi * 8];
  const sh8 bq1 = *(const sh8*)&Qs[t_loc * PITCH + 32 + lhi * 8];

  const int sl = tid & 63, d0s = (tid >> 6) << 4;
  {
    const unsigned short* srck = kh + (size_t)sl * C + d0s;
    *(sh8*)&Ks[0][sl * PITCH + d0s]     = *(const sh8*)(srck);
    *(sh8*)&Ks[0][sl * PITCH + d0s + 8] = *(const sh8*)(srck + 8);
    const unsigned short* srcv = vh + (size_t)sl * C + d0s;
    sh8 u0 = *(const sh8*)(srcv);
    sh8 u1 = *(const sh8*)(srcv + 8);
#pragma unroll
    for (int j = 0; j < 8; ++j) Vs[0][(d0s + j) * PITCH + sl] = (unsigned short)u0[j];
#pragma unroll
    for (int j = 0; j < 8; ++j) Vs[0][(d0s + 8 + j) * PITCH + sl] = (unsigned short)u1[j];
    if (tid < 64) mks[0][tid] = mask[b * T + tid];
  }
  __syncthreads();

  float m_run = -1e30f, l_run = 0.f;
  f32x4 oacc[4] = {};
  int cur = 0;
  sh8 kr0, kr1, vr0, vr1;
  float mkr = 0.f;

  for (int s0 = 0; s0 < T; s0 += 64) {
    const int nxt = cur ^ 1;
    const bool more = (s0 + 64 < T);
    if (more) {
      const unsigned short* srck = kh + (size_t)(s0 + 64 + sl) * C + d0s;
      kr0 = *(const sh8*)(srck);
      kr1 = *(const sh8*)(srck + 8);
      const unsigned short* srcv = vh + (size_t)(s0 + 64 + sl) * C + d0s;
      vr0 = *(const sh8*)(srcv);
      vr1 = *(const sh8*)(srcv + 8);
      if (tid < 64) mkr = mask[b * T + s0 + 64 + tid];
    }

    float p[16];
#pragma unroll
    for (int n = 0; n < 4; ++n) {
      const sh8 a0 = *(const sh8*)&Ks[cur][(n * 16 + l15) * PITCH + lhi * 8];
      const sh8 a1 = *(const sh8*)&Ks[cur][(n * 16 + l15) * PITCH + 32 + lhi * 8];
      f32x4 acc = {};
      acc = __builtin_amdgcn_mfma_f32_16x16x32_bf16(a0, bq0, acc, 0, 0, 0);
      acc = __builtin_amdgcn_mfma_f32_16x16x32_bf16(a1, bq1, acc, 0, 0, 0);
#pragma unroll
      for (int r = 0; r < 4; ++r) {
        const int s = s0 + n * 16 + lhi * 4 + r;
        float v = acc[r] * 0.125f;
        const int j = s - t + 4;
        if ((unsigned)j < 9u) v += qekl[t_loc * 12 + j];
        if (mask_t * mks[cur][s - s0] == 0.f) v = -10000.0f;
        p[n * 4 + r] = v;
      }
    }
    float mloc = p[0];
#pragma unroll
    for (int i = 1; i < 16; ++i) mloc = fmaxf(mloc, p[i]);
    mloc = fmaxf(mloc, __shfl_xor(mloc, 16));
    mloc = fmaxf(mloc, __shfl_xor(mloc, 32));
    const float m_new = fmaxf(m_run, mloc);
    const float f = __expf(m_run - m_new);
    float sloc = 0.f;
#pragma unroll
    for (int i = 0; i < 16; ++i) { p[i] = __expf(p[i] - m_new); sloc += p[i]; }
    sloc += __shfl_xor(sloc, 16);
    sloc += __shfl_xor(sloc, 32);
    l_run = l_run * f + sloc;
    m_run = m_new;
#pragma unroll
    for (int m = 0; m < 4; ++m)
#pragma unroll
      for (int r = 0; r < 4; ++r) oacc[m][r] *= f;
#pragma unroll
    for (int n = 0; n < 4; ++n) {
      uint2 pk;
      pk.x = (unsigned)f2b(p[n * 4 + 0]) | ((unsigned)f2b(p[n * 4 + 1]) << 16);
      pk.y = (unsigned)f2b(p[n * 4 + 2]) | ((unsigned)f2b(p[n * 4 + 3]) << 16);
      *(uint2*)&Ps[t_loc * PITCH + n * 16 + lhi * 4] = pk;
    }
    asm volatile("s_waitcnt lgkmcnt(0)" ::: "memory");
    const sh8 bp0 = *(const sh8*)&Ps[t_loc * PITCH + lhi * 8];
    const sh8 bp1 = *(const sh8*)&Ps[t_loc * PITCH + 32 + lhi * 8];
#pragma unroll
    for (int m = 0; m < 4; ++m) {
      const sh8 a0 = *(const sh8*)&Vs[cur][(m * 16 + l15) * PITCH + lhi * 8];
      const sh8 a1 = *(const sh8*)&Vs[cur][(m * 16 + l15) * PITCH + 32 + lhi * 8];
      oacc[m] = __builtin_amdgcn_mfma_f32_16x16x32_bf16(a0, bp0, oacc[m], 0, 0, 0);
      oacc[m] = __builtin_amdgcn_mfma_f32_16x16x32_bf16(a1, bp1, oacc[m], 0, 0, 0);
    }
    if (t + 4 >= s0 && t < s0 + 68) {
#pragma unroll
      for (int j = 0; j < 9; ++j) {
        const int s = t + j - 4;
        if (s >= s0 && s < s0 + 64) {
          const float pv = b2f(Ps[t_loc * PITCH + (s - s0)]);
#pragma unroll
          for (int m = 0; m < 4; ++m)
#pragma unroll
            for (int r = 0; r < 4; ++r)
              oacc[m][r] = fmaf(pv, evs[(m * 16 + lhi * 4 + r) * 9 + j], oacc[m][r]);
        }
      }
    }
    if (more) {
      *(sh8*)&Ks[nxt][sl * PITCH + d0s]     = kr0;
      *(sh8*)&Ks[nxt][sl * PITCH + d0s + 8] = kr1;
#pragma unroll
      for (int j = 0; j < 8; ++j) Vs[nxt][(d0s + j) * PITCH + sl] = (unsigned short)vr0[j];
#pragma unroll
      for (int j = 0; j < 8; ++j) Vs[nxt][(d0s + 8 + j) * PITCH + sl] = (unsigned short)vr1[j];
      if (tid < 64) mks[nxt][tid] = mkr;
    }
    __syncthreads();
    cur = nxt;
  }
  const float invl = 1.f / l_run;
  unsigned short* ob = outp + (size_t)(b * T + t) * C + h * D;
#pragma unroll
  for (int m = 0; m < 4; ++m) {
    ushort4 hz;
    hz.x = f2b(oacc[m][0] * invl);
    hz.y = f2b(oacc[m][1] * invl);
    hz.z = f2b(oacc[m][2] * invl);
    hz.w = f2b(oacc[m][3] * invl);
    *(ushort4*)(ob + m * 16 + lhi * 4) = hz;
  }
}

// ---------------------------------------------------------------------------
// Wave-per-t add+layernorm, everything t-major.
template <int NP, bool MASKY, bool MASKF>
__global__ __launch_bounds__(256) void add_norm_wave(
    const float* __restrict__ xr, const float* __restrict__ ypart,
    const float* __restrict__ g, const float* __restrict__ bta,
    const float* __restrict__ mask, float* __restrict__ dst,
    unsigned short* __restrict__ dsth)
{
  const int b = blockIdx.y;
  const int t = blockIdx.x * 4 + (threadIdx.x >> 6);
  const int lane = threadIdx.x & 63;
  const float mkt = mask[b * T + t];
  const size_t rowoff = ((size_t)b * T + t) * C;
  const int ci0 = lane * 12;

  float vv[12];
  float sum = 0.f, sq = 0.f;
#pragma unroll
  for (int q = 0; q < 3; ++q) {
    const int ci = ci0 + q * 4;
    float4 xv = *(const float4*)(xr + rowoff + ci);
    float4 yv = make_float4(0.f, 0.f, 0.f, 0.f);
#pragma unroll
    for (int p = 0; p < NP; ++p) {
      float4 t4 = *(const float4*)(ypart + (size_t)p * B * T * C + rowoff + ci);
      yv.x += t4.x; yv.y += t4.y; yv.z += t4.z; yv.w += t4.w;
    }
    if (MASKY) { yv.x *= mkt; yv.y *= mkt; yv.z *= mkt; yv.w *= mkt; }
    const float v0 = xv.x + yv.x, v1 = xv.y + yv.y;
    const float v2 = xv.z + yv.z, v3 = xv.w + yv.w;
    vv[q * 4 + 0] = v0; vv[q * 4 + 1] = v1; vv[q * 4 + 2] = v2; vv[q * 4 + 3] = v3;
    sum += v0 + v1 + v2 + v3;
    sq = fmaf(v0, v0, fmaf(v1, v1, fmaf(v2, v2, fmaf(v3, v3, sq))));
  }
#pragma unroll
  for (int o = 32; o > 0; o >>= 1) {
    sum += __shfl_xor(sum, o);
    sq += __shfl_xor(sq, o);
  }
  const float m = sum * (1.f / C);
  const float rs = rsqrtf(sq * (1.f / C) - m * m + 1e-5f);
#pragma unroll
  for (int q = 0; q < 3; ++q) {
    const int ci = ci0 + q * 4;
    float4 gv = *(const float4*)(g + ci);
    float4 bv = *(const float4*)(bta + ci);
    float o0 = (vv[q * 4 + 0] - m) * rs * gv.x + bv.x;
    float o1 = (vv[q * 4 + 1] - m) * rs * gv.y + bv.y;
    float o2 = (vv[q * 4 + 2] - m) * rs * gv.z + bv.z;
    float o3 = (vv[q * 4 + 3] - m) * rs * gv.w + bv.w;
    if (MASKF) { o0 *= mkt; o1 *= mkt; o2 *= mkt; o3 *= mkt; }
    *(float4*)(dst + rowoff + ci) = make_float4(o0, o1, o2, o3);
    const float hm = MASKF ? 1.f : mkt;
    ushort4 hz;
    hz.x = f2b(o0 * hm); hz.y = f2b(o1 * hm); hz.z = f2b(o2 * hm); hz.w = f2b(o3 * hm);
    *(ushort4*)(dsth + rowoff + ci) = hz;
  }
}

}  // namespace

extern "C" void kernel_launch(void* const* d_in, const int* in_sizes, int n_in,
                              void* d_out, int out_size, void* d_ws, size_t ws_size,
                              hipStream_t stream) {
  const float* x_in = (const float*)d_in[0];
  const float* mask = (const float*)d_in[1];
  const float* Wq = (const float*)d_in[2];
  const float* bq = (const float*)d_in[3];
  const float* Wk = (const float*)d_in[4];
  const float* bk = (const float*)d_in[5];
  const float* Wv = (const float*)d_in[6];
  const float* bv = (const float*)d_in[7];
  const float* Wo = (const float*)d_in[8];
  const float* bo = (const float*)d_in[9];
  const float* ek = (const float*)d_in[10];
  const float* ev = (const float*)d_in[11];
  const float* w1 = (const float*)d_in[12];
  const float* b1 = (const float*)d_in[13];
  const float* w2 = (const float*)d_in[14];
  const float* b2 = (const float*)d_in[15];
  const float* n1g = (const float*)d_in[16];
  const float* n1b = (const float*)d_in[17];
  const float* n2g = (const float*)d_in[18];
  const float* n2b = (const float*)d_in[19];

  float* ws = (float*)d_ws;
  const size_t SZ_X = (size_t)B * C * T;
  const size_t SZ_W1 = (size_t)3 * FF * C;
  float* xr    = ws;
  float* xr1   = xr + SZ_X;
  float* ypart = xr1 + SZ_X;
  unsigned short* xbh = (unsigned short*)(ypart + 4 * SZ_X);
  unsigned short* xfh = xbh + SZ_X;
  unsigned short* qbh = xfh + SZ_X;
  unsigned short* kbh = qbh + SZ_X;
  unsigned short* vbh = kbh + SZ_X;
  unsigned short* hidh = vbh + SZ_X;
  unsigned short* w1t = hidh + (size_t)B * FF * T;
  unsigned short* w2t = w1t + (size_t)NL * SZ_W1;
  unsigned short* wqt = w2t + (size_t)NL * SZ_W1;
  unsigned short* wkt = wqt + (size_t)NL * C * C;
  unsigned short* wvt = wkt + (size_t)NL * C * C;
  unsigned short* wot = wvt + (size_t)NL * C * C;
  float* outp = (float*)d_out;

  const dim3 blk(256);
  // upfront: input transpose + ALL layers' weight conversion
  transpose_cvt_in<<<dim3(T / 32, C / 32, B), blk, 0, stream>>>(x_in, xbh, xr);
  cvt_qkvo_tiled<<<dim3((C / 16) * (C / 128), 4, NL), blk, 0, stream>>>(
      Wq, Wk, Wv, Wo, wqt, wkt, wvt, wot);
  cvt_ffn_tiled<<<dim3((FF / 16) * (C / 128), 2, NL), blk, 0, stream>>>(
      w1, w2, w1t, w2t);

  for (int i = 0; i < NL; ++i) {
    const size_t wOff = (size_t)i * C * C;
    const unsigned short* w1l = w1t + (size_t)i * SZ_W1;
    const unsigned short* w2l = w2t + (size_t)i * SZ_W1;
    // QKV projection -> bf16 q,k,v   (576 blocks, BN=64)
    mfma_conv<1, 64, 1, false, false, true><<<dim3(8 * 18 * 4), blk, 0, stream>>>(
        xbh, wqt + wOff, wkt + wOff, wvt + wOff,
        bq + i * C, bk + i * C, bv + i * C, mask,
        qbh, kbh, vbh, C, C, 6, 4);
    // fused attention -> bf16
    fused_attn<<<dim3(T / 64, B * H), blk, 0, stream>>>(
        qbh, kbh, vbh, mask, ek + (size_t)i * D * 9, ev + (size_t)i * D * 9, hidh);
    // Wo projection: split-K3 -> fp32 partials   (576 blocks, BN=64)
    mfma_conv<1, 64, 3, false, false, false><<<dim3(8 * 6 * 12), blk, 0, stream>>>(
        hidh, wot + wOff, wot + wOff, wot + wOff,
        bo + i * C, bo + i * C, bo + i * C, mask,
        ypart, ypart, ypart, C, C, 6, 12);
    add_norm_wave<3, false, false><<<dim3(T / 4, B), blk, 0, stream>>>(
        xr, ypart, n1g + i * C, n1b + i * C, mask, xr1, xfh);
    // FFN up: BN=128 (wave 64x64), GELU+mask, bf16 out   (384 blocks)
    mfma_conv<3, 128, 1, true, true, true><<<dim3(4 * 24 * 4), blk, 0, stream>>>(
        xfh, w1l, w1l, w1l, b1 + i * FF, b1 + i * FF, b1 + i * FF, mask,
        hidh, hidh, hidh, C, FF, 24, 4);
    // FFN down: BN=128, split-K4 -> fp32 partials   (384 blocks)
    mfma_conv<3, 128, 4, false, false, false><<<dim3(4 * 6 * 16), blk, 0, stream>>>(
        hidh, w2l, w2l, w2l, b2 + i * C, b2 + i * C, b2 + i * C, mask,
        ypart, ypart, ypart, FF, C, 6, 16);
    add_norm_wave<4, true, true><<<dim3(T / 4, B), blk, 0, stream>>>(
        xr1, ypart, n2g + i * C, n2b + i * C, mask, xr, xbh);
  }
  transpose_out<<<dim3(T / 32, C / 32, B), blk, 0, stream>>>(xr, outp);
}